// Round 7
// baseline (1890.748 us; speedup 1.0000x reference)
//
#include <hip/hip_runtime.h>

#define DEV __device__ __forceinline__

typedef __attribute__((ext_vector_type(8))) short short8;
typedef __attribute__((ext_vector_type(4))) float f32x4;
typedef unsigned short u16;

constexpr int kV = 80000, kD = 300, kNN = 32, kEE = 64, kHH = 4, kCC = 75;
constexpr int kB = 32, kT = 35, kU = 1024, kVG = 50000;
constexpr int kG = kB * kT;          // 1120
constexpr int kM = kG;

constexpr size_t alignup(size_t x) { return (x + 255) & ~size_t(255); }
constexpr size_t OFF_BAR   = 0;       // 64 flag slots (1024 B reserved)
constexpr size_t OFF_WSRC  = 1024;
constexpr size_t OFF_WDST  = alignup(OFF_WSRC + 1200 * 4);
constexpr size_t OFF_BIAS  = alignup(OFF_WDST + 1200 * 4);
constexpr size_t OFF_SIG   = alignup(OFF_BIAS + 3 * 4096 * 4);
constexpr size_t OFF_WX0   = alignup(OFF_SIG + (size_t)35 * 32 * 640 * 2);
constexpr size_t OFF_WX12  = alignup(OFF_WX0 + (size_t)4096 * 640 * 2);
constexpr size_t OFF_GATES = alignup(OFF_WX12 + (size_t)2 * 4096 * 1024 * 2);
constexpr size_t OFF_HIST  = alignup(OFF_GATES + (size_t)1120 * 4096 * 4);
constexpr size_t OFF_PART  = alignup(OFF_HIST + (size_t)3 * 35 * 32 * 1024 * 2);
constexpr size_t OFF_LSE   = alignup(OFF_PART + (size_t)1120 * 784 * 8);
constexpr size_t OFF_LINWB = alignup(OFF_LSE + 1120 * 4);
constexpr size_t kLinWBytes = (size_t)kVG * 1024 * 2;
constexpr size_t kNeedBW   = OFF_LINWB + kLinWBytes;
constexpr size_t OFF_WHB   = alignup(OFF_LINWB + kLinWBytes);
constexpr size_t kWhbBytes = (size_t)3 * 4096 * 1024 * 2;
constexpr size_t kNeedWHB  = OFF_WHB + kWhbBytes;

DEV u16 f2bf(float f) {
  union { float f; unsigned u; } v; v.f = f;
  unsigned r = v.u + 0x7fffu + ((v.u >> 16) & 1u);
  return (u16)(r >> 16);
}
DEV float fexp(float x) { return __builtin_amdgcn_exp2f(x * 1.4426950408889634f); }
DEV float fsigm(float x) {
  float t = __builtin_amdgcn_exp2f(-1.4426950408889634f * x);
  return __builtin_amdgcn_rcpf(1.f + t);
}
DEV float ftanh(float x) {
  float xc = fminf(fmaxf(x, -20.f), 20.f);
  float t = __builtin_amdgcn_exp2f(2.8853900817779268f * xc);
  return (t - 1.f) * __builtin_amdgcn_rcpf(t + 1.f);
}
DEV f32x4 mfma16(short8 a, short8 b, f32x4 c) {
  return __builtin_amdgcn_mfma_f32_16x16x32_bf16(a, b, c, 0, 0, 0);
}
// store a bf16 directly to the coherent LLC (bypass non-coherent per-XCD L2).
DEV void store_u16_llc(u16* p, u16 v) {
  unsigned vv = v;
  asm volatile("global_store_short %0, %1, off sc0 sc1"
               :: "v"(p), "v"(vv) : "memory");
}

// ---------------- prep: ws_src/ws_dst (W @ att vectors), bias sums ----------
__global__ void prep_small(const float* __restrict__ gat_W,
                           const float* __restrict__ att_src,
                           const float* __restrict__ att_dst,
                           const float* __restrict__ b_ih,
                           const float* __restrict__ b_hh,
                           float* __restrict__ ws_src, float* __restrict__ ws_dst,
                           float* __restrict__ bias_sum) {
  int total = 1200 + 1200 + 3 * 4096;
  for (int i = blockIdx.x * blockDim.x + threadIdx.x; i < total; i += gridDim.x * blockDim.x) {
    if (i < 1200) {
      int d = i >> 2, h = i & 3;
      float s = 0.f;
      for (int c = 0; c < kCC; ++c) s += gat_W[d * 300 + h * kCC + c] * att_src[h * kCC + c];
      ws_src[i] = s;
    } else if (i < 2400) {
      int j = i - 1200; int d = j >> 2, h = j & 3;
      float s = 0.f;
      for (int c = 0; c < kCC; ++c) s += gat_W[d * 300 + h * kCC + c] * att_dst[h * kCC + c];
      ws_dst[j] = s;
    } else {
      int j = i - 2400;
      bias_sum[j] = b_ih[j] + b_hh[j];
    }
  }
}

// ---------------- prep: bf16 weights (W_ih0, W_ih_rest, W_hh) ---------------
__global__ void wx_prep(const float* __restrict__ W_ih0,
                        const float* __restrict__ W_ih_rest,
                        const float* __restrict__ W_hh,
                        u16* __restrict__ wx0, u16* __restrict__ wx12,
                        u16* __restrict__ whb) {
  const int n0 = 4096 * 640;
  const int n12 = 2 * 4096 * 1024;
  const int nhh = 3 * 4096 * 1024;
  int total = n0 + n12 + nhh;
  for (int i = blockIdx.x * blockDim.x + threadIdx.x; i < total; i += gridDim.x * blockDim.x) {
    if (i < n0) {
      int row = i / 640, col = i - row * 640;
      float v = (col < 600) ? W_ih0[row * 600 + col] : 0.f;
      wx0[i] = f2bf(v);
    } else if (i < n0 + n12) {
      int j = i - n0;
      wx12[j] = f2bf(W_ih_rest[j]);
    } else {
      int j = i - n0 - n12;
      if (whb) whb[j] = f2bf(W_hh[j]);
    }
  }
}

// ---------------- prep: bf16 copy of lin_W ----------------------------------
__global__ void wb_conv(const float* __restrict__ W, u16* __restrict__ Wb) {
  const long n = (long)kVG * 1024;
  long stride = (long)gridDim.x * blockDim.x * 8;
  for (long i = (long)(blockIdx.x * blockDim.x + threadIdx.x) * 8; i < n; i += stride) {
    float4 a = *(const float4*)(W + i);
    float4 b = *(const float4*)(W + i + 4);
    u16 t[8] = {f2bf(a.x), f2bf(a.y), f2bf(a.z), f2bf(a.w),
                f2bf(b.x), f2bf(b.y), f2bf(b.z), f2bf(b.w)};
    *(uint4*)(Wb + i) = *(const uint4*)t;
  }
}

// ---------------- GAT (node-0 only, factored attention) ---------------------
__global__ void __launch_bounds__(256) gat_kernel(
    const int* __restrict__ x_indices, const int* __restrict__ edge_index,
    const float* __restrict__ X, const float* __restrict__ gat_W,
    const float* __restrict__ gat_bias, const float* __restrict__ ws_src,
    const float* __restrict__ ws_dst, u16* __restrict__ sig) {
  __shared__ float xs[32][301];
  __shared__ float a_s[32][4];
  __shared__ float a_d0[4];
  __shared__ float alpha[4][32];
  __shared__ float xw[4][301];
  __shared__ int allowed[32];
  int g = blockIdx.x, tid = threadIdx.x;
  const int* idx = x_indices + g * 32;
  for (int i = tid; i < 32 * 300; i += 256) {
    int j = i / 300, d2 = i - j * 300;
    xs[j][d2] = X[(size_t)idx[j] * 300 + d2];
  }
  if (tid < 32) allowed[tid] = (tid == 0) ? 1 : 0;
  __syncthreads();
  if (tid < 128) {
    int j = tid >> 2, h = tid & 3;
    float s = 0.f;
    for (int d2 = 0; d2 < 300; ++d2) s += xs[j][d2] * ws_src[d2 * 4 + h];
    a_s[j][h] = s;
  } else if (tid < 132) {
    int h = tid - 128; float s = 0.f;
    for (int d2 = 0; d2 < 300; ++d2) s += xs[0][d2] * ws_dst[d2 * 4 + h];
    a_d0[h] = s;
  } else if (tid >= 192) {
    int e = tid - 192;
    int src = edge_index[g * 128 + e];
    int dst = edge_index[g * 128 + 64 + e];
    if (dst == 0) allowed[src] = 1;
  }
  __syncthreads();
  if (tid < 4) {
    int h = tid;
    float ev[32];
    float mx = -1e30f;
    #pragma unroll
    for (int j = 0; j < 32; ++j) {
      float v = a_d0[h] + a_s[j][h];
      v = (v > 0.f) ? v : 0.2f * v;
      v = allowed[j] ? v : -1e9f;
      ev[j] = v; mx = fmaxf(mx, v);
    }
    float ssum = 0.f;
    #pragma unroll
    for (int j = 0; j < 32; ++j) { float p = fexp(ev[j] - mx); ev[j] = p; ssum += p; }
    float inv = 1.f / ssum;
    #pragma unroll
    for (int j = 0; j < 32; ++j) alpha[h][j] = ev[j] * inv;
  }
  __syncthreads();
  for (int i = tid; i < 4 * 300; i += 256) {
    int h = i / 300, d2 = i - h * 300;
    float s = 0.f;
    #pragma unroll
    for (int j = 0; j < 32; ++j) s += alpha[h][j] * xs[j][d2];
    xw[h][d2] = s;
  }
  __syncthreads();
  int t = g % 35, b = g / 35;
  u16* srow = sig + ((size_t)t * 32 + b) * 640;
  for (int hc = tid; hc < 300; hc += 256) {
    srow[hc] = f2bf(xs[0][hc]);           // curr_emb = X[idx 0]
    int h = hc / 75;
    float s = gat_bias[hc];
    for (int d2 = 0; d2 < 300; ++d2) s += xw[h][d2] * gat_W[d2 * 300 + hc];
    srow[300 + hc] = f2bf(s);
  }
  for (int i2 = 600 + tid; i2 < 640; i2 += 256) srow[i2] = 0;  // zero pad
}

// ---------------- fence-free flag barrier (LLC-direct h stores) -------------
DEV void flag_barrier(unsigned* flags, int nb, unsigned s) {
  __syncthreads();   // implies vmcnt drain: h stores complete at LLC
  if (threadIdx.x == 0)
    __hip_atomic_store(flags + blockIdx.x, s, __ATOMIC_RELAXED, __HIP_MEMORY_SCOPE_AGENT);
  if (threadIdx.x < 64) {
    for (int j = threadIdx.x; j < nb; j += 64) {
      while (__hip_atomic_load(flags + j, __ATOMIC_RELAXED, __HIP_MEMORY_SCOPE_AGENT) < s)
        __builtin_amdgcn_s_sleep(1);
    }
  }
  __syncthreads();
}

// ---------------- bulk input-gate GEMM (reg-prefetch + LDS dbuf) ------------
__global__ void __launch_bounds__(256, 1) gemm_ig(
    const u16* __restrict__ A, const u16* __restrict__ Bw,
    float* __restrict__ gates, int K) {
  int bid = blockIdx.x;
  int bm = bid % 9, bn = bid / 9;
  int m0 = bm * 128, n0 = bn * 128;
  int tid = threadIdx.x, w = tid >> 6, lane = tid & 63, l15 = lane & 15, lhi = lane >> 4;
  int wm = w & 1, wn = w >> 1;
  __shared__ u16 As[2][128][40];
  __shared__ u16 Bs[2][128][40];
  int rowq[2], chq[2];
  const u16* asrc[2];
  const u16* bsrc[2];
  bool aok[2];
  #pragma unroll
  for (int qq = 0; qq < 2; ++qq) {
    int c = tid * 2 + qq; rowq[qq] = c >> 2; chq[qq] = c & 3;
    int m = m0 + rowq[qq];
    aok[qq] = (m < kM);
    int mm = aok[qq] ? m : 0;
    asrc[qq] = A + (size_t)mm * K + chq[qq] * 8;
    bsrc[qq] = Bw + (size_t)(n0 + rowq[qq]) * K + chq[qq] * 8;
  }
  uint4 av[2], bv[2];
  auto LOAD = [&](int k0) {
    #pragma unroll
    for (int qq = 0; qq < 2; ++qq) {
      uint4 a{0u, 0u, 0u, 0u};
      if (aok[qq]) a = *(const uint4*)(asrc[qq] + k0);
      av[qq] = a;
      bv[qq] = *(const uint4*)(bsrc[qq] + k0);
    }
  };
  f32x4 acc[4][4];
  #pragma unroll
  for (int i = 0; i < 4; ++i)
    #pragma unroll
    for (int j = 0; j < 4; ++j) { f32x4 z = {0.f, 0.f, 0.f, 0.f}; acc[i][j] = z; }

  int nkt = K >> 5;
  LOAD(0);
  for (int kt = 0; kt < nkt; ++kt) {
    int cur = kt & 1;
    #pragma unroll
    for (int qq = 0; qq < 2; ++qq) {
      *(uint4*)&As[cur][rowq[qq]][chq[qq] * 8] = av[qq];
      *(uint4*)&Bs[cur][rowq[qq]][chq[qq] * 8] = bv[qq];
    }
    __syncthreads();
    if (kt < nkt - 1) LOAD((kt + 1) * 32);
    short8 bfr[4];
    #pragma unroll
    for (int nt = 0; nt < 4; ++nt)
      bfr[nt] = *(const short8*)&Bs[cur][wn * 64 + nt * 16 + l15][lhi * 8];
    #pragma unroll
    for (int mt = 0; mt < 4; ++mt) {
      short8 af = *(const short8*)&As[cur][wm * 64 + mt * 16 + l15][lhi * 8];
      #pragma unroll
      for (int nt = 0; nt < 4; ++nt)
        acc[mt][nt] = mfma16(af, bfr[nt], acc[mt][nt]);
    }
  }
  #pragma unroll
  for (int mt = 0; mt < 4; ++mt) {
    #pragma unroll
    for (int r = 0; r < 4; ++r) {
      int m = m0 + wm * 64 + mt * 16 + lhi * 4 + r;
      if (m < kM) {
        float* orow = gates + (size_t)m * 4096;
        #pragma unroll
        for (int nt = 0; nt < 4; ++nt) {
          int n = n0 + wn * 64 + nt * 16 + l15;
          orow[n] = acc[mt][nt][r];
        }
      }
    }
  }
}

// ---------------- LSTM recurrence: 64 blocks x 16 units, W_hh LDS-resident --
__global__ void __launch_bounds__(256, 1) lstm_rec(
    const float* __restrict__ W_hh_l,   // [4096][1024] fp32, this layer
    const u16* __restrict__ whb_l,      // bf16 copy (may be null)
    const float* __restrict__ gates,    // [1120][4096] f32 (x-part)
    const float* __restrict__ bias_l,   // [4096]
    u16* __restrict__ hout,             // [35*32][1024] bf16
    unsigned* flags, unsigned sbase) {
  const int p = blockIdx.x;             // 0..63
  const int u0 = p * 16;
  const int tid = threadIdx.x;
  const int w = tid >> 6, lane = tid & 63, l15 = lane & 15, lhi = lane >> 4;
  __shared__ u16 whs[64][1032];         // row = gate*16 + unit
  __shared__ float gbuf[64][33];

  if (whb_l) {
    for (int i = tid; i < 64 * 128; i += 256) {
      int row = i >> 7, seg = i & 127;
      int g = row >> 4, j = row & 15;
      uint4 v = *(const uint4*)(whb_l + (((size_t)(g * 1024 + u0 + j)) << 10) + seg * 8);
      *(uint4*)&whs[row][seg * 8] = v;
    }
  } else {
    for (int i = tid; i < 64 * 256; i += 256) {
      int row = i >> 8, seg = i & 255;
      int g = row >> 4, j = row & 15;
      const float* src = W_hh_l + (((size_t)(g * 1024 + u0 + j)) << 10) + seg * 4;
      float4 f = *(const float4*)src;
      u16 tmp[4] = {f2bf(f.x), f2bf(f.y), f2bf(f.z), f2bf(f.w)};
      *(uint2*)&whs[row][seg * 4] = *(const uint2*)tmp;
    }
  }

  const int pu = tid & 15, pb = tid >> 4;  // unit pu; batches pb, pb+16
  const float* gb = gates + u0 + pu;
  float bias_r[4];
  #pragma unroll
  for (int g = 0; g < 4; ++g) bias_r[g] = bias_l[g * 1024 + u0 + pu];
  float c0 = 0.f, c1 = 0.f;

  float gx0[4], gx1[4];
  #pragma unroll
  for (int g = 0; g < 4; ++g) {
    gx0[g] = gb[(size_t)pb * 4096 + g * 1024];
    gx1[g] = gb[(size_t)(pb + 16) * 4096 + g * 1024];
  }
  __syncthreads();  // whs ready (also before t=0 h-stores/barrier)

  for (int t = 0; t < 35; ++t) {
    float p0[4] = {0.f, 0.f, 0.f, 0.f}, p1[4] = {0.f, 0.f, 0.f, 0.f};
    if (t > 0) {
      const u16* hp = hout + (size_t)(t - 1) * 32 * 1024;
      const u16* h0p = hp + l15 * 1024 + lhi * 8;
      const u16* h1p = hp + (l15 + 16) * 1024 + lhi * 8;
      f32x4 acc0 = {0.f, 0.f, 0.f, 0.f}, acc1 = {0.f, 0.f, 0.f, 0.f};
      #pragma unroll 8
      for (int ks = 0; ks < 32; ++ks) {
        int k = ks * 32;
        short8 af = *(const short8*)&whs[w * 16 + l15][k + lhi * 8];
        short8 b0 = *(const short8*)(h0p + k);
        short8 b1 = *(const short8*)(h1p + k);
        acc0 = mfma16(af, b0, acc0);
        acc1 = mfma16(af, b1, acc1);
      }
      #pragma unroll
      for (int r = 0; r < 4; ++r) {
        gbuf[w * 16 + lhi * 4 + r][l15]      = acc0[r];
        gbuf[w * 16 + lhi * 4 + r][l15 + 16] = acc1[r];
      }
      __syncthreads();
      #pragma unroll
      for (int g = 0; g < 4; ++g) {
        p0[g] = gbuf[g * 16 + pu][pb];
        p1[g] = gbuf[g * 16 + pu][pb + 16];
      }
    }
    float gxn0[4], gxn1[4];
    if (t < 34) {
      #pragma unroll
      for (int g = 0; g < 4; ++g) {
        gxn0[g] = gb[((size_t)(t + 1) * 32 + pb) * 4096 + g * 1024];
        gxn1[g] = gb[((size_t)(t + 1) * 32 + pb + 16) * 4096 + g * 1024];
      }
    }
    float iv0 = gx0[0] + p0[0] + bias_r[0];
    float fv0 = gx0[1] + p0[1] + bias_r[1];
    float gv0 = gx0[2] + p0[2] + bias_r[2];
    float ov0 = gx0[3] + p0[3] + bias_r[3];
    float iv1 = gx1[0] + p1[0] + bias_r[0];
    float fv1 = gx1[1] + p1[1] + bias_r[1];
    float gv1 = gx1[2] + p1[2] + bias_r[2];
    float ov1 = gx1[3] + p1[3] + bias_r[3];
    float cc0 = fsigm(fv0) * c0 + fsigm(iv0) * ftanh(gv0);
    float hh0 = fsigm(ov0) * ftanh(cc0); c0 = cc0;
    float cc1 = fsigm(fv1) * c1 + fsigm(iv1) * ftanh(gv1);
    float hh1 = fsigm(ov1) * ftanh(cc1); c1 = cc1;
    store_u16_llc(hout + ((size_t)(t * 32 + pb)) * 1024 + u0 + pu, f2bf(hh0));
    store_u16_llc(hout + ((size_t)(t * 32 + pb + 16)) * 1024 + u0 + pu, f2bf(hh1));
    if (t < 34) flag_barrier(flags, 64, sbase + (unsigned)t + 1u);
    #pragma unroll
    for (int g = 0; g < 4; ++g) { gx0[g] = gxn0[g]; gx1[g] = gxn1[g]; }
  }
}

// ---------------- logits GEMM (reg-prefetch + LDS dbuf) + row partials ------
template <bool BW16>
__global__ void __launch_bounds__(256, 1) gemm_logits(
    const u16* __restrict__ hist2, const u16* __restrict__ linwb,
    const float* __restrict__ lin_W, const float* __restrict__ lin_b,
    float* __restrict__ out, float2* __restrict__ partials) {
  // XCD-bijective swizzle: 9 consecutive logical tiles (one B-strip) -> one XCD
  int nwg = gridDim.x, orig = blockIdx.x;
  int q = nwg >> 3, r = nwg & 7, xcd = orig & 7, off = orig >> 3;
  int bid = (xcd < r ? xcd * (q + 1) : r * (q + 1) + (xcd - r) * q) + off;
  int bm = bid % 9, bn = bid / 9;
  int m0 = bm * 128, n0 = bn * 128;
  int tid = threadIdx.x, w = tid >> 6, lane = tid & 63, l15 = lane & 15, lhi = lane >> 4;
  int wm = w & 1, wn = w >> 1;
  __shared__ u16 As[2][128][40];
  __shared__ u16 Bs[2][128][40];
  int rowq[2], chq[2];
  const u16* asrc[2];
  const u16* bsrc16[2];
  const float* bsrc32[2];
  bool aok[2], bok[2];
  #pragma unroll
  for (int qq = 0; qq < 2; ++qq) {
    int c = tid * 2 + qq; rowq[qq] = c >> 2; chq[qq] = c & 3;
    int m = m0 + rowq[qq];
    aok[qq] = (m < kM);
    int mm = aok[qq] ? m : 0;
    asrc[qq] = hist2 + (((size_t)((mm % 35) * 32 + mm / 35)) << 10) + chq[qq] * 8;
    int n = n0 + rowq[qq];
    bok[qq] = (n < kVG);
    int nn = bok[qq] ? n : 0;
    bsrc16[qq] = linwb + ((size_t)nn << 10) + chq[qq] * 8;
    bsrc32[qq] = lin_W + ((size_t)nn << 10) + chq[qq] * 8;
  }
  uint4 av[2], bv[2];
  auto LOAD = [&](int k0) {
    #pragma unroll
    for (int qq = 0; qq < 2; ++qq) {
      uint4 a{0u, 0u, 0u, 0u};
      if (aok[qq]) a = *(const uint4*)(asrc[qq] + k0);
      av[qq] = a;
      uint4 b{0u, 0u, 0u, 0u};
      if (bok[qq]) {
        if (BW16) {
          b = *(const uint4*)(bsrc16[qq] + k0);
        } else {
          float4 f0 = *(const float4*)(bsrc32[qq] + k0);
          float4 f1 = *(const float4*)(bsrc32[qq] + k0 + 4);
          b.x = (unsigned)f2bf(f0.x) | ((unsigned)f2bf(f0.y) << 16);
          b.y = (unsigned)f2bf(f0.z) | ((unsigned)f2bf(f0.w) << 16);
          b.z = (unsigned)f2bf(f1.x) | ((unsigned)f2bf(f1.y) << 16);
          b.w = (unsigned)f2bf(f1.z) | ((unsigned)f2bf(f1.w) << 16);
        }
      }
      bv[qq] = b;
    }
  };
  f32x4 acc[4][4];
  #pragma unroll
  for (int i = 0; i < 4; ++i)
    #pragma unroll
    for (int j = 0; j < 4; ++j) { f32x4 z = {0.f, 0.f, 0.f, 0.f}; acc[i][j] = z; }

  LOAD(0);
  for (int kt = 0; kt < 32; ++kt) {
    int cur = kt & 1;
    #pragma unroll
    for (int qq = 0; qq < 2; ++qq) {
      *(uint4*)&As[cur][rowq[qq]][chq[qq] * 8] = av[qq];
      *(uint4*)&Bs[cur][rowq[qq]][chq[qq] * 8] = bv[qq];
    }
    __syncthreads();
    if (kt < 31) LOAD((kt + 1) * 32);
    short8 bfr[4];
    #pragma unroll
    for (int nt = 0; nt < 4; ++nt)
      bfr[nt] = *(const short8*)&Bs[cur][wn * 64 + nt * 16 + l15][lhi * 8];
    #pragma unroll
    for (int mt = 0; mt < 4; ++mt) {
      short8 af = *(const short8*)&As[cur][wm * 64 + mt * 16 + l15][lhi * 8];
      #pragma unroll
      for (int nt = 0; nt < 4; ++nt)
        acc[mt][nt] = mfma16(af, bfr[nt], acc[mt][nt]);
    }
  }
  // epilogue: store logits + per-(row, 64-col-group) max/sumexp partials
  float bcol[4]; int ncol[4];
  #pragma unroll
  for (int nt = 0; nt < 4; ++nt) {
    int n = n0 + wn * 64 + nt * 16 + l15;
    ncol[nt] = n;
    bcol[nt] = (n < kVG) ? lin_b[n] : -INFINITY;
  }
  #pragma unroll
  for (int mt = 0; mt < 4; ++mt) {
    #pragma unroll
    for (int r = 0; r < 4; ++r) {
      int m = m0 + wm * 64 + mt * 16 + lhi * 4 + r;
      float v0 = acc[mt][0][r] + bcol[0];
      float v1 = acc[mt][1][r] + bcol[1];
      float v2 = acc[mt][2][r] + bcol[2];
      float v3 = acc[mt][3][r] + bcol[3];
      bool mok = (m < kM);
      if (mok) {
        float* orow = out + (size_t)m * kVG;
        if (ncol[0] < kVG) orow[ncol[0]] = v0;
        if (ncol[1] < kVG) orow[ncol[1]] = v1;
        if (ncol[2] < kVG) orow[ncol[2]] = v2;
        if (ncol[3] < kVG) orow[ncol[3]] = v3;
      }
      float mx = fmaxf(fmaxf(v0, v1), fmaxf(v2, v3));
      #pragma unroll
      for (int d2 = 1; d2 < 16; d2 <<= 1) mx = fmaxf(mx, __shfl_xor(mx, d2, 64));
      float sv = 0.f;
      sv += (v0 > -1e30f) ? fexp(v0 - mx) : 0.f;
      sv += (v1 > -1e30f) ? fexp(v1 - mx) : 0.f;
      sv += (v2 > -1e30f) ? fexp(v2 - mx) : 0.f;
      sv += (v3 > -1e30f) ? fexp(v3 - mx) : 0.f;
      #pragma unroll
      for (int d2 = 1; d2 < 16; d2 <<= 1) sv += __shfl_xor(sv, d2, 64);
      if (mok && l15 == 0)
        partials[(size_t)m * 784 + bn * 2 + wn] = make_float2(mx, sv);
    }
  }
}

// ---------------- row logsumexp reduce --------------------------------------
__global__ void reduce_rows(const float2* __restrict__ partials, float* __restrict__ lse) {
  int m = blockIdx.x, tid = threadIdx.x;
  float mx = -INFINITY, s = 0.f;
  for (int j = tid; j < 782; j += 256) {
    float2 p = partials[(size_t)m * 784 + j];
    if (p.x > mx) { s = s * fexp(mx - p.x) + p.y; mx = p.x; }
    else          { s += p.y * fexp(p.x - mx); }
  }
  for (int d = 1; d < 64; d <<= 1) {
    float omx = __shfl_xor(mx, d, 64);
    float os  = __shfl_xor(s, d, 64);
    if (omx > mx) { s = s * fexp(mx - omx) + os; mx = omx; }
    else          { s += os * fexp(omx - mx); }
  }
  __shared__ float smx[4], ssum[4];
  int w = tid >> 6;
  if ((tid & 63) == 0) { smx[w] = mx; ssum[w] = s; }
  __syncthreads();
  if (tid == 0) {
    for (int i = 1; i < 4; ++i) {
      float omx = smx[i], os = ssum[i];
      if (omx > mx) { s = s * fexp(mx - omx) + os; mx = omx; }
      else          { s += os * fexp(omx - mx); }
    }
    lse[m] = mx + logf(s);
  }
}

// ---------------- in-place log_softmax subtract -----------------------------
__global__ void sub_lse(float* __restrict__ out, const float* __restrict__ lse) {
  const int total4 = 14000000;  // 1120*50000/4
  for (int i = blockIdx.x * blockDim.x + threadIdx.x; i < total4; i += gridDim.x * blockDim.x) {
    int m = i / 12500;
    float4 v = ((float4*)out)[i];
    float L = lse[m];
    v.x -= L; v.y -= L; v.z -= L; v.w -= L;
    ((float4*)out)[i] = v;
  }
}

// ---------------- launch ----------------------------------------------------
extern "C" void kernel_launch(void* const* d_in, const int* in_sizes, int n_in,
                              void* d_out, int out_size, void* d_ws, size_t ws_size,
                              hipStream_t stream) {
  const int*   x_indices  = (const int*)d_in[0];
  const int*   edge_index = (const int*)d_in[1];
  const float* X          = (const float*)d_in[2];
  const float* gat_W      = (const float*)d_in[3];
  const float* att_src    = (const float*)d_in[4];
  const float* att_dst    = (const float*)d_in[5];
  const float* gat_bias   = (const float*)d_in[6];
  const float* W_ih0      = (const float*)d_in[7];
  const float* W_ih_rest  = (const float*)d_in[8];
  const float* W_hh       = (const float*)d_in[9];
  const float* b_ih       = (const float*)d_in[10];
  const float* b_hh       = (const float*)d_in[11];
  const float* lin_W      = (const float*)d_in[12];
  const float* lin_b      = (const float*)d_in[13];
  float* out = (float*)d_out;
  char* ws = (char*)d_ws;

  unsigned* flags    = (unsigned*)(ws + OFF_BAR);
  float*    ws_src   = (float*)(ws + OFF_WSRC);
  float*    ws_dst   = (float*)(ws + OFF_WDST);
  float*    bias_sum = (float*)(ws + OFF_BIAS);
  u16*      sig      = (u16*)(ws + OFF_SIG);
  u16*      wx0      = (u16*)(ws + OFF_WX0);
  u16*      wx12     = (u16*)(ws + OFF_WX12);
  float*    gates    = (float*)(ws + OFF_GATES);
  u16*      hist     = (u16*)(ws + OFF_HIST);
  float2*   partials = (float2*)(ws + OFF_PART);
  float*    lse      = (float*)(ws + OFF_LSE);
  u16*      linwb    = (u16*)(ws + OFF_LINWB);
  u16*      whb      = (u16*)(ws + OFF_WHB);
  bool use_bw  = (ws_size >= kNeedBW);
  bool use_whb = (ws_size >= kNeedWHB);

  u16* hist0 = hist;
  u16* hist1 = hist + (size_t)35 * 32 * 1024;
  u16* hist2 = hist + (size_t)2 * 35 * 32 * 1024;

  hipMemsetAsync(ws + OFF_BAR, 0, 1024, stream);
  prep_small<<<64, 256, 0, stream>>>(gat_W, att_src, att_dst, b_ih, b_hh,
                                     ws_src, ws_dst, bias_sum);
  wx_prep<<<2048, 256, 0, stream>>>(W_ih0, W_ih_rest, W_hh, wx0, wx12,
                                    use_whb ? whb : nullptr);
  if (use_bw) wb_conv<<<2048, 256, 0, stream>>>(lin_W, linwb);
  gat_kernel<<<kG, 256, 0, stream>>>(x_indices, edge_index, X, gat_W, gat_bias,
                                     ws_src, ws_dst, sig);
  // layer 0
  gemm_ig<<<288, 256, 0, stream>>>(sig, wx0, gates, 640);
  lstm_rec<<<64, 256, 0, stream>>>(W_hh, use_whb ? whb : nullptr,
                                   gates, bias_sum, hist0, flags, 0u);
  // layer 1
  gemm_ig<<<288, 256, 0, stream>>>(hist0, wx12, gates, 1024);
  lstm_rec<<<64, 256, 0, stream>>>(W_hh + (size_t)4096 * 1024,
                                   use_whb ? whb + (size_t)4096 * 1024 : nullptr,
                                   gates, bias_sum + 4096, hist1, flags, 34u);
  // layer 2
  gemm_ig<<<288, 256, 0, stream>>>(hist1, wx12 + (size_t)4096 * 1024, gates, 1024);
  lstm_rec<<<64, 256, 0, stream>>>(W_hh + (size_t)2 * 4096 * 1024,
                                   use_whb ? whb + (size_t)2 * 4096 * 1024 : nullptr,
                                   gates, bias_sum + 8192, hist2, flags, 68u);
  // logits + log_softmax
  if (use_bw)
    gemm_logits<true><<<9 * 391, 256, 0, stream>>>(hist2, linwb, lin_W, lin_b, out, partials);
  else
    gemm_logits<false><<<9 * 391, 256, 0, stream>>>(hist2, nullptr, lin_W, lin_b, out, partials);
  reduce_rows<<<kG, 256, 0, stream>>>(partials, lse);
  sub_lse<<<2048, 256, 0, stream>>>(out, lse);
}

// Round 8
// 1220.643 us; speedup vs baseline: 1.5490x; 1.5490x over previous
//
#include <hip/hip_runtime.h>

#define DEV __device__ __forceinline__

typedef __attribute__((ext_vector_type(8))) short short8;
typedef __attribute__((ext_vector_type(4))) float f32x4;
typedef unsigned short u16;

constexpr int kV = 80000, kD = 300, kNN = 32, kEE = 64, kHH = 4, kCC = 75;
constexpr int kB = 32, kT = 35, kU = 1024, kVG = 50000;
constexpr int kG = kB * kT;          // 1120
constexpr int kM = kG;

constexpr size_t alignup(size_t x) { return (x + 255) & ~size_t(255); }
constexpr size_t OFF_BAR   = 0;       // 128 flag slots (1024 B reserved)
constexpr size_t OFF_WSRC  = 1024;
constexpr size_t OFF_WDST  = alignup(OFF_WSRC + 1200 * 4);
constexpr size_t OFF_BIAS  = alignup(OFF_WDST + 1200 * 4);
constexpr size_t OFF_SIG   = alignup(OFF_BIAS + 3 * 4096 * 4);
constexpr size_t OFF_WX0   = alignup(OFF_SIG + (size_t)35 * 32 * 640 * 2);
constexpr size_t OFF_WX12  = alignup(OFF_WX0 + (size_t)4096 * 640 * 2);
constexpr size_t OFF_GATES = alignup(OFF_WX12 + (size_t)2 * 4096 * 1024 * 2);
constexpr size_t OFF_HIST  = alignup(OFF_GATES + (size_t)1120 * 4096 * 4);
constexpr size_t OFF_PART  = alignup(OFF_HIST + (size_t)3 * 35 * 32 * 1024 * 2);
constexpr size_t OFF_LSE   = alignup(OFF_PART + (size_t)1120 * 784 * 8);
constexpr size_t OFF_LINWB = alignup(OFF_LSE + 1120 * 4);
constexpr size_t kLinWBytes = (size_t)kVG * 1024 * 2;
constexpr size_t kNeedBW   = OFF_LINWB + kLinWBytes;
constexpr size_t OFF_WHB   = alignup(OFF_LINWB + kLinWBytes);
constexpr size_t kWhbBytes = (size_t)3 * 4096 * 1024 * 2;
constexpr size_t kNeedWHB  = OFF_WHB + kWhbBytes;

DEV u16 f2bf(float f) {
  union { float f; unsigned u; } v; v.f = f;
  unsigned r = v.u + 0x7fffu + ((v.u >> 16) & 1u);
  return (u16)(r >> 16);
}
DEV float fexp(float x) { return __builtin_amdgcn_exp2f(x * 1.4426950408889634f); }
DEV float fsigm(float x) {
  float t = __builtin_amdgcn_exp2f(-1.4426950408889634f * x);
  return __builtin_amdgcn_rcpf(1.f + t);
}
DEV float ftanh(float x) {
  float xc = fminf(fmaxf(x, -20.f), 20.f);
  float t = __builtin_amdgcn_exp2f(2.8853900817779268f * xc);
  return (t - 1.f) * __builtin_amdgcn_rcpf(t + 1.f);
}
DEV f32x4 mfma16(short8 a, short8 b, f32x4 c) {
  return __builtin_amdgcn_mfma_f32_16x16x32_bf16(a, b, c, 0, 0, 0);
}
// store a bf16 directly to the coherent LLC (bypass non-coherent per-XCD L2).
DEV void store_u16_llc(u16* p, u16 v) {
  unsigned vv = v;
  asm volatile("global_store_short %0, %1, off sc0 sc1"
               :: "v"(p), "v"(vv) : "memory");
}

// ---------------- prep: ws_src/ws_dst (W @ att vectors), bias sums ----------
__global__ void prep_small(const float* __restrict__ gat_W,
                           const float* __restrict__ att_src,
                           const float* __restrict__ att_dst,
                           const float* __restrict__ b_ih,
                           const float* __restrict__ b_hh,
                           float* __restrict__ ws_src, float* __restrict__ ws_dst,
                           float* __restrict__ bias_sum) {
  int total = 1200 + 1200 + 3 * 4096;
  for (int i = blockIdx.x * blockDim.x + threadIdx.x; i < total; i += gridDim.x * blockDim.x) {
    if (i < 1200) {
      int d = i >> 2, h = i & 3;
      float s = 0.f;
      for (int c = 0; c < kCC; ++c) s += gat_W[d * 300 + h * kCC + c] * att_src[h * kCC + c];
      ws_src[i] = s;
    } else if (i < 2400) {
      int j = i - 1200; int d = j >> 2, h = j & 3;
      float s = 0.f;
      for (int c = 0; c < kCC; ++c) s += gat_W[d * 300 + h * kCC + c] * att_dst[h * kCC + c];
      ws_dst[j] = s;
    } else {
      int j = i - 2400;
      bias_sum[j] = b_ih[j] + b_hh[j];
    }
  }
}

// ---------------- prep: bf16 weights (W_ih0, W_ih_rest, W_hh) ---------------
__global__ void wx_prep(const float* __restrict__ W_ih0,
                        const float* __restrict__ W_ih_rest,
                        const float* __restrict__ W_hh,
                        u16* __restrict__ wx0, u16* __restrict__ wx12,
                        u16* __restrict__ whb) {
  const int n0 = 4096 * 640;
  const int n12 = 2 * 4096 * 1024;
  const int nhh = 3 * 4096 * 1024;
  int total = n0 + n12 + nhh;
  for (int i = blockIdx.x * blockDim.x + threadIdx.x; i < total; i += gridDim.x * blockDim.x) {
    if (i < n0) {
      int row = i / 640, col = i - row * 640;
      float v = (col < 600) ? W_ih0[row * 600 + col] : 0.f;
      wx0[i] = f2bf(v);
    } else if (i < n0 + n12) {
      int j = i - n0;
      wx12[j] = f2bf(W_ih_rest[j]);
    } else {
      int j = i - n0 - n12;
      if (whb) whb[j] = f2bf(W_hh[j]);
    }
  }
}

// ---------------- prep: bf16 copy of lin_W ----------------------------------
__global__ void wb_conv(const float* __restrict__ W, u16* __restrict__ Wb) {
  const long n = (long)kVG * 1024;
  long stride = (long)gridDim.x * blockDim.x * 8;
  for (long i = (long)(blockIdx.x * blockDim.x + threadIdx.x) * 8; i < n; i += stride) {
    float4 a = *(const float4*)(W + i);
    float4 b = *(const float4*)(W + i + 4);
    u16 t[8] = {f2bf(a.x), f2bf(a.y), f2bf(a.z), f2bf(a.w),
                f2bf(b.x), f2bf(b.y), f2bf(b.z), f2bf(b.w)};
    *(uint4*)(Wb + i) = *(const uint4*)t;
  }
}

// ---------------- GAT (node-0 only, factored attention) ---------------------
__global__ void __launch_bounds__(256) gat_kernel(
    const int* __restrict__ x_indices, const int* __restrict__ edge_index,
    const float* __restrict__ X, const float* __restrict__ gat_W,
    const float* __restrict__ gat_bias, const float* __restrict__ ws_src,
    const float* __restrict__ ws_dst, u16* __restrict__ sig) {
  __shared__ float xs[32][301];
  __shared__ float a_s[32][4];
  __shared__ float a_d0[4];
  __shared__ float alpha[4][32];
  __shared__ float xw[4][301];
  __shared__ int allowed[32];
  int g = blockIdx.x, tid = threadIdx.x;
  const int* idx = x_indices + g * 32;
  for (int i = tid; i < 32 * 300; i += 256) {
    int j = i / 300, d2 = i - j * 300;
    xs[j][d2] = X[(size_t)idx[j] * 300 + d2];
  }
  if (tid < 32) allowed[tid] = (tid == 0) ? 1 : 0;
  __syncthreads();
  if (tid < 128) {
    int j = tid >> 2, h = tid & 3;
    float s = 0.f;
    for (int d2 = 0; d2 < 300; ++d2) s += xs[j][d2] * ws_src[d2 * 4 + h];
    a_s[j][h] = s;
  } else if (tid < 132) {
    int h = tid - 128; float s = 0.f;
    for (int d2 = 0; d2 < 300; ++d2) s += xs[0][d2] * ws_dst[d2 * 4 + h];
    a_d0[h] = s;
  } else if (tid >= 192) {
    int e = tid - 192;
    int src = edge_index[g * 128 + e];
    int dst = edge_index[g * 128 + 64 + e];
    if (dst == 0) allowed[src] = 1;
  }
  __syncthreads();
  if (tid < 4) {
    int h = tid;
    float ev[32];
    float mx = -1e30f;
    #pragma unroll
    for (int j = 0; j < 32; ++j) {
      float v = a_d0[h] + a_s[j][h];
      v = (v > 0.f) ? v : 0.2f * v;
      v = allowed[j] ? v : -1e9f;
      ev[j] = v; mx = fmaxf(mx, v);
    }
    float ssum = 0.f;
    #pragma unroll
    for (int j = 0; j < 32; ++j) { float p = fexp(ev[j] - mx); ev[j] = p; ssum += p; }
    float inv = 1.f / ssum;
    #pragma unroll
    for (int j = 0; j < 32; ++j) alpha[h][j] = ev[j] * inv;
  }
  __syncthreads();
  for (int i = tid; i < 4 * 300; i += 256) {
    int h = i / 300, d2 = i - h * 300;
    float s = 0.f;
    #pragma unroll
    for (int j = 0; j < 32; ++j) s += alpha[h][j] * xs[j][d2];
    xw[h][d2] = s;
  }
  __syncthreads();
  int t = g % 35, b = g / 35;
  u16* srow = sig + ((size_t)t * 32 + b) * 640;
  for (int hc = tid; hc < 300; hc += 256) {
    srow[hc] = f2bf(xs[0][hc]);           // curr_emb = X[idx 0]
    int h = hc / 75;
    float s = gat_bias[hc];
    for (int d2 = 0; d2 < 300; ++d2) s += xw[h][d2] * gat_W[d2 * 300 + hc];
    srow[300 + hc] = f2bf(s);
  }
  for (int i2 = 600 + tid; i2 < 640; i2 += 256) srow[i2] = 0;  // zero pad
}

// ---------------- fence-free flag barrier (LLC-direct h stores) -------------
DEV void flag_barrier(unsigned* flags, int nb, unsigned s) {
  __syncthreads();   // implies vmcnt drain: h stores complete at LLC
  if (threadIdx.x == 0)
    __hip_atomic_store(flags + blockIdx.x, s, __ATOMIC_RELAXED, __HIP_MEMORY_SCOPE_AGENT);
  if (threadIdx.x < 64) {
    for (int j = threadIdx.x; j < nb; j += 64) {
      while (__hip_atomic_load(flags + j, __ATOMIC_RELAXED, __HIP_MEMORY_SCOPE_AGENT) < s)
        __builtin_amdgcn_s_sleep(1);
    }
  }
  __syncthreads();
}

// ---------------- bulk input-gate GEMM (reg-prefetch + LDS dbuf) ------------
__global__ void __launch_bounds__(256, 1) gemm_ig(
    const u16* __restrict__ A, const u16* __restrict__ Bw,
    float* __restrict__ gates, int K) {
  int bid = blockIdx.x;
  int bm = bid % 9, bn = bid / 9;
  int m0 = bm * 128, n0 = bn * 128;
  int tid = threadIdx.x, w = tid >> 6, lane = tid & 63, l15 = lane & 15, lhi = lane >> 4;
  int wm = w & 1, wn = w >> 1;
  __shared__ u16 As[2][128][40];
  __shared__ u16 Bs[2][128][40];
  int rowq[2], chq[2];
  const u16* asrc[2];
  const u16* bsrc[2];
  bool aok[2];
  #pragma unroll
  for (int qq = 0; qq < 2; ++qq) {
    int c = tid * 2 + qq; rowq[qq] = c >> 2; chq[qq] = c & 3;
    int m = m0 + rowq[qq];
    aok[qq] = (m < kM);
    int mm = aok[qq] ? m : 0;
    asrc[qq] = A + (size_t)mm * K + chq[qq] * 8;
    bsrc[qq] = Bw + (size_t)(n0 + rowq[qq]) * K + chq[qq] * 8;
  }
  uint4 av[2], bv[2];
  auto LOAD = [&](int k0) {
    #pragma unroll
    for (int qq = 0; qq < 2; ++qq) {
      uint4 a{0u, 0u, 0u, 0u};
      if (aok[qq]) a = *(const uint4*)(asrc[qq] + k0);
      av[qq] = a;
      bv[qq] = *(const uint4*)(bsrc[qq] + k0);
    }
  };
  f32x4 acc[4][4];
  #pragma unroll
  for (int i = 0; i < 4; ++i)
    #pragma unroll
    for (int j = 0; j < 4; ++j) { f32x4 z = {0.f, 0.f, 0.f, 0.f}; acc[i][j] = z; }

  int nkt = K >> 5;
  LOAD(0);
  for (int kt = 0; kt < nkt; ++kt) {
    int cur = kt & 1;
    #pragma unroll
    for (int qq = 0; qq < 2; ++qq) {
      *(uint4*)&As[cur][rowq[qq]][chq[qq] * 8] = av[qq];
      *(uint4*)&Bs[cur][rowq[qq]][chq[qq] * 8] = bv[qq];
    }
    __syncthreads();
    if (kt < nkt - 1) LOAD((kt + 1) * 32);
    short8 bfr[4];
    #pragma unroll
    for (int nt = 0; nt < 4; ++nt)
      bfr[nt] = *(const short8*)&Bs[cur][wn * 64 + nt * 16 + l15][lhi * 8];
    #pragma unroll
    for (int mt = 0; mt < 4; ++mt) {
      short8 af = *(const short8*)&As[cur][wm * 64 + mt * 16 + l15][lhi * 8];
      #pragma unroll
      for (int nt = 0; nt < 4; ++nt)
        acc[mt][nt] = mfma16(af, bfr[nt], acc[mt][nt]);
    }
  }
  #pragma unroll
  for (int mt = 0; mt < 4; ++mt) {
    #pragma unroll
    for (int r = 0; r < 4; ++r) {
      int m = m0 + wm * 64 + mt * 16 + lhi * 4 + r;
      if (m < kM) {
        float* orow = gates + (size_t)m * 4096;
        #pragma unroll
        for (int nt = 0; nt < 4; ++nt) {
          int n = n0 + wn * 64 + nt * 16 + l15;
          orow[n] = acc[mt][nt][r];
        }
      }
    }
  }
}

// ---------------- LSTM recurrence: 128 blocks x 8 units (round-6 structure) -
__global__ void __launch_bounds__(256, 1) lstm_rec(
    const float* __restrict__ W_hh_l,   // [4096][1024] fp32, this layer
    const u16* __restrict__ whb_l,      // bf16 copy (may be null)
    const float* __restrict__ gates,    // [1120][4096] f32 (x-part)
    const float* __restrict__ bias_l,   // [4096]
    u16* __restrict__ hout,             // [35*32][1024] bf16
    unsigned* flags, unsigned sbase) {
  const int p = blockIdx.x;             // 0..127
  const int tid = threadIdx.x;
  const int w = tid >> 6, lane = tid & 63, l15 = lane & 15, lhi = lane >> 4;
  __shared__ u16 whs[32][1032];         // rows: idx = g*8+jj -> global g*1024+8p+jj
  __shared__ float pred[4][32][33];     // [wave][w-row][batch]
  if (whb_l) {
    for (int i = tid; i < 32 * 128; i += 256) {
      int row = i >> 7, seg = i & 127;
      int g = row >> 3, jj = row & 7;
      uint4 v = *(const uint4*)(whb_l + (((size_t)(g * 1024 + p * 8 + jj)) << 10) + seg * 8);
      *(uint4*)&whs[row][seg * 8] = v;
    }
  } else {
    for (int i = tid; i < 32 * 256; i += 256) {
      int row = i >> 8, seg = i & 255;
      int g = row >> 3, jj = row & 7;
      const float* src = W_hh_l + (((size_t)(g * 1024 + p * 8 + jj)) << 10) + seg * 4;
      float4 f = *(const float4*)src;
      u16 tmp[4] = {f2bf(f.x), f2bf(f.y), f2bf(f.z), f2bf(f.w)};
      *(uint2*)&whs[row][seg * 4] = *(const uint2*)tmp;
    }
  }
  const int bb = tid >> 3, jj2 = tid & 7;
  float bias_r[4];
  #pragma unroll
  for (int g = 0; g < 4; ++g) bias_r[g] = bias_l[g * 1024 + p * 8 + jj2];
  float c_reg = 0.f;
  const int kbase = w * 256;
  const float* gbase = gates + p * 8 + jj2 + (size_t)bb * 4096;

  // prefetch gx for t=0
  float gx[4];
  #pragma unroll
  for (int g = 0; g < 4; ++g) gx[g] = gbase[g * 1024];

  for (int t = 0; t < 35; ++t) {
    float gxn[4];
    if (t > 0) {
      const u16* hp = hout + (size_t)(t - 1) * 32 * 1024;
      const u16* hrow0 = hp + l15 * 1024 + lhi * 8;
      const u16* hrow1 = hp + (l15 + 16) * 1024 + lhi * 8;
      f32x4 acc00 = {0,0,0,0}, acc01 = {0,0,0,0}, acc10 = {0,0,0,0}, acc11 = {0,0,0,0};
      #pragma unroll
      for (int kk = 0; kk < 8; ++kk) {
        int k = kbase + kk * 32;
        short8 bf0 = *(const short8*)(hrow0 + k);
        short8 bf1 = *(const short8*)(hrow1 + k);
        short8 af0 = *(const short8*)&whs[l15][k + lhi * 8];
        short8 af1 = *(const short8*)&whs[16 + l15][k + lhi * 8];
        acc00 = mfma16(af0, bf0, acc00);
        acc01 = mfma16(af0, bf1, acc01);
        acc10 = mfma16(af1, bf0, acc10);
        acc11 = mfma16(af1, bf1, acc11);
      }
      // prefetch next step's gx while MFMAs drain (gates is constant data)
      if (t < 34) {
        const float* gp = gbase + (size_t)(t + 1) * 32 * 4096;
        #pragma unroll
        for (int g = 0; g < 4; ++g) gxn[g] = gp[g * 1024];
      }
      #pragma unroll
      for (int r = 0; r < 4; ++r) {
        pred[w][lhi * 4 + r][l15]       = acc00[r];
        pred[w][lhi * 4 + r][l15 + 16]  = acc01[r];
        pred[w][16 + lhi * 4 + r][l15]      = acc10[r];
        pred[w][16 + lhi * 4 + r][l15 + 16] = acc11[r];
      }
      __syncthreads();
    } else {
      const float* gp = gbase + (size_t)32 * 4096;
      #pragma unroll
      for (int g = 0; g < 4; ++g) gxn[g] = gp[g * 1024];
    }
    float pre[4];
    #pragma unroll
    for (int g = 0; g < 4; ++g) {
      float s = 0.f;
      if (t > 0) {
        int row = g * 8 + jj2;
        s = pred[0][row][bb] + pred[1][row][bb] + pred[2][row][bb] + pred[3][row][bb];
      }
      pre[g] = s;
    }
    float iv = gx[0] + pre[0] + bias_r[0];
    float fv = gx[1] + pre[1] + bias_r[1];
    float gv = gx[2] + pre[2] + bias_r[2];
    float ov = gx[3] + pre[3] + bias_r[3];
    float cc = fsigm(fv) * c_reg + fsigm(iv) * ftanh(gv);
    float hh = fsigm(ov) * ftanh(cc);
    c_reg = cc;
    store_u16_llc(hout + ((size_t)(t * 32 + bb)) * 1024 + p * 8 + jj2, f2bf(hh));
    if (t < 34) flag_barrier(flags, 128, sbase + (unsigned)t + 1u);
    #pragma unroll
    for (int g = 0; g < 4; ++g) gx[g] = gxn[g];
  }
}

// ---------------- logits GEMM (reg-prefetch + LDS dbuf) + row partials ------
template <bool BW16>
__global__ void __launch_bounds__(256, 1) gemm_logits(
    const u16* __restrict__ hist2, const u16* __restrict__ linwb,
    const float* __restrict__ lin_W, const float* __restrict__ lin_b,
    float* __restrict__ out, float2* __restrict__ partials) {
  // XCD-bijective swizzle: 9 consecutive logical tiles (one B-strip) -> one XCD
  int nwg = gridDim.x, orig = blockIdx.x;
  int q = nwg >> 3, r = nwg & 7, xcd = orig & 7, off = orig >> 3;
  int bid = (xcd < r ? xcd * (q + 1) : r * (q + 1) + (xcd - r) * q) + off;
  int bm = bid % 9, bn = bid / 9;
  int m0 = bm * 128, n0 = bn * 128;
  int tid = threadIdx.x, w = tid >> 6, lane = tid & 63, l15 = lane & 15, lhi = lane >> 4;
  int wm = w & 1, wn = w >> 1;
  __shared__ u16 As[2][128][40];
  __shared__ u16 Bs[2][128][40];
  int rowq[2], chq[2];
  const u16* asrc[2];
  const u16* bsrc16[2];
  const float* bsrc32[2];
  bool aok[2], bok[2];
  #pragma unroll
  for (int qq = 0; qq < 2; ++qq) {
    int c = tid * 2 + qq; rowq[qq] = c >> 2; chq[qq] = c & 3;
    int m = m0 + rowq[qq];
    aok[qq] = (m < kM);
    int mm = aok[qq] ? m : 0;
    asrc[qq] = hist2 + (((size_t)((mm % 35) * 32 + mm / 35)) << 10) + chq[qq] * 8;
    int n = n0 + rowq[qq];
    bok[qq] = (n < kVG);
    int nn = bok[qq] ? n : 0;
    bsrc16[qq] = linwb + ((size_t)nn << 10) + chq[qq] * 8;
    bsrc32[qq] = lin_W + ((size_t)nn << 10) + chq[qq] * 8;
  }
  uint4 av[2], bv[2];
  auto LOAD = [&](int k0) {
    #pragma unroll
    for (int qq = 0; qq < 2; ++qq) {
      uint4 a{0u, 0u, 0u, 0u};
      if (aok[qq]) a = *(const uint4*)(asrc[qq] + k0);
      av[qq] = a;
      uint4 b{0u, 0u, 0u, 0u};
      if (bok[qq]) {
        if (BW16) {
          b = *(const uint4*)(bsrc16[qq] + k0);
        } else {
          float4 f0 = *(const float4*)(bsrc32[qq] + k0);
          float4 f1 = *(const float4*)(bsrc32[qq] + k0 + 4);
          b.x = (unsigned)f2bf(f0.x) | ((unsigned)f2bf(f0.y) << 16);
          b.y = (unsigned)f2bf(f0.z) | ((unsigned)f2bf(f0.w) << 16);
          b.z = (unsigned)f2bf(f1.x) | ((unsigned)f2bf(f1.y) << 16);
          b.w = (unsigned)f2bf(f1.z) | ((unsigned)f2bf(f1.w) << 16);
        }
      }
      bv[qq] = b;
    }
  };
  f32x4 acc[4][4];
  #pragma unroll
  for (int i = 0; i < 4; ++i)
    #pragma unroll
    for (int j = 0; j < 4; ++j) { f32x4 z = {0.f, 0.f, 0.f, 0.f}; acc[i][j] = z; }

  LOAD(0);
  for (int kt = 0; kt < 32; ++kt) {
    int cur = kt & 1;
    #pragma unroll
    for (int qq = 0; qq < 2; ++qq) {
      *(uint4*)&As[cur][rowq[qq]][chq[qq] * 8] = av[qq];
      *(uint4*)&Bs[cur][rowq[qq]][chq[qq] * 8] = bv[qq];
    }
    __syncthreads();
    if (kt < 31) LOAD((kt + 1) * 32);
    short8 bfr[4];
    #pragma unroll
    for (int nt = 0; nt < 4; ++nt)
      bfr[nt] = *(const short8*)&Bs[cur][wn * 64 + nt * 16 + l15][lhi * 8];
    #pragma unroll
    for (int mt = 0; mt < 4; ++mt) {
      short8 af = *(const short8*)&As[cur][wm * 64 + mt * 16 + l15][lhi * 8];
      #pragma unroll
      for (int nt = 0; nt < 4; ++nt)
        acc[mt][nt] = mfma16(af, bfr[nt], acc[mt][nt]);
    }
  }
  // epilogue: store logits + per-(row, 64-col-group) max/sumexp partials
  float bcol[4]; int ncol[4];
  #pragma unroll
  for (int nt = 0; nt < 4; ++nt) {
    int n = n0 + wn * 64 + nt * 16 + l15;
    ncol[nt] = n;
    bcol[nt] = (n < kVG) ? lin_b[n] : -INFINITY;
  }
  #pragma unroll
  for (int mt = 0; mt < 4; ++mt) {
    #pragma unroll
    for (int r = 0; r < 4; ++r) {
      int m = m0 + wm * 64 + mt * 16 + lhi * 4 + r;
      float v0 = acc[mt][0][r] + bcol[0];
      float v1 = acc[mt][1][r] + bcol[1];
      float v2 = acc[mt][2][r] + bcol[2];
      float v3 = acc[mt][3][r] + bcol[3];
      bool mok = (m < kM);
      if (mok) {
        float* orow = out + (size_t)m * kVG;
        if (ncol[0] < kVG) orow[ncol[0]] = v0;
        if (ncol[1] < kVG) orow[ncol[1]] = v1;
        if (ncol[2] < kVG) orow[ncol[2]] = v2;
        if (ncol[3] < kVG) orow[ncol[3]] = v3;
      }
      float mx = fmaxf(fmaxf(v0, v1), fmaxf(v2, v3));
      #pragma unroll
      for (int d2 = 1; d2 < 16; d2 <<= 1) mx = fmaxf(mx, __shfl_xor(mx, d2, 64));
      float sv = 0.f;
      sv += (v0 > -1e30f) ? fexp(v0 - mx) : 0.f;
      sv += (v1 > -1e30f) ? fexp(v1 - mx) : 0.f;
      sv += (v2 > -1e30f) ? fexp(v2 - mx) : 0.f;
      sv += (v3 > -1e30f) ? fexp(v3 - mx) : 0.f;
      #pragma unroll
      for (int d2 = 1; d2 < 16; d2 <<= 1) sv += __shfl_xor(sv, d2, 64);
      if (mok && l15 == 0)
        partials[(size_t)m * 784 + bn * 2 + wn] = make_float2(mx, sv);
    }
  }
}

// ---------------- row logsumexp reduce --------------------------------------
__global__ void reduce_rows(const float2* __restrict__ partials, float* __restrict__ lse) {
  int m = blockIdx.x, tid = threadIdx.x;
  float mx = -INFINITY, s = 0.f;
  for (int j = tid; j < 782; j += 256) {
    float2 p = partials[(size_t)m * 784 + j];
    if (p.x > mx) { s = s * fexp(mx - p.x) + p.y; mx = p.x; }
    else          { s += p.y * fexp(p.x - mx); }
  }
  for (int d = 1; d < 64; d <<= 1) {
    float omx = __shfl_xor(mx, d, 64);
    float os  = __shfl_xor(s, d, 64);
    if (omx > mx) { s = s * fexp(mx - omx) + os; mx = omx; }
    else          { s += os * fexp(omx - mx); }
  }
  __shared__ float smx[4], ssum[4];
  int w = tid >> 6;
  if ((tid & 63) == 0) { smx[w] = mx; ssum[w] = s; }
  __syncthreads();
  if (tid == 0) {
    for (int i = 1; i < 4; ++i) {
      float omx = smx[i], os = ssum[i];
      if (omx > mx) { s = s * fexp(mx - omx) + os; mx = omx; }
      else          { s += os * fexp(omx - mx); }
    }
    lse[m] = mx + logf(s);
  }
}

// ---------------- in-place log_softmax subtract -----------------------------
__global__ void sub_lse(float* __restrict__ out, const float* __restrict__ lse) {
  const int total4 = 14000000;  // 1120*50000/4
  for (int i = blockIdx.x * blockDim.x + threadIdx.x; i < total4; i += gridDim.x * blockDim.x) {
    int m = i / 12500;
    float4 v = ((float4*)out)[i];
    float L = lse[m];
    v.x -= L; v.y -= L; v.z -= L; v.w -= L;
    ((float4*)out)[i] = v;
  }
}

// ---------------- launch ----------------------------------------------------
extern "C" void kernel_launch(void* const* d_in, const int* in_sizes, int n_in,
                              void* d_out, int out_size, void* d_ws, size_t ws_size,
                              hipStream_t stream) {
  const int*   x_indices  = (const int*)d_in[0];
  const int*   edge_index = (const int*)d_in[1];
  const float* X          = (const float*)d_in[2];
  const float* gat_W      = (const float*)d_in[3];
  const float* att_src    = (const float*)d_in[4];
  const float* att_dst    = (const float*)d_in[5];
  const float* gat_bias   = (const float*)d_in[6];
  const float* W_ih0      = (const float*)d_in[7];
  const float* W_ih_rest  = (const float*)d_in[8];
  const float* W_hh       = (const float*)d_in[9];
  const float* b_ih       = (const float*)d_in[10];
  const float* b_hh       = (const float*)d_in[11];
  const float* lin_W      = (const float*)d_in[12];
  const float* lin_b      = (const float*)d_in[13];
  float* out = (float*)d_out;
  char* ws = (char*)d_ws;

  unsigned* flags    = (unsigned*)(ws + OFF_BAR);
  float*    ws_src   = (float*)(ws + OFF_WSRC);
  float*    ws_dst   = (float*)(ws + OFF_WDST);
  float*    bias_sum = (float*)(ws + OFF_BIAS);
  u16*      sig      = (u16*)(ws + OFF_SIG);
  u16*      wx0      = (u16*)(ws + OFF_WX0);
  u16*      wx12     = (u16*)(ws + OFF_WX12);
  float*    gates    = (float*)(ws + OFF_GATES);
  u16*      hist     = (u16*)(ws + OFF_HIST);
  float2*   partials = (float2*)(ws + OFF_PART);
  float*    lse      = (float*)(ws + OFF_LSE);
  u16*      linwb    = (u16*)(ws + OFF_LINWB);
  u16*      whb      = (u16*)(ws + OFF_WHB);
  bool use_bw  = (ws_size >= kNeedBW);
  bool use_whb = (ws_size >= kNeedWHB);

  u16* hist0 = hist;
  u16* hist1 = hist + (size_t)35 * 32 * 1024;
  u16* hist2 = hist + (size_t)2 * 35 * 32 * 1024;

  hipMemsetAsync(ws + OFF_BAR, 0, 1024, stream);
  prep_small<<<64, 256, 0, stream>>>(gat_W, att_src, att_dst, b_ih, b_hh,
                                     ws_src, ws_dst, bias_sum);
  wx_prep<<<2048, 256, 0, stream>>>(W_ih0, W_ih_rest, W_hh, wx0, wx12,
                                    use_whb ? whb : nullptr);
  if (use_bw) wb_conv<<<2048, 256, 0, stream>>>(lin_W, linwb);
  gat_kernel<<<kG, 256, 0, stream>>>(x_indices, edge_index, X, gat_W, gat_bias,
                                     ws_src, ws_dst, sig);
  // layer 0
  gemm_ig<<<288, 256, 0, stream>>>(sig, wx0, gates, 640);
  lstm_rec<<<128, 256, 0, stream>>>(W_hh, use_whb ? whb : nullptr,
                                    gates, bias_sum, hist0, flags, 0u);
  // layer 1
  gemm_ig<<<288, 256, 0, stream>>>(hist0, wx12, gates, 1024);
  lstm_rec<<<128, 256, 0, stream>>>(W_hh + (size_t)4096 * 1024,
                                    use_whb ? whb + (size_t)4096 * 1024 : nullptr,
                                    gates, bias_sum + 4096, hist1, flags, 34u);
  // layer 2
  gemm_ig<<<288, 256, 0, stream>>>(hist1, wx12 + (size_t)4096 * 1024, gates, 1024);
  lstm_rec<<<128, 256, 0, stream>>>(W_hh + (size_t)2 * 4096 * 1024,
                                    use_whb ? whb + (size_t)2 * 4096 * 1024 : nullptr,
                                    gates, bias_sum + 8192, hist2, flags, 68u);
  // logits + log_softmax
  if (use_bw)
    gemm_logits<true><<<9 * 391, 256, 0, stream>>>(hist2, linwb, lin_W, lin_b, out, partials);
  else
    gemm_logits<false><<<9 * 391, 256, 0, stream>>>(hist2, nullptr, lin_W, lin_b, out, partials);
  reduce_rows<<<kG, 256, 0, stream>>>(partials, lse);
  sub_lse<<<2048, 256, 0, stream>>>(out, lse);
}

// Round 9
// 1168.403 us; speedup vs baseline: 1.6182x; 1.0447x over previous
//
#include <hip/hip_runtime.h>

#define DEV __device__ __forceinline__

typedef __attribute__((ext_vector_type(8))) short short8;
typedef __attribute__((ext_vector_type(4))) float f32x4;
typedef unsigned short u16;

constexpr int kV = 80000, kD = 300, kNN = 32, kEE = 64, kHH = 4, kCC = 75;
constexpr int kB = 32, kT = 35, kU = 1024, kVG = 50000;
constexpr int kG = kB * kT;          // 1120
constexpr int kM = kG;

constexpr size_t alignup(size_t x) { return (x + 255) & ~size_t(255); }
constexpr size_t OFF_BAR   = 0;       // 128 flag slots (1024 B reserved)
constexpr size_t OFF_WSRC  = 1024;
constexpr size_t OFF_WDST  = alignup(OFF_WSRC + 1200 * 4);
constexpr size_t OFF_BIAS  = alignup(OFF_WDST + 1200 * 4);
constexpr size_t OFF_SIG   = alignup(OFF_BIAS + 3 * 4096 * 4);
constexpr size_t OFF_WX0   = alignup(OFF_SIG + (size_t)35 * 32 * 640 * 2);
constexpr size_t OFF_WX12  = alignup(OFF_WX0 + (size_t)4096 * 640 * 2);
constexpr size_t OFF_GATES = alignup(OFF_WX12 + (size_t)2 * 4096 * 1024 * 2);
constexpr size_t OFF_HIST  = alignup(OFF_GATES + (size_t)1120 * 4096 * 4);
constexpr size_t OFF_PART  = alignup(OFF_HIST + (size_t)3 * 35 * 32 * 1024 * 2);
constexpr size_t OFF_LSE   = alignup(OFF_PART + (size_t)1120 * 784 * 8);
constexpr size_t OFF_LINWB = alignup(OFF_LSE + 1120 * 4);
constexpr size_t kLinWBytes = (size_t)kVG * 1024 * 2;
constexpr size_t kNeedBW   = OFF_LINWB + kLinWBytes;
constexpr size_t OFF_WHB   = alignup(OFF_LINWB + kLinWBytes);
constexpr size_t kWhbBytes = (size_t)3 * 4096 * 1024 * 2;
constexpr size_t kNeedWHB  = OFF_WHB + kWhbBytes;

DEV u16 f2bf(float f) {
  union { float f; unsigned u; } v; v.f = f;
  unsigned r = v.u + 0x7fffu + ((v.u >> 16) & 1u);
  return (u16)(r >> 16);
}
DEV float fexp(float x) { return __builtin_amdgcn_exp2f(x * 1.4426950408889634f); }
DEV float fsigm(float x) {
  float t = __builtin_amdgcn_exp2f(-1.4426950408889634f * x);
  return __builtin_amdgcn_rcpf(1.f + t);
}
DEV float ftanh(float x) {
  float xc = fminf(fmaxf(x, -20.f), 20.f);
  float t = __builtin_amdgcn_exp2f(2.8853900817779268f * xc);
  return (t - 1.f) * __builtin_amdgcn_rcpf(t + 1.f);
}
DEV f32x4 mfma16(short8 a, short8 b, f32x4 c) {
  return __builtin_amdgcn_mfma_f32_16x16x32_bf16(a, b, c, 0, 0, 0);
}
// store a bf16 directly to the coherent LLC (bypass non-coherent per-XCD L2).
DEV void store_u16_llc(u16* p, u16 v) {
  unsigned vv = v;
  asm volatile("global_store_short %0, %1, off sc0 sc1"
               :: "v"(p), "v"(vv) : "memory");
}
// async global->LDS DMA, 16B/lane, LDS dst = wave-uniform base + lane*16
DEV void gll16(const void* g, void* l) {
  __builtin_amdgcn_global_load_lds(
      (const __attribute__((address_space(1))) unsigned int*)g,
      (__attribute__((address_space(3))) unsigned int*)l, 16, 0, 0);
}

// ---------------- prep: ws_src/ws_dst (W @ att vectors), bias sums ----------
__global__ void prep_small(const float* __restrict__ gat_W,
                           const float* __restrict__ att_src,
                           const float* __restrict__ att_dst,
                           const float* __restrict__ b_ih,
                           const float* __restrict__ b_hh,
                           float* __restrict__ ws_src, float* __restrict__ ws_dst,
                           float* __restrict__ bias_sum) {
  int total = 1200 + 1200 + 3 * 4096;
  for (int i = blockIdx.x * blockDim.x + threadIdx.x; i < total; i += gridDim.x * blockDim.x) {
    if (i < 1200) {
      int d = i >> 2, h = i & 3;
      float s = 0.f;
      for (int c = 0; c < kCC; ++c) s += gat_W[d * 300 + h * kCC + c] * att_src[h * kCC + c];
      ws_src[i] = s;
    } else if (i < 2400) {
      int j = i - 1200; int d = j >> 2, h = j & 3;
      float s = 0.f;
      for (int c = 0; c < kCC; ++c) s += gat_W[d * 300 + h * kCC + c] * att_dst[h * kCC + c];
      ws_dst[j] = s;
    } else {
      int j = i - 2400;
      bias_sum[j] = b_ih[j] + b_hh[j];
    }
  }
}

// ---------------- prep: bf16 weights (W_ih0, W_ih_rest, W_hh) ---------------
__global__ void wx_prep(const float* __restrict__ W_ih0,
                        const float* __restrict__ W_ih_rest,
                        const float* __restrict__ W_hh,
                        u16* __restrict__ wx0, u16* __restrict__ wx12,
                        u16* __restrict__ whb) {
  const int n0 = 4096 * 640;
  const int n12 = 2 * 4096 * 1024;
  const int nhh = 3 * 4096 * 1024;
  int total = n0 + n12 + nhh;
  for (int i = blockIdx.x * blockDim.x + threadIdx.x; i < total; i += gridDim.x * blockDim.x) {
    if (i < n0) {
      int row = i / 640, col = i - row * 640;
      float v = (col < 600) ? W_ih0[row * 600 + col] : 0.f;
      wx0[i] = f2bf(v);
    } else if (i < n0 + n12) {
      int j = i - n0;
      wx12[j] = f2bf(W_ih_rest[j]);
    } else {
      int j = i - n0 - n12;
      if (whb) whb[j] = f2bf(W_hh[j]);
    }
  }
}

// ---------------- prep: bf16 copy of lin_W ----------------------------------
__global__ void wb_conv(const float* __restrict__ W, u16* __restrict__ Wb) {
  const long n = (long)kVG * 1024;
  long stride = (long)gridDim.x * blockDim.x * 8;
  for (long i = (long)(blockIdx.x * blockDim.x + threadIdx.x) * 8; i < n; i += stride) {
    float4 a = *(const float4*)(W + i);
    float4 b = *(const float4*)(W + i + 4);
    u16 t[8] = {f2bf(a.x), f2bf(a.y), f2bf(a.z), f2bf(a.w),
                f2bf(b.x), f2bf(b.y), f2bf(b.z), f2bf(b.w)};
    *(uint4*)(Wb + i) = *(const uint4*)t;
  }
}

// ---------------- GAT (node-0 only, factored attention) ---------------------
__global__ void __launch_bounds__(256) gat_kernel(
    const int* __restrict__ x_indices, const int* __restrict__ edge_index,
    const float* __restrict__ X, const float* __restrict__ gat_W,
    const float* __restrict__ gat_bias, const float* __restrict__ ws_src,
    const float* __restrict__ ws_dst, u16* __restrict__ sig) {
  __shared__ float xs[32][301];
  __shared__ float a_s[32][4];
  __shared__ float a_d0[4];
  __shared__ float alpha[4][32];
  __shared__ float xw[4][301];
  __shared__ int allowed[32];
  int g = blockIdx.x, tid = threadIdx.x;
  const int* idx = x_indices + g * 32;
  for (int i = tid; i < 32 * 300; i += 256) {
    int j = i / 300, d2 = i - j * 300;
    xs[j][d2] = X[(size_t)idx[j] * 300 + d2];
  }
  if (tid < 32) allowed[tid] = (tid == 0) ? 1 : 0;
  __syncthreads();
  if (tid < 128) {
    int j = tid >> 2, h = tid & 3;
    float s = 0.f;
    for (int d2 = 0; d2 < 300; ++d2) s += xs[j][d2] * ws_src[d2 * 4 + h];
    a_s[j][h] = s;
  } else if (tid < 132) {
    int h = tid - 128; float s = 0.f;
    for (int d2 = 0; d2 < 300; ++d2) s += xs[0][d2] * ws_dst[d2 * 4 + h];
    a_d0[h] = s;
  } else if (tid >= 192) {
    int e = tid - 192;
    int src = edge_index[g * 128 + e];
    int dst = edge_index[g * 128 + 64 + e];
    if (dst == 0) allowed[src] = 1;
  }
  __syncthreads();
  if (tid < 4) {
    int h = tid;
    float ev[32];
    float mx = -1e30f;
    #pragma unroll
    for (int j = 0; j < 32; ++j) {
      float v = a_d0[h] + a_s[j][h];
      v = (v > 0.f) ? v : 0.2f * v;
      v = allowed[j] ? v : -1e9f;
      ev[j] = v; mx = fmaxf(mx, v);
    }
    float ssum = 0.f;
    #pragma unroll
    for (int j = 0; j < 32; ++j) { float p = fexp(ev[j] - mx); ev[j] = p; ssum += p; }
    float inv = 1.f / ssum;
    #pragma unroll
    for (int j = 0; j < 32; ++j) alpha[h][j] = ev[j] * inv;
  }
  __syncthreads();
  for (int i = tid; i < 4 * 300; i += 256) {
    int h = i / 300, d2 = i - h * 300;
    float s = 0.f;
    #pragma unroll
    for (int j = 0; j < 32; ++j) s += alpha[h][j] * xs[j][d2];
    xw[h][d2] = s;
  }
  __syncthreads();
  int t = g % 35, b = g / 35;
  u16* srow = sig + ((size_t)t * 32 + b) * 640;
  for (int hc = tid; hc < 300; hc += 256) {
    srow[hc] = f2bf(xs[0][hc]);           // curr_emb = X[idx 0]
    int h = hc / 75;
    float s = gat_bias[hc];
    for (int d2 = 0; d2 < 300; ++d2) s += xw[h][d2] * gat_W[d2 * 300 + hc];
    srow[300 + hc] = f2bf(s);
  }
  for (int i2 = 600 + tid; i2 < 640; i2 += 256) srow[i2] = 0;  // zero pad
}

// ---------------- fence-free flag barrier (LLC-direct h stores) -------------
DEV void flag_barrier(unsigned* flags, int nb, unsigned s) {
  __syncthreads();   // implies vmcnt drain: h stores complete at LLC
  if (threadIdx.x == 0)
    __hip_atomic_store(flags + blockIdx.x, s, __ATOMIC_RELAXED, __HIP_MEMORY_SCOPE_AGENT);
  if (threadIdx.x < 64) {
    for (int j = threadIdx.x; j < nb; j += 64) {
      while (__hip_atomic_load(flags + j, __ATOMIC_RELAXED, __HIP_MEMORY_SCOPE_AGENT) < s)
        __builtin_amdgcn_s_sleep(1);
    }
  }
  __syncthreads();
}

// ---------------- bulk input-gate GEMM (global_load_lds staging, m97) -------
// gates written INTERLEAVED: gates[m][u*4+g]  (one float4 per (m,unit))
__global__ void __launch_bounds__(256, 1) gemm_ig(
    const u16* __restrict__ A, const u16* __restrict__ Bw,
    float* __restrict__ gates, int K) {
  int bid = blockIdx.x;
  int bm = bid % 9, bn = bid / 9;
  int m0 = bm * 128, n0 = bn * 128;
  int tid = threadIdx.x, w = tid >> 6, lane = tid & 63, l15 = lane & 15, lhi = lane >> 4;
  int wm = w & 1, wn = w >> 1;
  __shared__ u16 As[128][32];
  __shared__ u16 Bs[128][32];
  // per-lane source row pointers (k-independent part)
  int am0 = m0 + w * 32 + (lane >> 2);
  int am1 = am0 + 16;
  const u16* arow0 = A + (size_t)((am0 < kM) ? am0 : 0) * K + (lane & 3) * 8;
  const u16* arow1 = A + (size_t)((am1 < kM) ? am1 : 0) * K + (lane & 3) * 8;
  int bn0r = n0 + w * 32 + (lane >> 2);
  const u16* brow0 = Bw + (size_t)bn0r * K + (lane & 3) * 8;
  const u16* brow1 = Bw + (size_t)(bn0r + 16) * K + (lane & 3) * 8;
  u16* lA0 = &As[w * 32][0];      u16* lA1 = &As[w * 32 + 16][0];
  u16* lB0 = &Bs[w * 32][0];      u16* lB1 = &Bs[w * 32 + 16][0];

  f32x4 acc[4][4];
  #pragma unroll
  for (int i = 0; i < 4; ++i)
    #pragma unroll
    for (int j = 0; j < 4; ++j) { f32x4 z = {0.f, 0.f, 0.f, 0.f}; acc[i][j] = z; }

  int nkt = K >> 5;
  for (int kt = 0; kt < nkt; ++kt) {
    int k0 = kt * 32;
    gll16(arow0 + k0, lA0);
    gll16(arow1 + k0, lA1);
    gll16(brow0 + k0, lB0);
    gll16(brow1 + k0, lB1);
    asm volatile("s_waitcnt vmcnt(0)" ::: "memory");
    __syncthreads();
    short8 bfr[4];
    #pragma unroll
    for (int nt = 0; nt < 4; ++nt)
      bfr[nt] = *(const short8*)&Bs[wn * 64 + nt * 16 + l15][lhi * 8];
    #pragma unroll
    for (int mt = 0; mt < 4; ++mt) {
      short8 af = *(const short8*)&As[wm * 64 + mt * 16 + l15][lhi * 8];
      #pragma unroll
      for (int nt = 0; nt < 4; ++nt)
        acc[mt][nt] = mfma16(af, bfr[nt], acc[mt][nt]);
    }
    __syncthreads();
  }
  #pragma unroll
  for (int mt = 0; mt < 4; ++mt) {
    #pragma unroll
    for (int r = 0; r < 4; ++r) {
      int m = m0 + wm * 64 + mt * 16 + lhi * 4 + r;
      if (m < kM) {
        float* orow = gates + (size_t)m * 4096;
        #pragma unroll
        for (int nt = 0; nt < 4; ++nt) {
          int n = n0 + wn * 64 + nt * 16 + l15;
          orow[(n & 1023) * 4 + (n >> 10)] = acc[mt][nt][r];
        }
      }
    }
  }
}

// ---------------- LSTM recurrence: 128 blocks x 8 units ---------------------
__global__ void __launch_bounds__(256, 1) lstm_rec(
    const float* __restrict__ W_hh_l,   // [4096][1024] fp32, this layer
    const u16* __restrict__ whb_l,      // bf16 copy (may be null)
    const float* __restrict__ gates,    // [1120][1024][4] f32 interleaved
    const float* __restrict__ bias_l,   // [4096]
    u16* __restrict__ hout,             // [35*32][1024] bf16
    unsigned* flags, unsigned sbase) {
  const int p = blockIdx.x;             // 0..127
  const int tid = threadIdx.x;
  const int w = tid >> 6, lane = tid & 63, l15 = lane & 15, lhi = lane >> 4;
  __shared__ u16 whs[32][1032];         // rows: idx = g*8+jj -> global g*1024+8p+jj
  __shared__ float pred[4][32][33];     // [wave][w-row][batch]
  if (whb_l) {
    for (int i = tid; i < 32 * 128; i += 256) {
      int row = i >> 7, seg = i & 127;
      int g = row >> 3, jj = row & 7;
      uint4 v = *(const uint4*)(whb_l + (((size_t)(g * 1024 + p * 8 + jj)) << 10) + seg * 8);
      *(uint4*)&whs[row][seg * 8] = v;
    }
  } else {
    for (int i = tid; i < 32 * 256; i += 256) {
      int row = i >> 8, seg = i & 255;
      int g = row >> 3, jj = row & 7;
      const float* src = W_hh_l + (((size_t)(g * 1024 + p * 8 + jj)) << 10) + seg * 4;
      float4 f = *(const float4*)src;
      u16 tmp[4] = {f2bf(f.x), f2bf(f.y), f2bf(f.z), f2bf(f.w)};
      *(uint2*)&whs[row][seg * 4] = *(const uint2*)tmp;
    }
  }
  const int bb = tid >> 3, jj2 = tid & 7;
  float bias_r[4];
  #pragma unroll
  for (int g = 0; g < 4; ++g) bias_r[g] = bias_l[g * 1024 + p * 8 + jj2];
  float c_reg = 0.f;
  const int kbase = w * 256;
  const float4* gb4 = (const float4*)gates + (size_t)bb * 1024 + (p * 8 + jj2);

  // prefetch gx for t=0
  float4 gx = gb4[0];

  for (int t = 0; t < 35; ++t) {
    float4 gxn;
    if (t > 0) {
      const u16* hp = hout + (size_t)(t - 1) * 32 * 1024;
      const u16* hrow0 = hp + l15 * 1024 + lhi * 8;
      const u16* hrow1 = hp + (l15 + 16) * 1024 + lhi * 8;
      f32x4 acc00 = {0,0,0,0}, acc01 = {0,0,0,0}, acc10 = {0,0,0,0}, acc11 = {0,0,0,0};
      #pragma unroll
      for (int kk = 0; kk < 8; ++kk) {
        int k = kbase + kk * 32;
        short8 bf0 = *(const short8*)(hrow0 + k);
        short8 bf1 = *(const short8*)(hrow1 + k);
        short8 af0 = *(const short8*)&whs[l15][k + lhi * 8];
        short8 af1 = *(const short8*)&whs[16 + l15][k + lhi * 8];
        acc00 = mfma16(af0, bf0, acc00);
        acc01 = mfma16(af0, bf1, acc01);
        acc10 = mfma16(af1, bf0, acc10);
        acc11 = mfma16(af1, bf1, acc11);
      }
      if (t < 34) gxn = gb4[(size_t)(t + 1) * 32768 / 32 * 32];  // (t+1)*32*1024
      #pragma unroll
      for (int r = 0; r < 4; ++r) {
        pred[w][lhi * 4 + r][l15]       = acc00[r];
        pred[w][lhi * 4 + r][l15 + 16]  = acc01[r];
        pred[w][16 + lhi * 4 + r][l15]      = acc10[r];
        pred[w][16 + lhi * 4 + r][l15 + 16] = acc11[r];
      }
      __syncthreads();
    } else {
      gxn = gb4[(size_t)32 * 1024];
    }
    float pre[4];
    #pragma unroll
    for (int g = 0; g < 4; ++g) {
      float s = 0.f;
      if (t > 0) {
        int row = g * 8 + jj2;
        s = pred[0][row][bb] + pred[1][row][bb] + pred[2][row][bb] + pred[3][row][bb];
      }
      pre[g] = s;
    }
    float iv = gx.x + pre[0] + bias_r[0];
    float fv = gx.y + pre[1] + bias_r[1];
    float gv = gx.z + pre[2] + bias_r[2];
    float ov = gx.w + pre[3] + bias_r[3];
    float cc = fsigm(fv) * c_reg + fsigm(iv) * ftanh(gv);
    float hh = fsigm(ov) * ftanh(cc);
    c_reg = cc;
    store_u16_llc(hout + ((size_t)(t * 32 + bb)) * 1024 + p * 8 + jj2, f2bf(hh));
    if (t < 34) flag_barrier(flags, 128, sbase + (unsigned)t + 1u);
    gx = gxn;
  }
}

// ---------------- logits GEMM (global_load_lds staging) + row partials ------
DEV void logits_epilogue(f32x4 (&acc)[4][4], int m0, int n0, int wm, int wn,
                         int l15, int lhi, const float* lin_b,
                         float* out, float2* partials, int bn) {
  float bcol[4]; int ncol[4];
  #pragma unroll
  for (int nt = 0; nt < 4; ++nt) {
    int n = n0 + wn * 64 + nt * 16 + l15;
    ncol[nt] = n;
    bcol[nt] = (n < kVG) ? lin_b[n] : -INFINITY;
  }
  #pragma unroll
  for (int mt = 0; mt < 4; ++mt) {
    #pragma unroll
    for (int r = 0; r < 4; ++r) {
      int m = m0 + wm * 64 + mt * 16 + lhi * 4 + r;
      float v0 = acc[mt][0][r] + bcol[0];
      float v1 = acc[mt][1][r] + bcol[1];
      float v2 = acc[mt][2][r] + bcol[2];
      float v3 = acc[mt][3][r] + bcol[3];
      bool mok = (m < kM);
      if (mok) {
        float* orow = out + (size_t)m * kVG;
        if (ncol[0] < kVG) orow[ncol[0]] = v0;
        if (ncol[1] < kVG) orow[ncol[1]] = v1;
        if (ncol[2] < kVG) orow[ncol[2]] = v2;
        if (ncol[3] < kVG) orow[ncol[3]] = v3;
      }
      float mx = fmaxf(fmaxf(v0, v1), fmaxf(v2, v3));
      #pragma unroll
      for (int d2 = 1; d2 < 16; d2 <<= 1) mx = fmaxf(mx, __shfl_xor(mx, d2, 64));
      float sv = 0.f;
      sv += (v0 > -1e30f) ? fexp(v0 - mx) : 0.f;
      sv += (v1 > -1e30f) ? fexp(v1 - mx) : 0.f;
      sv += (v2 > -1e30f) ? fexp(v2 - mx) : 0.f;
      sv += (v3 > -1e30f) ? fexp(v3 - mx) : 0.f;
      #pragma unroll
      for (int d2 = 1; d2 < 16; d2 <<= 1) sv += __shfl_xor(sv, d2, 64);
      if (mok && l15 == 0)
        partials[(size_t)m * 784 + bn * 2 + wn] = make_float2(mx, sv);
    }
  }
}

__global__ void __launch_bounds__(256, 1) gemm_logits_async(
    const u16* __restrict__ hist2, const u16* __restrict__ linwb,
    const float* __restrict__ lin_b, float* __restrict__ out,
    float2* __restrict__ partials) {
  // XCD-bijective swizzle
  int nwg = gridDim.x, orig = blockIdx.x;
  int q = nwg >> 3, r = nwg & 7, xcd = orig & 7, off = orig >> 3;
  int bid = (xcd < r ? xcd * (q + 1) : r * (q + 1) + (xcd - r) * q) + off;
  int bm = bid % 9, bn = bid / 9;
  int m0 = bm * 128, n0 = bn * 128;
  int tid = threadIdx.x, w = tid >> 6, lane = tid & 63, l15 = lane & 15, lhi = lane >> 4;
  int wm = w & 1, wn = w >> 1;
  __shared__ u16 As[128][32];
  __shared__ u16 Bs[128][32];
  int am0 = m0 + w * 32 + (lane >> 2);
  int am1 = am0 + 16;
  int mm0 = (am0 < kM) ? am0 : 0, mm1 = (am1 < kM) ? am1 : 0;
  const u16* arow0 = hist2 + (((size_t)((mm0 % 35) * 32 + mm0 / 35)) << 10) + (lane & 3) * 8;
  const u16* arow1 = hist2 + (((size_t)((mm1 % 35) * 32 + mm1 / 35)) << 10) + (lane & 3) * 8;
  int nr0 = n0 + w * 32 + (lane >> 2);
  int nn0 = (nr0 < kVG) ? nr0 : 0, nn1 = (nr0 + 16 < kVG) ? nr0 + 16 : 0;
  const u16* brow0 = linwb + ((size_t)nn0 << 10) + (lane & 3) * 8;
  const u16* brow1 = linwb + ((size_t)nn1 << 10) + (lane & 3) * 8;
  u16* lA0 = &As[w * 32][0];      u16* lA1 = &As[w * 32 + 16][0];
  u16* lB0 = &Bs[w * 32][0];      u16* lB1 = &Bs[w * 32 + 16][0];

  f32x4 acc[4][4];
  #pragma unroll
  for (int i = 0; i < 4; ++i)
    #pragma unroll
    for (int j = 0; j < 4; ++j) { f32x4 z = {0.f, 0.f, 0.f, 0.f}; acc[i][j] = z; }

  for (int kt = 0; kt < 32; ++kt) {
    int k0 = kt * 32;
    gll16(arow0 + k0, lA0);
    gll16(arow1 + k0, lA1);
    gll16(brow0 + k0, lB0);
    gll16(brow1 + k0, lB1);
    asm volatile("s_waitcnt vmcnt(0)" ::: "memory");
    __syncthreads();
    short8 bfr[4];
    #pragma unroll
    for (int nt = 0; nt < 4; ++nt)
      bfr[nt] = *(const short8*)&Bs[wn * 64 + nt * 16 + l15][lhi * 8];
    #pragma unroll
    for (int mt = 0; mt < 4; ++mt) {
      short8 af = *(const short8*)&As[wm * 64 + mt * 16 + l15][lhi * 8];
      #pragma unroll
      for (int nt = 0; nt < 4; ++nt)
        acc[mt][nt] = mfma16(af, bfr[nt], acc[mt][nt]);
    }
    __syncthreads();
  }
  logits_epilogue(acc, m0, n0, wm, wn, l15, lhi, lin_b, out, partials, bn);
}

// fallback (no bf16 workspace image): reg-staged, fp32 B inline-converted
__global__ void __launch_bounds__(256, 1) gemm_logits_fb(
    const u16* __restrict__ hist2, const float* __restrict__ lin_W,
    const float* __restrict__ lin_b, float* __restrict__ out,
    float2* __restrict__ partials) {
  int nwg = gridDim.x, orig = blockIdx.x;
  int q = nwg >> 3, r = nwg & 7, xcd = orig & 7, off = orig >> 3;
  int bid = (xcd < r ? xcd * (q + 1) : r * (q + 1) + (xcd - r) * q) + off;
  int bm = bid % 9, bn = bid / 9;
  int m0 = bm * 128, n0 = bn * 128;
  int tid = threadIdx.x, w = tid >> 6, lane = tid & 63, l15 = lane & 15, lhi = lane >> 4;
  int wm = w & 1, wn = w >> 1;
  __shared__ u16 As[128][40];
  __shared__ u16 Bs[128][40];
  f32x4 acc[4][4];
  #pragma unroll
  for (int i = 0; i < 4; ++i)
    #pragma unroll
    for (int j = 0; j < 4; ++j) { f32x4 z = {0.f, 0.f, 0.f, 0.f}; acc[i][j] = z; }
  for (int kt = 0; kt < 32; ++kt) {
    int k0 = kt * 32;
    #pragma unroll
    for (int q2 = 0; q2 < 2; ++q2) {
      int c = tid * 2 + q2; int row = c >> 2; int ch = c & 3;
      int m = m0 + row;
      uint4 av{0u, 0u, 0u, 0u};
      if (m < kM) {
        int b = m / 35; int t = m - b * 35;
        av = *(const uint4*)(hist2 + ((size_t)(t * 32 + b) << 10) + k0 + ch * 8);
      }
      *(uint4*)&As[row][ch * 8] = av;
      int n = n0 + row;
      uint4 bv{0u, 0u, 0u, 0u};
      if (n < kVG) {
        const float* src = lin_W + (size_t)n * 1024 + k0 + ch * 8;
        float4 f0 = *(const float4*)(src);
        float4 f1 = *(const float4*)(src + 4);
        bv.x = (unsigned)f2bf(f0.x) | ((unsigned)f2bf(f0.y) << 16);
        bv.y = (unsigned)f2bf(f0.z) | ((unsigned)f2bf(f0.w) << 16);
        bv.z = (unsigned)f2bf(f1.x) | ((unsigned)f2bf(f1.y) << 16);
        bv.w = (unsigned)f2bf(f1.z) | ((unsigned)f2bf(f1.w) << 16);
      }
      *(uint4*)&Bs[row][ch * 8] = bv;
    }
    __syncthreads();
    short8 bfr[4];
    #pragma unroll
    for (int nt = 0; nt < 4; ++nt)
      bfr[nt] = *(const short8*)&Bs[wn * 64 + nt * 16 + l15][lhi * 8];
    #pragma unroll
    for (int mt = 0; mt < 4; ++mt) {
      short8 af = *(const short8*)&As[wm * 64 + mt * 16 + l15][lhi * 8];
      #pragma unroll
      for (int nt = 0; nt < 4; ++nt)
        acc[mt][nt] = mfma16(af, bfr[nt], acc[mt][nt]);
    }
    __syncthreads();
  }
  logits_epilogue(acc, m0, n0, wm, wn, l15, lhi, lin_b, out, partials, bn);
}

// ---------------- row logsumexp reduce --------------------------------------
__global__ void reduce_rows(const float2* __restrict__ partials, float* __restrict__ lse) {
  int m = blockIdx.x, tid = threadIdx.x;
  float mx = -INFINITY, s = 0.f;
  for (int j = tid; j < 782; j += 256) {
    float2 p = partials[(size_t)m * 784 + j];
    if (p.x > mx) { s = s * fexp(mx - p.x) + p.y; mx = p.x; }
    else          { s += p.y * fexp(p.x - mx); }
  }
  for (int d = 1; d < 64; d <<= 1) {
    float omx = __shfl_xor(mx, d, 64);
    float os  = __shfl_xor(s, d, 64);
    if (omx > mx) { s = s * fexp(mx - omx) + os; mx = omx; }
    else          { s += os * fexp(omx - mx); }
  }
  __shared__ float smx[4], ssum[4];
  int w = tid >> 6;
  if ((tid & 63) == 0) { smx[w] = mx; ssum[w] = s; }
  __syncthreads();
  if (tid == 0) {
    for (int i = 1; i < 4; ++i) {
      float omx = smx[i], os = ssum[i];
      if (omx > mx) { s = s * fexp(mx - omx) + os; mx = omx; }
      else          { s += os * fexp(omx - mx); }
    }
    lse[m] = mx + logf(s);
  }
}

// ---------------- in-place log_softmax subtract -----------------------------
__global__ void sub_lse(float* __restrict__ out, const float* __restrict__ lse) {
  const int total4 = 14000000;  // 1120*50000/4
  for (int i = blockIdx.x * blockDim.x + threadIdx.x; i < total4; i += gridDim.x * blockDim.x) {
    int m = i / 12500;
    float4 v = ((float4*)out)[i];
    float L = lse[m];
    v.x -= L; v.y -= L; v.z -= L; v.w -= L;
    ((float4*)out)[i] = v;
  }
}

// ---------------- launch ----------------------------------------------------
extern "C" void kernel_launch(void* const* d_in, const int* in_sizes, int n_in,
                              void* d_out, int out_size, void* d_ws, size_t ws_size,
                              hipStream_t stream) {
  const int*   x_indices  = (const int*)d_in[0];
  const int*   edge_index = (const int*)d_in[1];
  const float* X          = (const float*)d_in[2];
  const float* gat_W      = (const float*)d_in[3];
  const float* att_src    = (const float*)d_in[4];
  const float* att_dst    = (const float*)d_in[5];
  const float* gat_bias   = (const float*)d_in[6];
  const float* W_ih0      = (const float*)d_in[7];
  const float* W_ih_rest  = (const float*)d_in[8];
  const float* W_hh       = (const float*)d_in[9];
  const float* b_ih       = (const float*)d_in[10];
  const float* b_hh       = (const float*)d_in[11];
  const float* lin_W      = (const float*)d_in[12];
  const float* lin_b      = (const float*)d_in[13];
  float* out = (float*)d_out;
  char* ws = (char*)d_ws;

  unsigned* flags    = (unsigned*)(ws + OFF_BAR);
  float*    ws_src   = (float*)(ws + OFF_WSRC);
  float*    ws_dst   = (float*)(ws + OFF_WDST);
  float*    bias_sum = (float*)(ws + OFF_BIAS);
  u16*      sig      = (u16*)(ws + OFF_SIG);
  u16*      wx0      = (u16*)(ws + OFF_WX0);
  u16*      wx12     = (u16*)(ws + OFF_WX12);
  float*    gates    = (float*)(ws + OFF_GATES);
  u16*      hist     = (u16*)(ws + OFF_HIST);
  float2*   partials = (float2*)(ws + OFF_PART);
  float*    lse      = (float*)(ws + OFF_LSE);
  u16*      linwb    = (u16*)(ws + OFF_LINWB);
  u16*      whb      = (u16*)(ws + OFF_WHB);
  bool use_bw  = (ws_size >= kNeedBW);
  bool use_whb = (ws_size >= kNeedWHB);

  u16* hist0 = hist;
  u16* hist1 = hist + (size_t)35 * 32 * 1024;
  u16* hist2 = hist + (size_t)2 * 35 * 32 * 1024;

  hipMemsetAsync(ws + OFF_BAR, 0, 1024, stream);
  prep_small<<<64, 256, 0, stream>>>(gat_W, att_src, att_dst, b_ih, b_hh,
                                     ws_src, ws_dst, bias_sum);
  wx_prep<<<2048, 256, 0, stream>>>(W_ih0, W_ih_rest, W_hh, wx0, wx12,
                                    use_whb ? whb : nullptr);
  if (use_bw) wb_conv<<<2048, 256, 0, stream>>>(lin_W, linwb);
  gat_kernel<<<kG, 256, 0, stream>>>(x_indices, edge_index, X, gat_W, gat_bias,
                                     ws_src, ws_dst, sig);
  // layer 0
  gemm_ig<<<288, 256, 0, stream>>>(sig, wx0, gates, 640);
  lstm_rec<<<128, 256, 0, stream>>>(W_hh, use_whb ? whb : nullptr,
                                    gates, bias_sum, hist0, flags, 0u);
  // layer 1
  gemm_ig<<<288, 256, 0, stream>>>(hist0, wx12, gates, 1024);
  lstm_rec<<<128, 256, 0, stream>>>(W_hh + (size_t)4096 * 1024,
                                    use_whb ? whb + (size_t)4096 * 1024 : nullptr,
                                    gates, bias_sum + 4096, hist1, flags, 34u);
  // layer 2
  gemm_ig<<<288, 256, 0, stream>>>(hist1, wx12 + (size_t)4096 * 1024, gates, 1024);
  lstm_rec<<<128, 256, 0, stream>>>(W_hh + (size_t)2 * 4096 * 1024,
                                    use_whb ? whb + (size_t)2 * 4096 * 1024 : nullptr,
                                    gates, bias_sum + 8192, hist2, flags, 68u);
  // logits + log_softmax
  if (use_bw)
    gemm_logits_async<<<9 * 391, 256, 0, stream>>>(hist2, linwb, lin_b, out, partials);
  else
    gemm_logits_fb<<<9 * 391, 256, 0, stream>>>(hist2, lin_W, lin_b, out, partials);
  reduce_rows<<<kG, 256, 0, stream>>>(partials, lse);
  sub_lse<<<2048, 256, 0, stream>>>(out, lse);
}

// Round 10
// 1139.739 us; speedup vs baseline: 1.6589x; 1.0251x over previous
//
#include <hip/hip_runtime.h>

#define DEV __device__ __forceinline__

typedef __attribute__((ext_vector_type(8))) short short8;
typedef __attribute__((ext_vector_type(4))) float f32x4;
typedef unsigned short u16;

constexpr int kV = 80000, kD = 300, kNN = 32, kEE = 64, kHH = 4, kCC = 75;
constexpr int kB = 32, kT = 35, kU = 1024, kVG = 50000;
constexpr int kG = kB * kT;          // 1120
constexpr int kM = kG;

constexpr size_t alignup(size_t x) { return (x + 255) & ~size_t(255); }
constexpr size_t OFF_BAR   = 0;       // 128 flag slots (1024 B reserved)
constexpr size_t OFF_WSRC  = 1024;
constexpr size_t OFF_WDST  = alignup(OFF_WSRC + 1200 * 4);
constexpr size_t OFF_BIAS  = alignup(OFF_WDST + 1200 * 4);
constexpr size_t OFF_SIG   = alignup(OFF_BIAS + 3 * 4096 * 4);
constexpr size_t OFF_WX0   = alignup(OFF_SIG + (size_t)35 * 32 * 640 * 2);
constexpr size_t OFF_WX12  = alignup(OFF_WX0 + (size_t)4096 * 640 * 2);
constexpr size_t OFF_GATES = alignup(OFF_WX12 + (size_t)2 * 4096 * 1024 * 2);
constexpr size_t OFF_HIST  = alignup(OFF_GATES + (size_t)1120 * 4096 * 4);
constexpr size_t OFF_PART  = alignup(OFF_HIST + (size_t)3 * 35 * 32 * 1024 * 2);
constexpr size_t OFF_LSE   = alignup(OFF_PART + (size_t)1120 * 784 * 8);
constexpr size_t OFF_LINWB = alignup(OFF_LSE + 1120 * 4);
constexpr size_t kLinWBytes = (size_t)kVG * 1024 * 2;
constexpr size_t kNeedBW   = OFF_LINWB + kLinWBytes;
constexpr size_t OFF_WHB   = alignup(OFF_LINWB + kLinWBytes);
constexpr size_t kWhbBytes = (size_t)3 * 4096 * 1024 * 2;
constexpr size_t kNeedWHB  = OFF_WHB + kWhbBytes;

DEV u16 f2bf(float f) {
  union { float f; unsigned u; } v; v.f = f;
  unsigned r = v.u + 0x7fffu + ((v.u >> 16) & 1u);
  return (u16)(r >> 16);
}
DEV float fexp(float x) { return __builtin_amdgcn_exp2f(x * 1.4426950408889634f); }
DEV float fsigm(float x) {
  float t = __builtin_amdgcn_exp2f(-1.4426950408889634f * x);
  return __builtin_amdgcn_rcpf(1.f + t);
}
DEV float ftanh(float x) {
  float xc = fminf(fmaxf(x, -20.f), 20.f);
  float t = __builtin_amdgcn_exp2f(2.8853900817779268f * xc);
  return (t - 1.f) * __builtin_amdgcn_rcpf(t + 1.f);
}
DEV f32x4 mfma16(short8 a, short8 b, f32x4 c) {
  return __builtin_amdgcn_mfma_f32_16x16x32_bf16(a, b, c, 0, 0, 0);
}
// store a bf16 directly to the coherent LLC (bypass non-coherent per-XCD L2).
DEV void store_u16_llc(u16* p, u16 v) {
  unsigned vv = v;
  asm volatile("global_store_short %0, %1, off sc0 sc1"
               :: "v"(p), "v"(vv) : "memory");
}
// async global->LDS DMA, 16B/lane, LDS dst = wave-uniform base + lane*16
DEV void gll16(const void* g, void* l) {
  __builtin_amdgcn_global_load_lds(
      (const __attribute__((address_space(1))) unsigned int*)g,
      (__attribute__((address_space(3))) unsigned int*)l, 16, 0, 0);
}

// ---------------- prep: ws_src/ws_dst (W @ att vectors), bias sums ----------
__global__ void prep_small(const float* __restrict__ gat_W,
                           const float* __restrict__ att_src,
                           const float* __restrict__ att_dst,
                           const float* __restrict__ b_ih,
                           const float* __restrict__ b_hh,
                           float* __restrict__ ws_src, float* __restrict__ ws_dst,
                           float* __restrict__ bias_sum) {
  int total = 1200 + 1200 + 3 * 4096;
  for (int i = blockIdx.x * blockDim.x + threadIdx.x; i < total; i += gridDim.x * blockDim.x) {
    if (i < 1200) {
      int d = i >> 2, h = i & 3;
      float s = 0.f;
      for (int c = 0; c < kCC; ++c) s += gat_W[d * 300 + h * kCC + c] * att_src[h * kCC + c];
      ws_src[i] = s;
    } else if (i < 2400) {
      int j = i - 1200; int d = j >> 2, h = j & 3;
      float s = 0.f;
      for (int c = 0; c < kCC; ++c) s += gat_W[d * 300 + h * kCC + c] * att_dst[h * kCC + c];
      ws_dst[j] = s;
    } else {
      int j = i - 2400;
      bias_sum[j] = b_ih[j] + b_hh[j];
    }
  }
}

// ---------------- prep: bf16 weights (W_ih0, W_ih_rest, W_hh) ---------------
__global__ void wx_prep(const float* __restrict__ W_ih0,
                        const float* __restrict__ W_ih_rest,
                        const float* __restrict__ W_hh,
                        u16* __restrict__ wx0, u16* __restrict__ wx12,
                        u16* __restrict__ whb) {
  const int n0 = 4096 * 640;
  const int n12 = 2 * 4096 * 1024;
  const int nhh = 3 * 4096 * 1024;
  int total = n0 + n12 + nhh;
  for (int i = blockIdx.x * blockDim.x + threadIdx.x; i < total; i += gridDim.x * blockDim.x) {
    if (i < n0) {
      int row = i / 640, col = i - row * 640;
      float v = (col < 600) ? W_ih0[row * 600 + col] : 0.f;
      wx0[i] = f2bf(v);
    } else if (i < n0 + n12) {
      int j = i - n0;
      wx12[j] = f2bf(W_ih_rest[j]);
    } else {
      int j = i - n0 - n12;
      if (whb) whb[j] = f2bf(W_hh[j]);
    }
  }
}

// ---------------- prep: bf16 copy of lin_W ----------------------------------
__global__ void wb_conv(const float* __restrict__ W, u16* __restrict__ Wb) {
  const long n = (long)kVG * 1024;
  long stride = (long)gridDim.x * blockDim.x * 8;
  for (long i = (long)(blockIdx.x * blockDim.x + threadIdx.x) * 8; i < n; i += stride) {
    float4 a = *(const float4*)(W + i);
    float4 b = *(const float4*)(W + i + 4);
    u16 t[8] = {f2bf(a.x), f2bf(a.y), f2bf(a.z), f2bf(a.w),
                f2bf(b.x), f2bf(b.y), f2bf(b.z), f2bf(b.w)};
    *(uint4*)(Wb + i) = *(const uint4*)t;
  }
}

// ---------------- GAT (node-0 only, factored attention) ---------------------
__global__ void __launch_bounds__(256) gat_kernel(
    const int* __restrict__ x_indices, const int* __restrict__ edge_index,
    const float* __restrict__ X, const float* __restrict__ gat_W,
    const float* __restrict__ gat_bias, const float* __restrict__ ws_src,
    const float* __restrict__ ws_dst, u16* __restrict__ sig) {
  __shared__ float xs[32][301];
  __shared__ float a_s[32][4];
  __shared__ float a_d0[4];
  __shared__ float alpha[4][32];
  __shared__ float xw[4][301];
  __shared__ int allowed[32];
  int g = blockIdx.x, tid = threadIdx.x;
  const int* idx = x_indices + g * 32;
  for (int i = tid; i < 32 * 300; i += 256) {
    int j = i / 300, d2 = i - j * 300;
    xs[j][d2] = X[(size_t)idx[j] * 300 + d2];
  }
  if (tid < 32) allowed[tid] = (tid == 0) ? 1 : 0;
  __syncthreads();
  if (tid < 128) {
    int j = tid >> 2, h = tid & 3;
    float s = 0.f;
    for (int d2 = 0; d2 < 300; ++d2) s += xs[j][d2] * ws_src[d2 * 4 + h];
    a_s[j][h] = s;
  } else if (tid < 132) {
    int h = tid - 128; float s = 0.f;
    for (int d2 = 0; d2 < 300; ++d2) s += xs[0][d2] * ws_dst[d2 * 4 + h];
    a_d0[h] = s;
  } else if (tid >= 192) {
    int e = tid - 192;
    int src = edge_index[g * 128 + e];
    int dst = edge_index[g * 128 + 64 + e];
    if (dst == 0) allowed[src] = 1;
  }
  __syncthreads();
  if (tid < 4) {
    int h = tid;
    float ev[32];
    float mx = -1e30f;
    #pragma unroll
    for (int j = 0; j < 32; ++j) {
      float v = a_d0[h] + a_s[j][h];
      v = (v > 0.f) ? v : 0.2f * v;
      v = allowed[j] ? v : -1e9f;
      ev[j] = v; mx = fmaxf(mx, v);
    }
    float ssum = 0.f;
    #pragma unroll
    for (int j = 0; j < 32; ++j) { float p = fexp(ev[j] - mx); ev[j] = p; ssum += p; }
    float inv = 1.f / ssum;
    #pragma unroll
    for (int j = 0; j < 32; ++j) alpha[h][j] = ev[j] * inv;
  }
  __syncthreads();
  for (int i = tid; i < 4 * 300; i += 256) {
    int h = i / 300, d2 = i - h * 300;
    float s = 0.f;
    #pragma unroll
    for (int j = 0; j < 32; ++j) s += alpha[h][j] * xs[j][d2];
    xw[h][d2] = s;
  }
  __syncthreads();
  int t = g % 35, b = g / 35;
  u16* srow = sig + ((size_t)t * 32 + b) * 640;
  for (int hc = tid; hc < 300; hc += 256) {
    srow[hc] = f2bf(xs[0][hc]);           // curr_emb = X[idx 0]
    int h = hc / 75;
    float s = gat_bias[hc];
    for (int d2 = 0; d2 < 300; ++d2) s += xw[h][d2] * gat_W[d2 * 300 + hc];
    srow[300 + hc] = f2bf(s);
  }
  for (int i2 = 600 + tid; i2 < 640; i2 += 256) srow[i2] = 0;  // zero pad
}

// ---------------- fence-free flag barrier (LLC-direct h stores) -------------
DEV void flag_barrier(unsigned* flags, int nb, unsigned s) {
  __syncthreads();   // implies vmcnt drain: h stores complete at LLC
  if (threadIdx.x == 0)
    __hip_atomic_store(flags + blockIdx.x, s, __ATOMIC_RELAXED, __HIP_MEMORY_SCOPE_AGENT);
  if (threadIdx.x < 64) {
    for (int j = threadIdx.x; j < nb; j += 64) {
      while (__hip_atomic_load(flags + j, __ATOMIC_RELAXED, __HIP_MEMORY_SCOPE_AGENT) < s)
        __builtin_amdgcn_s_sleep(1);
    }
  }
  __syncthreads();
}

// ---------------- bulk input-gate GEMM (gll16 dbuf + counted vmcnt) ---------
// gates written INTERLEAVED: gates[m][u*4+g]  (one float4 per (m,unit))
__global__ void __launch_bounds__(256, 4) gemm_ig(
    const u16* __restrict__ A, const u16* __restrict__ Bw,
    float* __restrict__ gates, int K) {
  int bid = blockIdx.x;
  int bm = bid % 9, bn = bid / 9;
  int m0 = bm * 128, n0 = bn * 128;
  int tid = threadIdx.x, w = tid >> 6, lane = tid & 63, l15 = lane & 15, lhi = lane >> 4;
  int wm = w & 1, wn = w >> 1;
  __shared__ u16 As[2][128][32];
  __shared__ u16 Bs[2][128][32];
  int am0 = m0 + w * 32 + (lane >> 2);
  int am1 = am0 + 16;
  const u16* arow0 = A + (size_t)((am0 < kM) ? am0 : 0) * K + (lane & 3) * 8;
  const u16* arow1 = A + (size_t)((am1 < kM) ? am1 : 0) * K + (lane & 3) * 8;
  int bn0r = n0 + w * 32 + (lane >> 2);
  const u16* brow0 = Bw + (size_t)bn0r * K + (lane & 3) * 8;
  const u16* brow1 = Bw + (size_t)(bn0r + 16) * K + (lane & 3) * 8;

  f32x4 acc[4][4];
  #pragma unroll
  for (int i = 0; i < 4; ++i)
    #pragma unroll
    for (int j = 0; j < 4; ++j) { f32x4 z = {0.f, 0.f, 0.f, 0.f}; acc[i][j] = z; }

  auto ISSUE = [&](int k0, int buf) {
    gll16(arow0 + k0, &As[buf][w * 32][0]);
    gll16(arow1 + k0, &As[buf][w * 32 + 16][0]);
    gll16(brow0 + k0, &Bs[buf][w * 32][0]);
    gll16(brow1 + k0, &Bs[buf][w * 32 + 16][0]);
  };
  int nkt = K >> 5;
  ISSUE(0, 0);
  for (int kt = 0; kt < nkt; ++kt) {
    int cur = kt & 1;
    if (kt < nkt - 1) {
      ISSUE((kt + 1) * 32, cur ^ 1);
      asm volatile("s_waitcnt vmcnt(4)" ::: "memory");
    } else {
      asm volatile("s_waitcnt vmcnt(0)" ::: "memory");
    }
    __builtin_amdgcn_s_barrier();
    __builtin_amdgcn_sched_barrier(0);
    short8 bfr[4];
    #pragma unroll
    for (int nt = 0; nt < 4; ++nt)
      bfr[nt] = *(const short8*)&Bs[cur][wn * 64 + nt * 16 + l15][lhi * 8];
    #pragma unroll
    for (int mt = 0; mt < 4; ++mt) {
      short8 af = *(const short8*)&As[cur][wm * 64 + mt * 16 + l15][lhi * 8];
      #pragma unroll
      for (int nt = 0; nt < 4; ++nt)
        acc[mt][nt] = mfma16(af, bfr[nt], acc[mt][nt]);
    }
    __builtin_amdgcn_sched_barrier(0);
    __builtin_amdgcn_s_barrier();
  }
  #pragma unroll
  for (int mt = 0; mt < 4; ++mt) {
    #pragma unroll
    for (int r = 0; r < 4; ++r) {
      int m = m0 + wm * 64 + mt * 16 + lhi * 4 + r;
      if (m < kM) {
        float* orow = gates + (size_t)m * 4096;
        #pragma unroll
        for (int nt = 0; nt < 4; ++nt) {
          int n = n0 + wn * 64 + nt * 16 + l15;
          orow[(n & 1023) * 4 + (n >> 10)] = acc[mt][nt][r];
        }
      }
    }
  }
}

// ---------------- LSTM recurrence: 128 blocks x 8 units ---------------------
__global__ void __launch_bounds__(256, 1) lstm_rec(
    const float* __restrict__ W_hh_l,   // [4096][1024] fp32, this layer
    const u16* __restrict__ whb_l,      // bf16 copy (may be null)
    const float* __restrict__ gates,    // [1120][1024][4] f32 interleaved
    const float* __restrict__ bias_l,   // [4096]
    u16* __restrict__ hout,             // [35*32][1024] bf16
    unsigned* flags, unsigned sbase) {
  const int p = blockIdx.x;             // 0..127
  const int tid = threadIdx.x;
  const int w = tid >> 6, lane = tid & 63, l15 = lane & 15, lhi = lane >> 4;
  __shared__ u16 whs[32][1032];         // rows: idx = g*8+jj -> global g*1024+8p+jj
  __shared__ float pred[4][32][33];     // [wave][w-row][batch]
  if (whb_l) {
    for (int i = tid; i < 32 * 128; i += 256) {
      int row = i >> 7, seg = i & 127;
      int g = row >> 3, jj = row & 7;
      uint4 v = *(const uint4*)(whb_l + (((size_t)(g * 1024 + p * 8 + jj)) << 10) + seg * 8);
      *(uint4*)&whs[row][seg * 8] = v;
    }
  } else {
    for (int i = tid; i < 32 * 256; i += 256) {
      int row = i >> 8, seg = i & 255;
      int g = row >> 3, jj = row & 7;
      const float* src = W_hh_l + (((size_t)(g * 1024 + p * 8 + jj)) << 10) + seg * 4;
      float4 f = *(const float4*)src;
      u16 tmp[4] = {f2bf(f.x), f2bf(f.y), f2bf(f.z), f2bf(f.w)};
      *(uint2*)&whs[row][seg * 4] = *(const uint2*)tmp;
    }
  }
  const int bb = tid >> 3, jj2 = tid & 7;
  float bias_r[4];
  #pragma unroll
  for (int g = 0; g < 4; ++g) bias_r[g] = bias_l[g * 1024 + p * 8 + jj2];
  float c_reg = 0.f;
  const int kbase = w * 256;
  const float4* gb4 = (const float4*)gates + (size_t)bb * 1024 + (p * 8 + jj2);

  // prefetch gx for t=0
  float4 gx = gb4[0];

  for (int t = 0; t < 35; ++t) {
    float4 gxn;
    if (t > 0) {
      const u16* hp = hout + (size_t)(t - 1) * 32 * 1024;
      const u16* hrow0 = hp + l15 * 1024 + lhi * 8;
      const u16* hrow1 = hp + (l15 + 16) * 1024 + lhi * 8;
      f32x4 acc00 = {0,0,0,0}, acc01 = {0,0,0,0}, acc10 = {0,0,0,0}, acc11 = {0,0,0,0};
      #pragma unroll
      for (int kk = 0; kk < 8; ++kk) {
        int k = kbase + kk * 32;
        short8 bf0 = *(const short8*)(hrow0 + k);
        short8 bf1 = *(const short8*)(hrow1 + k);
        short8 af0 = *(const short8*)&whs[l15][k + lhi * 8];
        short8 af1 = *(const short8*)&whs[16 + l15][k + lhi * 8];
        acc00 = mfma16(af0, bf0, acc00);
        acc01 = mfma16(af0, bf1, acc01);
        acc10 = mfma16(af1, bf0, acc10);
        acc11 = mfma16(af1, bf1, acc11);
      }
      if (t < 34) gxn = gb4[(size_t)(t + 1) * 32768];  // (t+1)*32*1024 float4
      #pragma unroll
      for (int r = 0; r < 4; ++r) {
        pred[w][lhi * 4 + r][l15]       = acc00[r];
        pred[w][lhi * 4 + r][l15 + 16]  = acc01[r];
        pred[w][16 + lhi * 4 + r][l15]      = acc10[r];
        pred[w][16 + lhi * 4 + r][l15 + 16] = acc11[r];
      }
      __syncthreads();
    } else {
      gxn = gb4[(size_t)32 * 1024];
    }
    float pre[4];
    #pragma unroll
    for (int g = 0; g < 4; ++g) {
      float s = 0.f;
      if (t > 0) {
        int row = g * 8 + jj2;
        s = pred[0][row][bb] + pred[1][row][bb] + pred[2][row][bb] + pred[3][row][bb];
      }
      pre[g] = s;
    }
    float iv = gx.x + pre[0] + bias_r[0];
    float fv = gx.y + pre[1] + bias_r[1];
    float gv = gx.z + pre[2] + bias_r[2];
    float ov = gx.w + pre[3] + bias_r[3];
    float cc = fsigm(fv) * c_reg + fsigm(iv) * ftanh(gv);
    float hh = fsigm(ov) * ftanh(cc);
    c_reg = cc;
    store_u16_llc(hout + ((size_t)(t * 32 + bb)) * 1024 + p * 8 + jj2, f2bf(hh));
    if (t < 34) flag_barrier(flags, 128, sbase + (unsigned)t + 1u);
    gx = gxn;
  }
}

// ---------------- logits GEMM epilogue --------------------------------------
DEV void logits_epilogue(f32x4 (&acc)[4][4], int m0, int n0, int wm, int wn,
                         int l15, int lhi, const float* lin_b,
                         float* out, float2* partials, int bn) {
  float bcol[4]; int ncol[4];
  #pragma unroll
  for (int nt = 0; nt < 4; ++nt) {
    int n = n0 + wn * 64 + nt * 16 + l15;
    ncol[nt] = n;
    bcol[nt] = (n < kVG) ? lin_b[n] : -INFINITY;
  }
  #pragma unroll
  for (int mt = 0; mt < 4; ++mt) {
    #pragma unroll
    for (int r = 0; r < 4; ++r) {
      int m = m0 + wm * 64 + mt * 16 + lhi * 4 + r;
      float v0 = acc[mt][0][r] + bcol[0];
      float v1 = acc[mt][1][r] + bcol[1];
      float v2 = acc[mt][2][r] + bcol[2];
      float v3 = acc[mt][3][r] + bcol[3];
      bool mok = (m < kM);
      if (mok) {
        float* orow = out + (size_t)m * kVG;
        if (ncol[0] < kVG) orow[ncol[0]] = v0;
        if (ncol[1] < kVG) orow[ncol[1]] = v1;
        if (ncol[2] < kVG) orow[ncol[2]] = v2;
        if (ncol[3] < kVG) orow[ncol[3]] = v3;
      }
      float mx = fmaxf(fmaxf(v0, v1), fmaxf(v2, v3));
      #pragma unroll
      for (int d2 = 1; d2 < 16; d2 <<= 1) mx = fmaxf(mx, __shfl_xor(mx, d2, 64));
      float sv = 0.f;
      sv += (v0 > -1e30f) ? fexp(v0 - mx) : 0.f;
      sv += (v1 > -1e30f) ? fexp(v1 - mx) : 0.f;
      sv += (v2 > -1e30f) ? fexp(v2 - mx) : 0.f;
      sv += (v3 > -1e30f) ? fexp(v3 - mx) : 0.f;
      #pragma unroll
      for (int d2 = 1; d2 < 16; d2 <<= 1) sv += __shfl_xor(sv, d2, 64);
      if (mok && l15 == 0)
        partials[(size_t)m * 784 + bn * 2 + wn] = make_float2(mx, sv);
    }
  }
}

// ---------------- logits GEMM (gll16 dbuf + counted vmcnt) ------------------
__global__ void __launch_bounds__(256, 4) gemm_logits_async(
    const u16* __restrict__ hist2, const u16* __restrict__ linwb,
    const float* __restrict__ lin_b, float* __restrict__ out,
    float2* __restrict__ partials) {
  // XCD-bijective swizzle
  int nwg = gridDim.x, orig = blockIdx.x;
  int q = nwg >> 3, r = nwg & 7, xcd = orig & 7, off = orig >> 3;
  int bid = (xcd < r ? xcd * (q + 1) : r * (q + 1) + (xcd - r) * q) + off;
  int bm = bid % 9, bn = bid / 9;
  int m0 = bm * 128, n0 = bn * 128;
  int tid = threadIdx.x, w = tid >> 6, lane = tid & 63, l15 = lane & 15, lhi = lane >> 4;
  int wm = w & 1, wn = w >> 1;
  __shared__ u16 As[2][128][32];
  __shared__ u16 Bs[2][128][32];
  int am0 = m0 + w * 32 + (lane >> 2);
  int am1 = am0 + 16;
  int mm0 = (am0 < kM) ? am0 : 0, mm1 = (am1 < kM) ? am1 : 0;
  const u16* arow0 = hist2 + (((size_t)((mm0 % 35) * 32 + mm0 / 35)) << 10) + (lane & 3) * 8;
  const u16* arow1 = hist2 + (((size_t)((mm1 % 35) * 32 + mm1 / 35)) << 10) + (lane & 3) * 8;
  int nr0 = n0 + w * 32 + (lane >> 2);
  int nn0 = (nr0 < kVG) ? nr0 : 0, nn1 = (nr0 + 16 < kVG) ? nr0 + 16 : 0;
  const u16* brow0 = linwb + ((size_t)nn0 << 10) + (lane & 3) * 8;
  const u16* brow1 = linwb + ((size_t)nn1 << 10) + (lane & 3) * 8;

  f32x4 acc[4][4];
  #pragma unroll
  for (int i = 0; i < 4; ++i)
    #pragma unroll
    for (int j = 0; j < 4; ++j) { f32x4 z = {0.f, 0.f, 0.f, 0.f}; acc[i][j] = z; }

  auto ISSUE = [&](int k0, int buf) {
    gll16(arow0 + k0, &As[buf][w * 32][0]);
    gll16(arow1 + k0, &As[buf][w * 32 + 16][0]);
    gll16(brow0 + k0, &Bs[buf][w * 32][0]);
    gll16(brow1 + k0, &Bs[buf][w * 32 + 16][0]);
  };
  ISSUE(0, 0);
  for (int kt = 0; kt < 32; ++kt) {
    int cur = kt & 1;
    if (kt < 31) {
      ISSUE((kt + 1) * 32, cur ^ 1);
      asm volatile("s_waitcnt vmcnt(4)" ::: "memory");
    } else {
      asm volatile("s_waitcnt vmcnt(0)" ::: "memory");
    }
    __builtin_amdgcn_s_barrier();
    __builtin_amdgcn_sched_barrier(0);
    short8 bfr[4];
    #pragma unroll
    for (int nt = 0; nt < 4; ++nt)
      bfr[nt] = *(const short8*)&Bs[cur][wn * 64 + nt * 16 + l15][lhi * 8];
    #pragma unroll
    for (int mt = 0; mt < 4; ++mt) {
      short8 af = *(const short8*)&As[cur][wm * 64 + mt * 16 + l15][lhi * 8];
      #pragma unroll
      for (int nt = 0; nt < 4; ++nt)
        acc[mt][nt] = mfma16(af, bfr[nt], acc[mt][nt]);
    }
    __builtin_amdgcn_sched_barrier(0);
    __builtin_amdgcn_s_barrier();
  }
  logits_epilogue(acc, m0, n0, wm, wn, l15, lhi, lin_b, out, partials, bn);
}

// fallback (no bf16 workspace image): reg-staged, fp32 B inline-converted
__global__ void __launch_bounds__(256, 1) gemm_logits_fb(
    const u16* __restrict__ hist2, const float* __restrict__ lin_W,
    const float* __restrict__ lin_b, float* __restrict__ out,
    float2* __restrict__ partials) {
  int nwg = gridDim.x, orig = blockIdx.x;
  int q = nwg >> 3, r = nwg & 7, xcd = orig & 7, off = orig >> 3;
  int bid = (xcd < r ? xcd * (q + 1) : r * (q + 1) + (xcd - r) * q) + off;
  int bm = bid % 9, bn = bid / 9;
  int m0 = bm * 128, n0 = bn * 128;
  int tid = threadIdx.x, w = tid >> 6, lane = tid & 63, l15 = lane & 15, lhi = lane >> 4;
  int wm = w & 1, wn = w >> 1;
  __shared__ u16 As[128][40];
  __shared__ u16 Bs[128][40];
  f32x4 acc[4][4];
  #pragma unroll
  for (int i = 0; i < 4; ++i)
    #pragma unroll
    for (int j = 0; j < 4; ++j) { f32x4 z = {0.f, 0.f, 0.f, 0.f}; acc[i][j] = z; }
  for (int kt = 0; kt < 32; ++kt) {
    int k0 = kt * 32;
    #pragma unroll
    for (int q2 = 0; q2 < 2; ++q2) {
      int c = tid * 2 + q2; int row = c >> 2; int ch = c & 3;
      int m = m0 + row;
      uint4 av{0u, 0u, 0u, 0u};
      if (m < kM) {
        int b = m / 35; int t = m - b * 35;
        av = *(const uint4*)(hist2 + ((size_t)(t * 32 + b) << 10) + k0 + ch * 8);
      }
      *(uint4*)&As[row][ch * 8] = av;
      int n = n0 + row;
      uint4 bv{0u, 0u, 0u, 0u};
      if (n < kVG) {
        const float* src = lin_W + (size_t)n * 1024 + k0 + ch * 8;
        float4 f0 = *(const float4*)(src);
        float4 f1 = *(const float4*)(src + 4);
        bv.x = (unsigned)f2bf(f0.x) | ((unsigned)f2bf(f0.y) << 16);
        bv.y = (unsigned)f2bf(f0.z) | ((unsigned)f2bf(f0.w) << 16);
        bv.z = (unsigned)f2bf(f1.x) | ((unsigned)f2bf(f1.y) << 16);
        bv.w = (unsigned)f2bf(f1.z) | ((unsigned)f2bf(f1.w) << 16);
      }
      *(uint4*)&Bs[row][ch * 8] = bv;
    }
    __syncthreads();
    short8 bfr[4];
    #pragma unroll
    for (int nt = 0; nt < 4; ++nt)
      bfr[nt] = *(const short8*)&Bs[wn * 64 + nt * 16 + l15][lhi * 8];
    #pragma unroll
    for (int mt = 0; mt < 4; ++mt) {
      short8 af = *(const short8*)&As[wm * 64 + mt * 16 + l15][lhi * 8];
      #pragma unroll
      for (int nt = 0; nt < 4; ++nt)
        acc[mt][nt] = mfma16(af, bfr[nt], acc[mt][nt]);
    }
    __syncthreads();
  }
  logits_epilogue(acc, m0, n0, wm, wn, l15, lhi, lin_b, out, partials, bn);
}

// ---------------- row logsumexp reduce --------------------------------------
__global__ void reduce_rows(const float2* __restrict__ partials, float* __restrict__ lse) {
  int m = blockIdx.x, tid = threadIdx.x;
  float mx = -INFINITY, s = 0.f;
  for (int j = tid; j < 782; j += 256) {
    float2 p = partials[(size_t)m * 784 + j];
    if (p.x > mx) { s = s * fexp(mx - p.x) + p.y; mx = p.x; }
    else          { s += p.y * fexp(p.x - mx); }
  }
  for (int d = 1; d < 64; d <<= 1) {
    float omx = __shfl_xor(mx, d, 64);
    float os  = __shfl_xor(s, d, 64);
    if (omx > mx) { s = s * fexp(mx - omx) + os; mx = omx; }
    else          { s += os * fexp(omx - mx); }
  }
  __shared__ float smx[4], ssum[4];
  int w = tid >> 6;
  if ((tid & 63) == 0) { smx[w] = mx; ssum[w] = s; }
  __syncthreads();
  if (tid == 0) {
    for (int i = 1; i < 4; ++i) {
      float omx = smx[i], os = ssum[i];
      if (omx > mx) { s = s * fexp(mx - omx) + os; mx = omx; }
      else          { s += os * fexp(omx - mx); }
    }
    lse[m] = mx + logf(s);
  }
}

// ---------------- in-place log_softmax subtract -----------------------------
__global__ void sub_lse(float* __restrict__ out, const float* __restrict__ lse) {
  const int total4 = 14000000;  // 1120*50000/4
  for (int i = blockIdx.x * blockDim.x + threadIdx.x; i < total4; i += gridDim.x * blockDim.x) {
    int m = i / 12500;
    float4 v = ((float4*)out)[i];
    float L = lse[m];
    v.x -= L; v.y -= L; v.z -= L; v.w -= L;
    ((float4*)out)[i] = v;
  }
}

// ---------------- launch ----------------------------------------------------
extern "C" void kernel_launch(void* const* d_in, const int* in_sizes, int n_in,
                              void* d_out, int out_size, void* d_ws, size_t ws_size,
                              hipStream_t stream) {
  const int*   x_indices  = (const int*)d_in[0];
  const int*   edge_index = (const int*)d_in[1];
  const float* X          = (const float*)d_in[2];
  const float* gat_W      = (const float*)d_in[3];
  const float* att_src    = (const float*)d_in[4];
  const float* att_dst    = (const float*)d_in[5];
  const float* gat_bias   = (const float*)d_in[6];
  const float* W_ih0      = (const float*)d_in[7];
  const float* W_ih_rest  = (const float*)d_in[8];
  const float* W_hh       = (const float*)d_in[9];
  const float* b_ih       = (const float*)d_in[10];
  const float* b_hh       = (const float*)d_in[11];
  const float* lin_W      = (const float*)d_in[12];
  const float* lin_b      = (const float*)d_in[13];
  float* out = (float*)d_out;
  char* ws = (char*)d_ws;

  unsigned* flags    = (unsigned*)(ws + OFF_BAR);
  float*    ws_src   = (float*)(ws + OFF_WSRC);
  float*    ws_dst   = (float*)(ws + OFF_WDST);
  float*    bias_sum = (float*)(ws + OFF_BIAS);
  u16*      sig      = (u16*)(ws + OFF_SIG);
  u16*      wx0      = (u16*)(ws + OFF_WX0);
  u16*      wx12     = (u16*)(ws + OFF_WX12);
  float*    gates    = (float*)(ws + OFF_GATES);
  u16*      hist     = (u16*)(ws + OFF_HIST);
  float2*   partials = (float2*)(ws + OFF_PART);
  float*    lse      = (float*)(ws + OFF_LSE);
  u16*      linwb    = (u16*)(ws + OFF_LINWB);
  u16*      whb      = (u16*)(ws + OFF_WHB);
  bool use_bw  = (ws_size >= kNeedBW);
  bool use_whb = (ws_size >= kNeedWHB);

  u16* hist0 = hist;
  u16* hist1 = hist + (size_t)35 * 32 * 1024;
  u16* hist2 = hist + (size_t)2 * 35 * 32 * 1024;

  hipMemsetAsync(ws + OFF_BAR, 0, 1024, stream);
  prep_small<<<64, 256, 0, stream>>>(gat_W, att_src, att_dst, b_ih, b_hh,
                                     ws_src, ws_dst, bias_sum);
  wx_prep<<<2048, 256, 0, stream>>>(W_ih0, W_ih_rest, W_hh, wx0, wx12,
                                    use_whb ? whb : nullptr);
  if (use_bw) wb_conv<<<2048, 256, 0, stream>>>(lin_W, linwb);
  gat_kernel<<<kG, 256, 0, stream>>>(x_indices, edge_index, X, gat_W, gat_bias,
                                     ws_src, ws_dst, sig);
  // layer 0
  gemm_ig<<<288, 256, 0, stream>>>(sig, wx0, gates, 640);
  lstm_rec<<<128, 256, 0, stream>>>(W_hh, use_whb ? whb : nullptr,
                                    gates, bias_sum, hist0, flags, 0u);
  // layer 1
  gemm_ig<<<288, 256, 0, stream>>>(hist0, wx12, gates, 1024);
  lstm_rec<<<128, 256, 0, stream>>>(W_hh + (size_t)4096 * 1024,
                                    use_whb ? whb + (size_t)4096 * 1024 : nullptr,
                                    gates, bias_sum + 4096, hist1, flags, 34u);
  // layer 2
  gemm_ig<<<288, 256, 0, stream>>>(hist1, wx12 + (size_t)4096 * 1024, gates, 1024);
  lstm_rec<<<128, 256, 0, stream>>>(W_hh + (size_t)2 * 4096 * 1024,
                                    use_whb ? whb + (size_t)2 * 4096 * 1024 : nullptr,
                                    gates, bias_sum + 8192, hist2, flags, 68u);
  // logits + log_softmax
  if (use_bw)
    gemm_logits_async<<<9 * 391, 256, 0, stream>>>(hist2, linwb, lin_b, out, partials);
  else
    gemm_logits_fb<<<9 * 391, 256, 0, stream>>>(hist2, lin_W, lin_b, out, partials);
  reduce_rows<<<kG, 256, 0, stream>>>(partials, lse);
  sub_lse<<<2048, 256, 0, stream>>>(out, lse);
}

// Round 11
// 1100.449 us; speedup vs baseline: 1.7182x; 1.0357x over previous
//
#include <hip/hip_runtime.h>

#define DEV __device__ __forceinline__

typedef __attribute__((ext_vector_type(8))) short short8;
typedef __attribute__((ext_vector_type(4))) float f32x4;
typedef unsigned short u16;

constexpr int kV = 80000, kD = 300, kNN = 32, kEE = 64, kHH = 4, kCC = 75;
constexpr int kB = 32, kT = 35, kU = 1024, kVG = 50000;
constexpr int kG = kB * kT;          // 1120
constexpr int kM = kG;

constexpr size_t alignup(size_t x) { return (x + 255) & ~size_t(255); }
constexpr size_t OFF_BAR   = 0;       // 128 flag slots (1024 B reserved)
constexpr size_t OFF_WSRC  = 1024;
constexpr size_t OFF_WDST  = alignup(OFF_WSRC + 1200 * 4);
constexpr size_t OFF_BIAS  = alignup(OFF_WDST + 1200 * 4);
constexpr size_t OFF_SIG   = alignup(OFF_BIAS + 3 * 4096 * 4);
constexpr size_t OFF_WX0   = alignup(OFF_SIG + (size_t)35 * 32 * 640 * 2);
constexpr size_t OFF_WX12  = alignup(OFF_WX0 + (size_t)4096 * 640 * 2);
constexpr size_t OFF_GATES = alignup(OFF_WX12 + (size_t)2 * 4096 * 1024 * 2);
constexpr size_t OFF_HIST  = alignup(OFF_GATES + (size_t)1120 * 4096 * 4);
constexpr size_t OFF_PART  = alignup(OFF_HIST + (size_t)3 * 35 * 32 * 1024 * 2);
constexpr size_t OFF_LSE   = alignup(OFF_PART + (size_t)1120 * 784 * 8);
constexpr size_t OFF_LINWB = alignup(OFF_LSE + 1120 * 4);
constexpr size_t kLinWBytes = (size_t)kVG * 1024 * 2;
constexpr size_t kNeedBW   = OFF_LINWB + kLinWBytes;
constexpr size_t OFF_WHB   = alignup(OFF_LINWB + kLinWBytes);
constexpr size_t kWhbBytes = (size_t)3 * 4096 * 1024 * 2;
constexpr size_t kNeedWHB  = OFF_WHB + kWhbBytes;

DEV u16 f2bf(float f) {
  union { float f; unsigned u; } v; v.f = f;
  unsigned r = v.u + 0x7fffu + ((v.u >> 16) & 1u);
  return (u16)(r >> 16);
}
DEV float fexp(float x) { return __builtin_amdgcn_exp2f(x * 1.4426950408889634f); }
DEV float fsigm(float x) {
  float t = __builtin_amdgcn_exp2f(-1.4426950408889634f * x);
  return __builtin_amdgcn_rcpf(1.f + t);
}
DEV float ftanh(float x) {
  float xc = fminf(fmaxf(x, -20.f), 20.f);
  float t = __builtin_amdgcn_exp2f(2.8853900817779268f * xc);
  return (t - 1.f) * __builtin_amdgcn_rcpf(t + 1.f);
}
DEV f32x4 mfma16(short8 a, short8 b, f32x4 c) {
  return __builtin_amdgcn_mfma_f32_16x16x32_bf16(a, b, c, 0, 0, 0);
}
// store a bf16 directly to the coherent LLC (bypass non-coherent per-XCD L2).
DEV void store_u16_llc(u16* p, u16 v) {
  unsigned vv = v;
  asm volatile("global_store_short %0, %1, off sc0 sc1"
               :: "v"(p), "v"(vv) : "memory");
}
// async global->LDS DMA, 16B/lane, LDS dst = wave-uniform base + lane*16
DEV void gll16(const void* g, void* l) {
  __builtin_amdgcn_global_load_lds(
      (const __attribute__((address_space(1))) unsigned int*)g,
      (__attribute__((address_space(3))) unsigned int*)l, 16, 0, 0);
}
// fp32 -> bf16 x8 conversion slice (grid-stride over n elements, /8)
DEV void conv_slice(const float* src, u16* dst, long n, long tid0, long stride) {
  long n8 = n >> 3;
  for (long i = tid0; i < n8; i += stride) {
    long o = i * 8;
    float4 a = *(const float4*)(src + o);
    float4 b = *(const float4*)(src + o + 4);
    u16 t[8] = {f2bf(a.x), f2bf(a.y), f2bf(a.z), f2bf(a.w),
                f2bf(b.x), f2bf(b.y), f2bf(b.z), f2bf(b.w)};
    *(uint4*)(dst + o) = *(const uint4*)t;
  }
}

// ---------------- prep: ws_src/ws_dst (W @ att vectors), bias sums ----------
__global__ void prep_small(const float* __restrict__ gat_W,
                           const float* __restrict__ att_src,
                           const float* __restrict__ att_dst,
                           const float* __restrict__ b_ih,
                           const float* __restrict__ b_hh,
                           float* __restrict__ ws_src, float* __restrict__ ws_dst,
                           float* __restrict__ bias_sum) {
  int total = 1200 + 1200 + 3 * 4096;
  for (int i = blockIdx.x * blockDim.x + threadIdx.x; i < total; i += gridDim.x * blockDim.x) {
    if (i < 1200) {
      int d = i >> 2, h = i & 3;
      float s = 0.f;
      for (int c = 0; c < kCC; ++c) s += gat_W[d * 300 + h * kCC + c] * att_src[h * kCC + c];
      ws_src[i] = s;
    } else if (i < 2400) {
      int j = i - 1200; int d = j >> 2, h = j & 3;
      float s = 0.f;
      for (int c = 0; c < kCC; ++c) s += gat_W[d * 300 + h * kCC + c] * att_dst[h * kCC + c];
      ws_dst[j] = s;
    } else {
      int j = i - 2400;
      bias_sum[j] = b_ih[j] + b_hh[j];
    }
  }
}

// ---------------- prep: bf16 weights (W_ih0, W_ih_rest, W_hh layers 0..n) ---
__global__ void wx_prep(const float* __restrict__ W_ih0,
                        const float* __restrict__ W_ih_rest,
                        const float* __restrict__ W_hh,
                        u16* __restrict__ wx0, u16* __restrict__ wx12,
                        u16* __restrict__ whb, int nhh_layers) {
  const int n0 = 4096 * 640;
  const int n12 = 2 * 4096 * 1024;
  const int nhh = nhh_layers * 4096 * 1024;
  int total = n0 + n12 + nhh;
  for (int i = blockIdx.x * blockDim.x + threadIdx.x; i < total; i += gridDim.x * blockDim.x) {
    if (i < n0) {
      int row = i / 640, col = i - row * 640;
      float v = (col < 600) ? W_ih0[row * 600 + col] : 0.f;
      wx0[i] = f2bf(v);
    } else if (i < n0 + n12) {
      int j = i - n0;
      wx12[j] = f2bf(W_ih_rest[j]);
    } else {
      int j = i - n0 - n12;
      if (whb) whb[j] = f2bf(W_hh[j]);
    }
  }
}

// ---------------- prep: bf16 copy of lin_W (fallback when not hidden) -------
__global__ void wb_conv(const float* __restrict__ W, u16* __restrict__ Wb) {
  const long n = (long)kVG * 1024;
  conv_slice(W, Wb, n, (long)(blockIdx.x * blockDim.x + threadIdx.x),
             (long)gridDim.x * blockDim.x);
}

// ---------------- GAT (node-0 only, factored attention) ---------------------
__global__ void __launch_bounds__(256) gat_kernel(
    const int* __restrict__ x_indices, const int* __restrict__ edge_index,
    const float* __restrict__ X, const float* __restrict__ gat_W,
    const float* __restrict__ gat_bias, const float* __restrict__ ws_src,
    const float* __restrict__ ws_dst, u16* __restrict__ sig) {
  __shared__ float xs[32][301];
  __shared__ float a_s[32][4];
  __shared__ float a_d0[4];
  __shared__ float alpha[4][32];
  __shared__ float xw[4][301];
  __shared__ int allowed[32];
  int g = blockIdx.x, tid = threadIdx.x;
  const int* idx = x_indices + g * 32;
  for (int i = tid; i < 32 * 300; i += 256) {
    int j = i / 300, d2 = i - j * 300;
    xs[j][d2] = X[(size_t)idx[j] * 300 + d2];
  }
  if (tid < 32) allowed[tid] = (tid == 0) ? 1 : 0;
  __syncthreads();
  if (tid < 128) {
    int j = tid >> 2, h = tid & 3;
    float s = 0.f;
    for (int d2 = 0; d2 < 300; ++d2) s += xs[j][d2] * ws_src[d2 * 4 + h];
    a_s[j][h] = s;
  } else if (tid < 132) {
    int h = tid - 128; float s = 0.f;
    for (int d2 = 0; d2 < 300; ++d2) s += xs[0][d2] * ws_dst[d2 * 4 + h];
    a_d0[h] = s;
  } else if (tid >= 192) {
    int e = tid - 192;
    int src = edge_index[g * 128 + e];
    int dst = edge_index[g * 128 + 64 + e];
    if (dst == 0) allowed[src] = 1;
  }
  __syncthreads();
  if (tid < 4) {
    int h = tid;
    float ev[32];
    float mx = -1e30f;
    #pragma unroll
    for (int j = 0; j < 32; ++j) {
      float v = a_d0[h] + a_s[j][h];
      v = (v > 0.f) ? v : 0.2f * v;
      v = allowed[j] ? v : -1e9f;
      ev[j] = v; mx = fmaxf(mx, v);
    }
    float ssum = 0.f;
    #pragma unroll
    for (int j = 0; j < 32; ++j) { float p = fexp(ev[j] - mx); ev[j] = p; ssum += p; }
    float inv = 1.f / ssum;
    #pragma unroll
    for (int j = 0; j < 32; ++j) alpha[h][j] = ev[j] * inv;
  }
  __syncthreads();
  for (int i = tid; i < 4 * 300; i += 256) {
    int h = i / 300, d2 = i - h * 300;
    float s = 0.f;
    #pragma unroll
    for (int j = 0; j < 32; ++j) s += alpha[h][j] * xs[j][d2];
    xw[h][d2] = s;
  }
  __syncthreads();
  int t = g % 35, b = g / 35;
  u16* srow = sig + ((size_t)t * 32 + b) * 640;
  for (int hc = tid; hc < 300; hc += 256) {
    srow[hc] = f2bf(xs[0][hc]);           // curr_emb = X[idx 0]
    int h = hc / 75;
    float s = gat_bias[hc];
    for (int d2 = 0; d2 < 300; ++d2) s += xw[h][d2] * gat_W[d2 * 300 + hc];
    srow[300 + hc] = f2bf(s);
  }
  for (int i2 = 600 + tid; i2 < 640; i2 += 256) srow[i2] = 0;  // zero pad
}

// ---------------- fence-free flag barrier (LLC-direct h stores) -------------
DEV void flag_barrier(unsigned* flags, int nb, unsigned s) {
  __syncthreads();   // implies vmcnt drain: h stores complete at LLC
  if (threadIdx.x == 0)
    __hip_atomic_store(flags + blockIdx.x, s, __ATOMIC_RELAXED, __HIP_MEMORY_SCOPE_AGENT);
  if (threadIdx.x < 64) {
    for (int j = threadIdx.x; j < nb; j += 64) {
      while (__hip_atomic_load(flags + j, __ATOMIC_RELAXED, __HIP_MEMORY_SCOPE_AGENT) < s)
        __builtin_amdgcn_s_sleep(1);
    }
  }
  __syncthreads();
}

// ---------------- bulk input-gate GEMM (gll16 dbuf + swizzled LDS) ----------
// gates written INTERLEAVED: gates[m][u*4+g]  (one float4 per (m,unit))
__global__ void __launch_bounds__(256, 4) gemm_ig(
    const u16* __restrict__ A, const u16* __restrict__ Bw,
    float* __restrict__ gates, int K) {
  int bid = blockIdx.x;
  int bm = bid % 9, bn = bid / 9;
  int m0 = bm * 128, n0 = bn * 128;
  int tid = threadIdx.x, w = tid >> 6, lane = tid & 63, l15 = lane & 15, lhi = lane >> 4;
  int wm = w & 1, wn = w >> 1;
  __shared__ u16 As[2][128][32];
  __shared__ u16 Bs[2][128][32];
  // swizzled global chunk: lane loads chunk (lane&3)^((lane>>3)&3) of its row,
  // so LDS[r][p] = global[r][p ^ ((r>>1)&3)]  (bank-conflict-free ds_read_b128)
  int cl = ((lane & 3) ^ ((lane >> 3) & 3)) * 8;
  int am0 = m0 + w * 32 + (lane >> 2);
  int am1 = am0 + 16;
  const u16* arow0 = A + (size_t)((am0 < kM) ? am0 : 0) * K + cl;
  const u16* arow1 = A + (size_t)((am1 < kM) ? am1 : 0) * K + cl;
  int bn0r = n0 + w * 32 + (lane >> 2);
  const u16* brow0 = Bw + (size_t)bn0r * K + cl;
  const u16* brow1 = Bw + (size_t)(bn0r + 16) * K + cl;
  const int koff = (lhi ^ ((l15 >> 1) & 3)) * 8;  // read-side swizzle

  f32x4 acc[4][4];
  #pragma unroll
  for (int i = 0; i < 4; ++i)
    #pragma unroll
    for (int j = 0; j < 4; ++j) { f32x4 z = {0.f, 0.f, 0.f, 0.f}; acc[i][j] = z; }

  auto ISSUE = [&](int k0, int buf) {
    gll16(arow0 + k0, &As[buf][w * 32][0]);
    gll16(arow1 + k0, &As[buf][w * 32 + 16][0]);
    gll16(brow0 + k0, &Bs[buf][w * 32][0]);
    gll16(brow1 + k0, &Bs[buf][w * 32 + 16][0]);
  };
  int nkt = K >> 5;
  ISSUE(0, 0);
  for (int kt = 0; kt < nkt; ++kt) {
    int cur = kt & 1;
    if (kt < nkt - 1) {
      ISSUE((kt + 1) * 32, cur ^ 1);
      asm volatile("s_waitcnt vmcnt(4)" ::: "memory");
    } else {
      asm volatile("s_waitcnt vmcnt(0)" ::: "memory");
    }
    __builtin_amdgcn_s_barrier();
    __builtin_amdgcn_sched_barrier(0);
    short8 bfr[4];
    #pragma unroll
    for (int nt = 0; nt < 4; ++nt)
      bfr[nt] = *(const short8*)&Bs[cur][wn * 64 + nt * 16 + l15][koff];
    #pragma unroll
    for (int mt = 0; mt < 4; ++mt) {
      short8 af = *(const short8*)&As[cur][wm * 64 + mt * 16 + l15][koff];
      #pragma unroll
      for (int nt = 0; nt < 4; ++nt)
        acc[mt][nt] = mfma16(af, bfr[nt], acc[mt][nt]);
    }
    __builtin_amdgcn_sched_barrier(0);
    __builtin_amdgcn_s_barrier();
  }
  #pragma unroll
  for (int mt = 0; mt < 4; ++mt) {
    #pragma unroll
    for (int r = 0; r < 4; ++r) {
      int m = m0 + wm * 64 + mt * 16 + lhi * 4 + r;
      if (m < kM) {
        float* orow = gates + (size_t)m * 4096;
        #pragma unroll
        for (int nt = 0; nt < 4; ++nt) {
          int n = n0 + wn * 64 + nt * 16 + l15;
          orow[(n & 1023) * 4 + (n >> 10)] = acc[mt][nt][r];
        }
      }
    }
  }
}

// ---------------- LSTM recurrence: 128 rec blocks + optional converter blocks
__global__ void __launch_bounds__(256, 1) lstm_rec(
    const float* __restrict__ W_hh_l,   // [4096][1024] fp32, this layer
    const u16* __restrict__ whb_l,      // bf16 copy (may be null)
    const float* __restrict__ gates,    // [1120][1024][4] f32 interleaved
    const float* __restrict__ bias_l,   // [4096]
    u16* __restrict__ hout,             // [35*32][1024] bf16
    unsigned* flags, unsigned sbase,
    const float* csrcA, u16* cdstA, long ncA,   // hidden conversion task A
    const float* csrcB, u16* cdstB, long ncB) { // hidden conversion task B
  if (blockIdx.x >= 128) {
    // converter block: runs on the otherwise-idle half of the machine
    long tid0 = (long)(blockIdx.x - 128) * 256 + threadIdx.x;
    long stride = 128L * 256;
    if (cdstA) conv_slice(csrcA, cdstA, ncA, tid0, stride);
    if (cdstB) conv_slice(csrcB, cdstB, ncB, tid0, stride);
    return;
  }
  const int p = blockIdx.x;             // 0..127
  const int tid = threadIdx.x;
  const int w = tid >> 6, lane = tid & 63, l15 = lane & 15, lhi = lane >> 4;
  __shared__ u16 whs[32][1032];         // rows: idx = g*8+jj -> global g*1024+8p+jj
  __shared__ float pred[4][32][33];     // [wave][w-row][batch]
  if (whb_l) {
    for (int i = tid; i < 32 * 128; i += 256) {
      int row = i >> 7, seg = i & 127;
      int g = row >> 3, jj = row & 7;
      uint4 v = *(const uint4*)(whb_l + (((size_t)(g * 1024 + p * 8 + jj)) << 10) + seg * 8);
      *(uint4*)&whs[row][seg * 8] = v;
    }
  } else {
    for (int i = tid; i < 32 * 256; i += 256) {
      int row = i >> 8, seg = i & 255;
      int g = row >> 3, jj = row & 7;
      const float* src = W_hh_l + (((size_t)(g * 1024 + p * 8 + jj)) << 10) + seg * 4;
      float4 f = *(const float4*)src;
      u16 tmp[4] = {f2bf(f.x), f2bf(f.y), f2bf(f.z), f2bf(f.w)};
      *(uint2*)&whs[row][seg * 4] = *(const uint2*)tmp;
    }
  }
  const int bb = tid >> 3, jj2 = tid & 7;
  float bias_r[4];
  #pragma unroll
  for (int g = 0; g < 4; ++g) bias_r[g] = bias_l[g * 1024 + p * 8 + jj2];
  float c_reg = 0.f;
  const int kbase = w * 256;
  const float4* gb4 = (const float4*)gates + (size_t)bb * 1024 + (p * 8 + jj2);

  // prefetch gx for t=0
  float4 gx = gb4[0];

  for (int t = 0; t < 35; ++t) {
    float4 gxn;
    if (t > 0) {
      const u16* hp = hout + (size_t)(t - 1) * 32 * 1024;
      const u16* hrow0 = hp + l15 * 1024 + lhi * 8;
      const u16* hrow1 = hp + (l15 + 16) * 1024 + lhi * 8;
      f32x4 acc00 = {0,0,0,0}, acc01 = {0,0,0,0}, acc10 = {0,0,0,0}, acc11 = {0,0,0,0};
      #pragma unroll
      for (int kk = 0; kk < 8; ++kk) {
        int k = kbase + kk * 32;
        short8 bf0 = *(const short8*)(hrow0 + k);
        short8 bf1 = *(const short8*)(hrow1 + k);
        short8 af0 = *(const short8*)&whs[l15][k + lhi * 8];
        short8 af1 = *(const short8*)&whs[16 + l15][k + lhi * 8];
        acc00 = mfma16(af0, bf0, acc00);
        acc01 = mfma16(af0, bf1, acc01);
        acc10 = mfma16(af1, bf0, acc10);
        acc11 = mfma16(af1, bf1, acc11);
      }
      if (t < 34) gxn = gb4[(size_t)(t + 1) * 32768];  // (t+1)*32*1024 float4
      #pragma unroll
      for (int r = 0; r < 4; ++r) {
        pred[w][lhi * 4 + r][l15]       = acc00[r];
        pred[w][lhi * 4 + r][l15 + 16]  = acc01[r];
        pred[w][16 + lhi * 4 + r][l15]      = acc10[r];
        pred[w][16 + lhi * 4 + r][l15 + 16] = acc11[r];
      }
      __syncthreads();
    } else {
      gxn = gb4[(size_t)32 * 1024];
    }
    float pre[4];
    #pragma unroll
    for (int g = 0; g < 4; ++g) {
      float s = 0.f;
      if (t > 0) {
        int row = g * 8 + jj2;
        s = pred[0][row][bb] + pred[1][row][bb] + pred[2][row][bb] + pred[3][row][bb];
      }
      pre[g] = s;
    }
    float iv = gx.x + pre[0] + bias_r[0];
    float fv = gx.y + pre[1] + bias_r[1];
    float gv = gx.z + pre[2] + bias_r[2];
    float ov = gx.w + pre[3] + bias_r[3];
    float cc = fsigm(fv) * c_reg + fsigm(iv) * ftanh(gv);
    float hh = fsigm(ov) * ftanh(cc);
    c_reg = cc;
    store_u16_llc(hout + ((size_t)(t * 32 + bb)) * 1024 + p * 8 + jj2, f2bf(hh));
    if (t < 34) flag_barrier(flags, 128, sbase + (unsigned)t + 1u);
    gx = gxn;
  }
}

// ---------------- logits GEMM epilogue --------------------------------------
DEV void logits_epilogue(f32x4 (&acc)[4][4], int m0, int n0, int wm, int wn,
                         int l15, int lhi, const float* lin_b,
                         float* out, float2* partials, int bn) {
  float bcol[4]; int ncol[4];
  #pragma unroll
  for (int nt = 0; nt < 4; ++nt) {
    int n = n0 + wn * 64 + nt * 16 + l15;
    ncol[nt] = n;
    bcol[nt] = (n < kVG) ? lin_b[n] : -INFINITY;
  }
  #pragma unroll
  for (int mt = 0; mt < 4; ++mt) {
    #pragma unroll
    for (int r = 0; r < 4; ++r) {
      int m = m0 + wm * 64 + mt * 16 + lhi * 4 + r;
      float v0 = acc[mt][0][r] + bcol[0];
      float v1 = acc[mt][1][r] + bcol[1];
      float v2 = acc[mt][2][r] + bcol[2];
      float v3 = acc[mt][3][r] + bcol[3];
      bool mok = (m < kM);
      if (mok) {
        float* orow = out + (size_t)m * kVG;
        if (ncol[0] < kVG) orow[ncol[0]] = v0;
        if (ncol[1] < kVG) orow[ncol[1]] = v1;
        if (ncol[2] < kVG) orow[ncol[2]] = v2;
        if (ncol[3] < kVG) orow[ncol[3]] = v3;
      }
      float mx = fmaxf(fmaxf(v0, v1), fmaxf(v2, v3));
      #pragma unroll
      for (int d2 = 1; d2 < 16; d2 <<= 1) mx = fmaxf(mx, __shfl_xor(mx, d2, 64));
      float sv = 0.f;
      sv += (v0 > -1e30f) ? fexp(v0 - mx) : 0.f;
      sv += (v1 > -1e30f) ? fexp(v1 - mx) : 0.f;
      sv += (v2 > -1e30f) ? fexp(v2 - mx) : 0.f;
      sv += (v3 > -1e30f) ? fexp(v3 - mx) : 0.f;
      #pragma unroll
      for (int d2 = 1; d2 < 16; d2 <<= 1) sv += __shfl_xor(sv, d2, 64);
      if (mok && l15 == 0)
        partials[(size_t)m * 784 + bn * 2 + wn] = make_float2(mx, sv);
    }
  }
}

// ---------------- logits GEMM (gll16 dbuf + swizzled LDS) -------------------
__global__ void __launch_bounds__(256, 4) gemm_logits_async(
    const u16* __restrict__ hist2, const u16* __restrict__ linwb,
    const float* __restrict__ lin_b, float* __restrict__ out,
    float2* __restrict__ partials) {
  // XCD-bijective swizzle
  int nwg = gridDim.x, orig = blockIdx.x;
  int q = nwg >> 3, r = nwg & 7, xcd = orig & 7, off = orig >> 3;
  int bid = (xcd < r ? xcd * (q + 1) : r * (q + 1) + (xcd - r) * q) + off;
  int bm = bid % 9, bn = bid / 9;
  int m0 = bm * 128, n0 = bn * 128;
  int tid = threadIdx.x, w = tid >> 6, lane = tid & 63, l15 = lane & 15, lhi = lane >> 4;
  int wm = w & 1, wn = w >> 1;
  __shared__ u16 As[2][128][32];
  __shared__ u16 Bs[2][128][32];
  int cl = ((lane & 3) ^ ((lane >> 3) & 3)) * 8;
  int am0 = m0 + w * 32 + (lane >> 2);
  int am1 = am0 + 16;
  int mm0 = (am0 < kM) ? am0 : 0, mm1 = (am1 < kM) ? am1 : 0;
  const u16* arow0 = hist2 + (((size_t)((mm0 % 35) * 32 + mm0 / 35)) << 10) + cl;
  const u16* arow1 = hist2 + (((size_t)((mm1 % 35) * 32 + mm1 / 35)) << 10) + cl;
  int nr0 = n0 + w * 32 + (lane >> 2);
  int nn0 = (nr0 < kVG) ? nr0 : 0, nn1 = (nr0 + 16 < kVG) ? nr0 + 16 : 0;
  const u16* brow0 = linwb + ((size_t)nn0 << 10) + cl;
  const u16* brow1 = linwb + ((size_t)nn1 << 10) + cl;
  const int koff = (lhi ^ ((l15 >> 1) & 3)) * 8;

  f32x4 acc[4][4];
  #pragma unroll
  for (int i = 0; i < 4; ++i)
    #pragma unroll
    for (int j = 0; j < 4; ++j) { f32x4 z = {0.f, 0.f, 0.f, 0.f}; acc[i][j] = z; }

  auto ISSUE = [&](int k0, int buf) {
    gll16(arow0 + k0, &As[buf][w * 32][0]);
    gll16(arow1 + k0, &As[buf][w * 32 + 16][0]);
    gll16(brow0 + k0, &Bs[buf][w * 32][0]);
    gll16(brow1 + k0, &Bs[buf][w * 32 + 16][0]);
  };
  ISSUE(0, 0);
  for (int kt = 0; kt < 32; ++kt) {
    int cur = kt & 1;
    if (kt < 31) {
      ISSUE((kt + 1) * 32, cur ^ 1);
      asm volatile("s_waitcnt vmcnt(4)" ::: "memory");
    } else {
      asm volatile("s_waitcnt vmcnt(0)" ::: "memory");
    }
    __builtin_amdgcn_s_barrier();
    __builtin_amdgcn_sched_barrier(0);
    short8 bfr[4];
    #pragma unroll
    for (int nt = 0; nt < 4; ++nt)
      bfr[nt] = *(const short8*)&Bs[cur][wn * 64 + nt * 16 + l15][koff];
    #pragma unroll
    for (int mt = 0; mt < 4; ++mt) {
      short8 af = *(const short8*)&As[cur][wm * 64 + mt * 16 + l15][koff];
      #pragma unroll
      for (int nt = 0; nt < 4; ++nt)
        acc[mt][nt] = mfma16(af, bfr[nt], acc[mt][nt]);
    }
    __builtin_amdgcn_sched_barrier(0);
    __builtin_amdgcn_s_barrier();
  }
  logits_epilogue(acc, m0, n0, wm, wn, l15, lhi, lin_b, out, partials, bn);
}

// fallback (no bf16 workspace image): reg-staged, fp32 B inline-converted
__global__ void __launch_bounds__(256, 1) gemm_logits_fb(
    const u16* __restrict__ hist2, const float* __restrict__ lin_W,
    const float* __restrict__ lin_b, float* __restrict__ out,
    float2* __restrict__ partials) {
  int nwg = gridDim.x, orig = blockIdx.x;
  int q = nwg >> 3, r = nwg & 7, xcd = orig & 7, off = orig >> 3;
  int bid = (xcd < r ? xcd * (q + 1) : r * (q + 1) + (xcd - r) * q) + off;
  int bm = bid % 9, bn = bid / 9;
  int m0 = bm * 128, n0 = bn * 128;
  int tid = threadIdx.x, w = tid >> 6, lane = tid & 63, l15 = lane & 15, lhi = lane >> 4;
  int wm = w & 1, wn = w >> 1;
  __shared__ u16 As[128][40];
  __shared__ u16 Bs[128][40];
  f32x4 acc[4][4];
  #pragma unroll
  for (int i = 0; i < 4; ++i)
    #pragma unroll
    for (int j = 0; j < 4; ++j) { f32x4 z = {0.f, 0.f, 0.f, 0.f}; acc[i][j] = z; }
  for (int kt = 0; kt < 32; ++kt) {
    int k0 = kt * 32;
    #pragma unroll
    for (int q2 = 0; q2 < 2; ++q2) {
      int c = tid * 2 + q2; int row = c >> 2; int ch = c & 3;
      int m = m0 + row;
      uint4 av{0u, 0u, 0u, 0u};
      if (m < kM) {
        int b = m / 35; int t = m - b * 35;
        av = *(const uint4*)(hist2 + ((size_t)(t * 32 + b) << 10) + k0 + ch * 8);
      }
      *(uint4*)&As[row][ch * 8] = av;
      int n = n0 + row;
      uint4 bv{0u, 0u, 0u, 0u};
      if (n < kVG) {
        const float* src = lin_W + (size_t)n * 1024 + k0 + ch * 8;
        float4 f0 = *(const float4*)(src);
        float4 f1 = *(const float4*)(src + 4);
        bv.x = (unsigned)f2bf(f0.x) | ((unsigned)f2bf(f0.y) << 16);
        bv.y = (unsigned)f2bf(f0.z) | ((unsigned)f2bf(f0.w) << 16);
        bv.z = (unsigned)f2bf(f1.x) | ((unsigned)f2bf(f1.y) << 16);
        bv.w = (unsigned)f2bf(f1.z) | ((unsigned)f2bf(f1.w) << 16);
      }
      *(uint4*)&Bs[row][ch * 8] = bv;
    }
    __syncthreads();
    short8 bfr[4];
    #pragma unroll
    for (int nt = 0; nt < 4; ++nt)
      bfr[nt] = *(const short8*)&Bs[wn * 64 + nt * 16 + l15][lhi * 8];
    #pragma unroll
    for (int mt = 0; mt < 4; ++mt) {
      short8 af = *(const short8*)&As[wm * 64 + mt * 16 + l15][lhi * 8];
      #pragma unroll
      for (int nt = 0; nt < 4; ++nt)
        acc[mt][nt] = mfma16(af, bfr[nt], acc[mt][nt]);
    }
    __syncthreads();
  }
  logits_epilogue(acc, m0, n0, wm, wn, l15, lhi, lin_b, out, partials, bn);
}

// ---------------- row logsumexp reduce --------------------------------------
__global__ void reduce_rows(const float2* __restrict__ partials, float* __restrict__ lse) {
  int m = blockIdx.x, tid = threadIdx.x;
  float mx = -INFINITY, s = 0.f;
  for (int j = tid; j < 782; j += 256) {
    float2 p = partials[(size_t)m * 784 + j];
    if (p.x > mx) { s = s * fexp(mx - p.x) + p.y; mx = p.x; }
    else          { s += p.y * fexp(p.x - mx); }
  }
  for (int d = 1; d < 64; d <<= 1) {
    float omx = __shfl_xor(mx, d, 64);
    float os  = __shfl_xor(s, d, 64);
    if (omx > mx) { s = s * fexp(mx - omx) + os; mx = omx; }
    else          { s += os * fexp(omx - mx); }
  }
  __shared__ float smx[4], ssum[4];
  int w = tid >> 6;
  if ((tid & 63) == 0) { smx[w] = mx; ssum[w] = s; }
  __syncthreads();
  if (tid == 0) {
    for (int i = 1; i < 4; ++i) {
      float omx = smx[i], os = ssum[i];
      if (omx > mx) { s = s * fexp(mx - omx) + os; mx = omx; }
      else          { s += os * fexp(omx - mx); }
    }
    lse[m] = mx + logf(s);
  }
}

// ---------------- in-place log_softmax subtract -----------------------------
__global__ void sub_lse(float* __restrict__ out, const float* __restrict__ lse) {
  const int total4 = 14000000;  // 1120*50000/4
  for (int i = blockIdx.x * blockDim.x + threadIdx.x; i < total4; i += gridDim.x * blockDim.x) {
    int m = i / 12500;
    float4 v = ((float4*)out)[i];
    float L = lse[m];
    v.x -= L; v.y -= L; v.z -= L; v.w -= L;
    ((float4*)out)[i] = v;
  }
}

// ---------------- launch ----------------------------------------------------
extern "C" void kernel_launch(void* const* d_in, const int* in_sizes, int n_in,
                              void* d_out, int out_size, void* d_ws, size_t ws_size,
                              hipStream_t stream) {
  const int*   x_indices  = (const int*)d_in[0];
  const int*   edge_index = (const int*)d_in[1];
  const float* X          = (const float*)d_in[2];
  const float* gat_W      = (const float*)d_in[3];
  const float* att_src    = (const float*)d_in[4];
  const float* att_dst    = (const float*)d_in[5];
  const float* gat_bias   = (const float*)d_in[6];
  const float* W_ih0      = (const float*)d_in[7];
  const float* W_ih_rest  = (const float*)d_in[8];
  const float* W_hh       = (const float*)d_in[9];
  const float* b_ih       = (const float*)d_in[10];
  const float* b_hh       = (const float*)d_in[11];
  const float* lin_W      = (const float*)d_in[12];
  const float* lin_b      = (const float*)d_in[13];
  float* out = (float*)d_out;
  char* ws = (char*)d_ws;

  unsigned* flags    = (unsigned*)(ws + OFF_BAR);
  float*    ws_src   = (float*)(ws + OFF_WSRC);
  float*    ws_dst   = (float*)(ws + OFF_WDST);
  float*    bias_sum = (float*)(ws + OFF_BIAS);
  u16*      sig      = (u16*)(ws + OFF_SIG);
  u16*      wx0      = (u16*)(ws + OFF_WX0);
  u16*      wx12     = (u16*)(ws + OFF_WX12);
  float*    gates    = (float*)(ws + OFF_GATES);
  u16*      hist     = (u16*)(ws + OFF_HIST);
  float2*   partials = (float2*)(ws + OFF_PART);
  float*    lse      = (float*)(ws + OFF_LSE);
  u16*      linwb    = (u16*)(ws + OFF_LINWB);
  u16*      whb      = (u16*)(ws + OFF_WHB);
  bool use_bw  = (ws_size >= kNeedBW);
  bool use_whb = (ws_size >= kNeedWHB);
  bool hide = use_bw && use_whb;   // conversions hidden inside lstm_rec

  u16* hist0 = hist;
  u16* hist1 = hist + (size_t)35 * 32 * 1024;
  u16* hist2 = hist + (size_t)2 * 35 * 32 * 1024;
  const long nLinHalf = (long)kVG * 1024 / 2;   // 25,600,000

  hipMemsetAsync(ws + OFF_BAR, 0, 1024, stream);
  prep_small<<<64, 256, 0, stream>>>(gat_W, att_src, att_dst, b_ih, b_hh,
                                     ws_src, ws_dst, bias_sum);
  wx_prep<<<2048, 256, 0, stream>>>(W_ih0, W_ih_rest, W_hh, wx0, wx12,
                                    use_whb ? whb : nullptr, hide ? 1 : 3);
  if (use_bw && !hide) wb_conv<<<2048, 256, 0, stream>>>(lin_W, linwb);
  gat_kernel<<<kG, 256, 0, stream>>>(x_indices, edge_index, X, gat_W, gat_bias,
                                     ws_src, ws_dst, sig);
  // layer 0 (+ hidden conversions: whb layers 1-2, lin_W first half)
  gemm_ig<<<288, 256, 0, stream>>>(sig, wx0, gates, 640);
  lstm_rec<<<hide ? 256 : 128, 256, 0, stream>>>(
      W_hh, use_whb ? whb : nullptr, gates, bias_sum, hist0, flags, 0u,
      hide ? W_hh + (size_t)4096 * 1024 : nullptr,
      hide ? whb + (size_t)4096 * 1024 : nullptr, (long)2 * 4096 * 1024,
      hide ? lin_W : nullptr, hide ? linwb : nullptr, nLinHalf);
  // layer 1 (+ hidden conversion: lin_W second half)
  gemm_ig<<<288, 256, 0, stream>>>(hist0, wx12, gates, 1024);
  lstm_rec<<<hide ? 256 : 128, 256, 0, stream>>>(
      W_hh + (size_t)4096 * 1024,
      use_whb ? whb + (size_t)4096 * 1024 : nullptr,
      gates, bias_sum + 4096, hist1, flags, 34u,
      hide ? lin_W + nLinHalf : nullptr,
      hide ? linwb + nLinHalf : nullptr, nLinHalf,
      nullptr, nullptr, 0);
  // layer 2
  gemm_ig<<<288, 256, 0, stream>>>(hist1, wx12 + (size_t)4096 * 1024, gates, 1024);
  lstm_rec<<<128, 256, 0, stream>>>(
      W_hh + (size_t)2 * 4096 * 1024,
      use_whb ? whb + (size_t)2 * 4096 * 1024 : nullptr,
      gates, bias_sum + 8192, hist2, flags, 68u,
      nullptr, nullptr, 0, nullptr, nullptr, 0);
  // logits + log_softmax
  if (use_bw)
    gemm_logits_async<<<9 * 391, 256, 0, stream>>>(hist2, linwb, lin_b, out, partials);
  else
    gemm_logits_fb<<<9 * 391, 256, 0, stream>>>(hist2, lin_W, lin_b, out, partials);
  reduce_rows<<<kG, 256, 0, stream>>>(partials, lse);
  sub_lse<<<2048, 256, 0, stream>>>(out, lse);
}

// Round 12
// 1063.895 us; speedup vs baseline: 1.7772x; 1.0344x over previous
//
#include <hip/hip_runtime.h>

#define DEV __device__ __forceinline__

typedef __attribute__((ext_vector_type(8))) short short8;
typedef __attribute__((ext_vector_type(4))) float f32x4;
typedef unsigned short u16;

constexpr int kV = 80000, kD = 300, kNN = 32, kEE = 64, kHH = 4, kCC = 75;
constexpr int kB = 32, kT = 35, kU = 1024, kVG = 50000;
constexpr int kG = kB * kT;          // 1120
constexpr int kM = kG;

constexpr size_t alignup(size_t x) { return (x + 255) & ~size_t(255); }
constexpr size_t OFF_BAR   = 0;       // 128 flag slots (1024 B reserved)
constexpr size_t OFF_WSRC  = 1024;
constexpr size_t OFF_WDST  = alignup(OFF_WSRC + 1200 * 4);
constexpr size_t OFF_BIAS  = alignup(OFF_WDST + 1200 * 4);
constexpr size_t OFF_SIG   = alignup(OFF_BIAS + 3 * 4096 * 4);
constexpr size_t OFF_WX0   = alignup(OFF_SIG + (size_t)35 * 32 * 640 * 2);
constexpr size_t OFF_WX12  = alignup(OFF_WX0 + (size_t)4096 * 640 * 2);
constexpr size_t OFF_GATES = alignup(OFF_WX12 + (size_t)2 * 4096 * 1024 * 2);
constexpr size_t OFF_HIST  = alignup(OFF_GATES + (size_t)1120 * 4096 * 4);
constexpr size_t OFF_PART  = alignup(OFF_HIST + (size_t)3 * 35 * 32 * 1024 * 2);
constexpr size_t OFF_LSE   = alignup(OFF_PART + (size_t)1120 * 784 * 8);
constexpr size_t OFF_LINWB = alignup(OFF_LSE + 1120 * 4);
constexpr size_t kLinWBytes = (size_t)kVG * 1024 * 2;
constexpr size_t kNeedBW   = OFF_LINWB + kLinWBytes;
constexpr size_t OFF_WHB   = alignup(OFF_LINWB + kLinWBytes);
constexpr size_t kWhbBytes = (size_t)3 * 4096 * 1024 * 2;
constexpr size_t kNeedWHB  = OFF_WHB + kWhbBytes;

DEV u16 f2bf(float f) {
  union { float f; unsigned u; } v; v.f = f;
  unsigned r = v.u + 0x7fffu + ((v.u >> 16) & 1u);
  return (u16)(r >> 16);
}
DEV float fexp(float x) { return __builtin_amdgcn_exp2f(x * 1.4426950408889634f); }
DEV float fsigm(float x) {
  float t = __builtin_amdgcn_exp2f(-1.4426950408889634f * x);
  return __builtin_amdgcn_rcpf(1.f + t);
}
DEV float ftanh(float x) {
  float xc = fminf(fmaxf(x, -20.f), 20.f);
  float t = __builtin_amdgcn_exp2f(2.8853900817779268f * xc);
  return (t - 1.f) * __builtin_amdgcn_rcpf(t + 1.f);
}
DEV f32x4 mfma16(short8 a, short8 b, f32x4 c) {
  return __builtin_amdgcn_mfma_f32_16x16x32_bf16(a, b, c, 0, 0, 0);
}
// store a bf16 directly to the coherent LLC (bypass non-coherent per-XCD L2).
DEV void store_u16_llc(u16* p, u16 v) {
  unsigned vv = v;
  asm volatile("global_store_short %0, %1, off sc0 sc1"
               :: "v"(p), "v"(vv) : "memory");
}
// async global->LDS DMA, 16B/lane, LDS dst = wave-uniform base + lane*16
DEV void gll16(const void* g, void* l) {
  __builtin_amdgcn_global_load_lds(
      (const __attribute__((address_space(1))) unsigned int*)g,
      (__attribute__((address_space(3))) unsigned int*)l, 16, 0, 0);
}
// fp32 -> bf16 x8 conversion slice (grid-stride over n elements, /8)
DEV void conv_slice(const float* src, u16* dst, long n, long tid0, long stride) {
  long n8 = n >> 3;
  for (long i = tid0; i < n8; i += stride) {
    long o = i * 8;
    float4 a = *(const float4*)(src + o);
    float4 b = *(const float4*)(src + o + 4);
    u16 t[8] = {f2bf(a.x), f2bf(a.y), f2bf(a.z), f2bf(a.w),
                f2bf(b.x), f2bf(b.y), f2bf(b.z), f2bf(b.w)};
    *(uint4*)(dst + o) = *(const uint4*)t;
  }
}

// ---------------- prep: ws_src/ws_dst (W @ att vectors), bias sums ----------
__global__ void prep_small(const float* __restrict__ gat_W,
                           const float* __restrict__ att_src,
                           const float* __restrict__ att_dst,
                           const float* __restrict__ b_ih,
                           const float* __restrict__ b_hh,
                           float* __restrict__ ws_src, float* __restrict__ ws_dst,
                           float* __restrict__ bias_sum) {
  int total = 1200 + 1200 + 3 * 4096;
  for (int i = blockIdx.x * blockDim.x + threadIdx.x; i < total; i += gridDim.x * blockDim.x) {
    if (i < 1200) {
      int d = i >> 2, h = i & 3;
      float s = 0.f;
      for (int c = 0; c < kCC; ++c) s += gat_W[d * 300 + h * kCC + c] * att_src[h * kCC + c];
      ws_src[i] = s;
    } else if (i < 2400) {
      int j = i - 1200; int d = j >> 2, h = j & 3;
      float s = 0.f;
      for (int c = 0; c < kCC; ++c) s += gat_W[d * 300 + h * kCC + c] * att_dst[h * kCC + c];
      ws_dst[j] = s;
    } else {
      int j = i - 2400;
      bias_sum[j] = b_ih[j] + b_hh[j];
    }
  }
}

// ---------------- prep: bf16 weights (W_ih0, W_ih_rest, W_hh layers 0..n) ---
__global__ void wx_prep(const float* __restrict__ W_ih0,
                        const float* __restrict__ W_ih_rest,
                        const float* __restrict__ W_hh,
                        u16* __restrict__ wx0, u16* __restrict__ wx12,
                        u16* __restrict__ whb, int nhh_layers) {
  const int n0 = 4096 * 640;
  const int n12 = 2 * 4096 * 1024;
  const int nhh = nhh_layers * 4096 * 1024;
  int total = n0 + n12 + nhh;
  for (int i = blockIdx.x * blockDim.x + threadIdx.x; i < total; i += gridDim.x * blockDim.x) {
    if (i < n0) {
      int row = i / 640, col = i - row * 640;
      float v = (col < 600) ? W_ih0[row * 600 + col] : 0.f;
      wx0[i] = f2bf(v);
    } else if (i < n0 + n12) {
      int j = i - n0;
      wx12[j] = f2bf(W_ih_rest[j]);
    } else {
      int j = i - n0 - n12;
      if (whb) whb[j] = f2bf(W_hh[j]);
    }
  }
}

// ---------------- prep: bf16 copy of lin_W (fallback when not hidden) -------
__global__ void wb_conv(const float* __restrict__ W, u16* __restrict__ Wb) {
  const long n = (long)kVG * 1024;
  conv_slice(W, Wb, n, (long)(blockIdx.x * blockDim.x + threadIdx.x),
             (long)gridDim.x * blockDim.x);
}

// ---------------- GAT (node-0 only, factored attention) ---------------------
__global__ void __launch_bounds__(256) gat_kernel(
    const int* __restrict__ x_indices, const int* __restrict__ edge_index,
    const float* __restrict__ X, const float* __restrict__ gat_W,
    const float* __restrict__ gat_bias, const float* __restrict__ ws_src,
    const float* __restrict__ ws_dst, u16* __restrict__ sig) {
  __shared__ float xs[32][301];
  __shared__ float a_s[32][4];
  __shared__ float a_d0[4];
  __shared__ float alpha[4][32];
  __shared__ float xw[4][301];
  __shared__ int allowed[32];
  int g = blockIdx.x, tid = threadIdx.x;
  const int* idx = x_indices + g * 32;
  for (int i = tid; i < 32 * 300; i += 256) {
    int j = i / 300, d2 = i - j * 300;
    xs[j][d2] = X[(size_t)idx[j] * 300 + d2];
  }
  if (tid < 32) allowed[tid] = (tid == 0) ? 1 : 0;
  __syncthreads();
  if (tid < 128) {
    int j = tid >> 2, h = tid & 3;
    float s = 0.f;
    for (int d2 = 0; d2 < 300; ++d2) s += xs[j][d2] * ws_src[d2 * 4 + h];
    a_s[j][h] = s;
  } else if (tid < 132) {
    int h = tid - 128; float s = 0.f;
    for (int d2 = 0; d2 < 300; ++d2) s += xs[0][d2] * ws_dst[d2 * 4 + h];
    a_d0[h] = s;
  } else if (tid >= 192) {
    int e = tid - 192;
    int src = edge_index[g * 128 + e];
    int dst = edge_index[g * 128 + 64 + e];
    if (dst == 0) allowed[src] = 1;
  }
  __syncthreads();
  if (tid < 4) {
    int h = tid;
    float ev[32];
    float mx = -1e30f;
    #pragma unroll
    for (int j = 0; j < 32; ++j) {
      float v = a_d0[h] + a_s[j][h];
      v = (v > 0.f) ? v : 0.2f * v;
      v = allowed[j] ? v : -1e9f;
      ev[j] = v; mx = fmaxf(mx, v);
    }
    float ssum = 0.f;
    #pragma unroll
    for (int j = 0; j < 32; ++j) { float p = fexp(ev[j] - mx); ev[j] = p; ssum += p; }
    float inv = 1.f / ssum;
    #pragma unroll
    for (int j = 0; j < 32; ++j) alpha[h][j] = ev[j] * inv;
  }
  __syncthreads();
  for (int i = tid; i < 4 * 300; i += 256) {
    int h = i / 300, d2 = i - h * 300;
    float s = 0.f;
    #pragma unroll
    for (int j = 0; j < 32; ++j) s += alpha[h][j] * xs[j][d2];
    xw[h][d2] = s;
  }
  __syncthreads();
  int t = g % 35, b = g / 35;
  u16* srow = sig + ((size_t)t * 32 + b) * 640;
  for (int hc = tid; hc < 300; hc += 256) {
    srow[hc] = f2bf(xs[0][hc]);           // curr_emb = X[idx 0]
    int h = hc / 75;
    float s = gat_bias[hc];
    for (int d2 = 0; d2 < 300; ++d2) s += xw[h][d2] * gat_W[d2 * 300 + hc];
    srow[300 + hc] = f2bf(s);
  }
  for (int i2 = 600 + tid; i2 < 640; i2 += 256) srow[i2] = 0;  // zero pad
}

// ---------------- bulk input-gate GEMM (gll16 dbuf + swizzled LDS) ----------
// gates written INTERLEAVED: gates[m][u*4+g]  (one float4 per (m,unit))
__global__ void __launch_bounds__(256, 4) gemm_ig(
    const u16* __restrict__ A, const u16* __restrict__ Bw,
    float* __restrict__ gates, int K) {
  int bid = blockIdx.x;
  int bm = bid % 9, bn = bid / 9;
  int m0 = bm * 128, n0 = bn * 128;
  int tid = threadIdx.x, w = tid >> 6, lane = tid & 63, l15 = lane & 15, lhi = lane >> 4;
  int wm = w & 1, wn = w >> 1;
  __shared__ u16 As[2][128][32];
  __shared__ u16 Bs[2][128][32];
  // swizzled global chunk: lane loads chunk (lane&3)^((lane>>3)&3) of its row,
  // so LDS[r][p] = global[r][p ^ ((r>>1)&3)]  (bank-conflict-free ds_read_b128)
  int cl = ((lane & 3) ^ ((lane >> 3) & 3)) * 8;
  int am0 = m0 + w * 32 + (lane >> 2);
  int am1 = am0 + 16;
  const u16* arow0 = A + (size_t)((am0 < kM) ? am0 : 0) * K + cl;
  const u16* arow1 = A + (size_t)((am1 < kM) ? am1 : 0) * K + cl;
  int bn0r = n0 + w * 32 + (lane >> 2);
  const u16* brow0 = Bw + (size_t)bn0r * K + cl;
  const u16* brow1 = Bw + (size_t)(bn0r + 16) * K + cl;
  const int koff = (lhi ^ ((l15 >> 1) & 3)) * 8;  // read-side swizzle

  f32x4 acc[4][4];
  #pragma unroll
  for (int i = 0; i < 4; ++i)
    #pragma unroll
    for (int j = 0; j < 4; ++j) { f32x4 z = {0.f, 0.f, 0.f, 0.f}; acc[i][j] = z; }

  auto ISSUE = [&](int k0, int buf) {
    gll16(arow0 + k0, &As[buf][w * 32][0]);
    gll16(arow1 + k0, &As[buf][w * 32 + 16][0]);
    gll16(brow0 + k0, &Bs[buf][w * 32][0]);
    gll16(brow1 + k0, &Bs[buf][w * 32 + 16][0]);
  };
  int nkt = K >> 5;
  ISSUE(0, 0);
  for (int kt = 0; kt < nkt; ++kt) {
    int cur = kt & 1;
    if (kt < nkt - 1) {
      ISSUE((kt + 1) * 32, cur ^ 1);
      asm volatile("s_waitcnt vmcnt(4)" ::: "memory");
    } else {
      asm volatile("s_waitcnt vmcnt(0)" ::: "memory");
    }
    __builtin_amdgcn_s_barrier();
    __builtin_amdgcn_sched_barrier(0);
    short8 bfr[4];
    #pragma unroll
    for (int nt = 0; nt < 4; ++nt)
      bfr[nt] = *(const short8*)&Bs[cur][wn * 64 + nt * 16 + l15][koff];
    #pragma unroll
    for (int mt = 0; mt < 4; ++mt) {
      short8 af = *(const short8*)&As[cur][wm * 64 + mt * 16 + l15][koff];
      #pragma unroll
      for (int nt = 0; nt < 4; ++nt)
        acc[mt][nt] = mfma16(af, bfr[nt], acc[mt][nt]);
    }
    __builtin_amdgcn_sched_barrier(0);
    __builtin_amdgcn_s_barrier();
  }
  #pragma unroll
  for (int mt = 0; mt < 4; ++mt) {
    #pragma unroll
    for (int r = 0; r < 4; ++r) {
      int m = m0 + wm * 64 + mt * 16 + lhi * 4 + r;
      if (m < kM) {
        float* orow = gates + (size_t)m * 4096;
        #pragma unroll
        for (int nt = 0; nt < 4; ++nt) {
          int n = n0 + wn * 64 + nt * 16 + l15;
          orow[(n & 1023) * 4 + (n >> 10)] = acc[mt][nt][r];
        }
      }
    }
  }
}

// ---------------- LSTM recurrence: producer-flag dataflow (no grid barrier) -
// Block p owns units [8p,8p+8). flag[p] = t+1 once h_t for those units is at
// LLC. Consumer wave w (K-slice [256w,256w+256)) waits only on its 32
// producers [32w, 32w+32) -> skew pipelines instead of accumulating.
__global__ void __launch_bounds__(256, 1) lstm_rec(
    const float* __restrict__ W_hh_l,   // [4096][1024] fp32, this layer
    const u16* __restrict__ whb_l,      // bf16 copy (may be null)
    const float* __restrict__ gates,    // [1120][1024][4] f32 interleaved
    const float* __restrict__ bias_l,   // [4096]
    u16* __restrict__ hout,             // [35*32][1024] bf16
    unsigned* flags, unsigned sbase,
    const float* csrcA, u16* cdstA, long ncA,   // hidden conversion task A
    const float* csrcB, u16* cdstB, long ncB) { // hidden conversion task B
  if (blockIdx.x >= 128) {
    // converter block: runs on the otherwise-idle half of the machine
    long tid0 = (long)(blockIdx.x - 128) * 256 + threadIdx.x;
    long stride = 128L * 256;
    if (cdstA) conv_slice(csrcA, cdstA, ncA, tid0, stride);
    if (cdstB) conv_slice(csrcB, cdstB, ncB, tid0, stride);
    return;
  }
  const int p = blockIdx.x;             // 0..127
  const int tid = threadIdx.x;
  const int w = tid >> 6, lane = tid & 63, l15 = lane & 15, lhi = lane >> 4;
  __shared__ u16 whs[32][1032];         // rows: idx = g*8+jj -> global g*1024+8p+jj
  __shared__ float pred[4][32][33];     // [wave][w-row][batch]
  if (whb_l) {
    for (int i = tid; i < 32 * 128; i += 256) {
      int row = i >> 7, seg = i & 127;
      int g = row >> 3, jj = row & 7;
      uint4 v = *(const uint4*)(whb_l + (((size_t)(g * 1024 + p * 8 + jj)) << 10) + seg * 8);
      *(uint4*)&whs[row][seg * 8] = v;
    }
  } else {
    for (int i = tid; i < 32 * 256; i += 256) {
      int row = i >> 8, seg = i & 255;
      int g = row >> 3, jj = row & 7;
      const float* src = W_hh_l + (((size_t)(g * 1024 + p * 8 + jj)) << 10) + seg * 4;
      float4 f = *(const float4*)src;
      u16 tmp[4] = {f2bf(f.x), f2bf(f.y), f2bf(f.z), f2bf(f.w)};
      *(uint2*)&whs[row][seg * 4] = *(const uint2*)tmp;
    }
  }
  const int bb = tid >> 3, jj2 = tid & 7;
  float bias_r[4];
  #pragma unroll
  for (int g = 0; g < 4; ++g) bias_r[g] = bias_l[g * 1024 + p * 8 + jj2];
  float c_reg = 0.f;
  const int kbase = w * 256;
  const float4* gb4 = (const float4*)gates + (size_t)bb * 1024 + (p * 8 + jj2);
  const unsigned* myflags = flags + w * 32 + (lane & 31);  // this wave's producers

  // prefetch gx for t=0
  float4 gx = gb4[0];

  for (int t = 0; t < 35; ++t) {
    float4 gxn;
    if (t > 0) {
      // wave-level producer wait: only the 32 producers of this wave's K-slice
      unsigned tgt = sbase + (unsigned)t;
      while (!__all((int)(__hip_atomic_load(myflags, __ATOMIC_RELAXED,
                                            __HIP_MEMORY_SCOPE_AGENT) >= tgt)))
        __builtin_amdgcn_s_sleep(1);
      asm volatile("" ::: "memory");   // pin h loads behind the wait
      const u16* hp = hout + (size_t)(t - 1) * 32 * 1024;
      const u16* hrow0 = hp + l15 * 1024 + lhi * 8;
      const u16* hrow1 = hp + (l15 + 16) * 1024 + lhi * 8;
      f32x4 acc00 = {0,0,0,0}, acc01 = {0,0,0,0}, acc10 = {0,0,0,0}, acc11 = {0,0,0,0};
      #pragma unroll
      for (int kk = 0; kk < 8; ++kk) {
        int k = kbase + kk * 32;
        short8 bf0 = *(const short8*)(hrow0 + k);
        short8 bf1 = *(const short8*)(hrow1 + k);
        short8 af0 = *(const short8*)&whs[l15][k + lhi * 8];
        short8 af1 = *(const short8*)&whs[16 + l15][k + lhi * 8];
        acc00 = mfma16(af0, bf0, acc00);
        acc01 = mfma16(af0, bf1, acc01);
        acc10 = mfma16(af1, bf0, acc10);
        acc11 = mfma16(af1, bf1, acc11);
      }
      if (t < 34) gxn = gb4[(size_t)(t + 1) * 32768];  // (t+1)*32*1024 float4
      #pragma unroll
      for (int r = 0; r < 4; ++r) {
        pred[w][lhi * 4 + r][l15]       = acc00[r];
        pred[w][lhi * 4 + r][l15 + 16]  = acc01[r];
        pred[w][16 + lhi * 4 + r][l15]      = acc10[r];
        pred[w][16 + lhi * 4 + r][l15 + 16] = acc11[r];
      }
      __syncthreads();
    } else {
      gxn = gb4[(size_t)32 * 1024];
    }
    float pre[4];
    #pragma unroll
    for (int g = 0; g < 4; ++g) {
      float s = 0.f;
      if (t > 0) {
        int row = g * 8 + jj2;
        s = pred[0][row][bb] + pred[1][row][bb] + pred[2][row][bb] + pred[3][row][bb];
      }
      pre[g] = s;
    }
    float iv = gx.x + pre[0] + bias_r[0];
    float fv = gx.y + pre[1] + bias_r[1];
    float gv = gx.z + pre[2] + bias_r[2];
    float ov = gx.w + pre[3] + bias_r[3];
    float cc = fsigm(fv) * c_reg + fsigm(iv) * ftanh(gv);
    float hh = fsigm(ov) * ftanh(cc);
    c_reg = cc;
    store_u16_llc(hout + ((size_t)(t * 32 + bb)) * 1024 + p * 8 + jj2, f2bf(hh));
    // __syncthreads waits vmcnt(0): all 4 waves' h stores are complete at LLC,
    // and pred is safe to overwrite next step. Then publish our flag.
    __syncthreads();
    if (t < 34 && tid == 0)
      __hip_atomic_store(flags + p, sbase + (unsigned)t + 1u,
                         __ATOMIC_RELAXED, __HIP_MEMORY_SCOPE_AGENT);
    gx = gxn;
  }
}

// ---------------- logits GEMM epilogue --------------------------------------
DEV void logits_epilogue(f32x4 (&acc)[4][4], int m0, int n0, int wm, int wn,
                         int l15, int lhi, const float* lin_b,
                         float* out, float2* partials, int bn) {
  float bcol[4]; int ncol[4];
  #pragma unroll
  for (int nt = 0; nt < 4; ++nt) {
    int n = n0 + wn * 64 + nt * 16 + l15;
    ncol[nt] = n;
    bcol[nt] = (n < kVG) ? lin_b[n] : -INFINITY;
  }
  #pragma unroll
  for (int mt = 0; mt < 4; ++mt) {
    #pragma unroll
    for (int r = 0; r < 4; ++r) {
      int m = m0 + wm * 64 + mt * 16 + lhi * 4 + r;
      float v0 = acc[mt][0][r] + bcol[0];
      float v1 = acc[mt][1][r] + bcol[1];
      float v2 = acc[mt][2][r] + bcol[2];
      float v3 = acc[mt][3][r] + bcol[3];
      bool mok = (m < kM);
      if (mok) {
        float* orow = out + (size_t)m * kVG;
        if (ncol[0] < kVG) orow[ncol[0]] = v0;
        if (ncol[1] < kVG) orow[ncol[1]] = v1;
        if (ncol[2] < kVG) orow[ncol[2]] = v2;
        if (ncol[3] < kVG) orow[ncol[3]] = v3;
      }
      float mx = fmaxf(fmaxf(v0, v1), fmaxf(v2, v3));
      #pragma unroll
      for (int d2 = 1; d2 < 16; d2 <<= 1) mx = fmaxf(mx, __shfl_xor(mx, d2, 64));
      float sv = 0.f;
      sv += (v0 > -1e30f) ? fexp(v0 - mx) : 0.f;
      sv += (v1 > -1e30f) ? fexp(v1 - mx) : 0.f;
      sv += (v2 > -1e30f) ? fexp(v2 - mx) : 0.f;
      sv += (v3 > -1e30f) ? fexp(v3 - mx) : 0.f;
      #pragma unroll
      for (int d2 = 1; d2 < 16; d2 <<= 1) sv += __shfl_xor(sv, d2, 64);
      if (mok && l15 == 0)
        partials[(size_t)m * 784 + bn * 2 + wn] = make_float2(mx, sv);
    }
  }
}

// ---------------- logits GEMM (gll16 dbuf + swizzled LDS) -------------------
__global__ void __launch_bounds__(256, 4) gemm_logits_async(
    const u16* __restrict__ hist2, const u16* __restrict__ linwb,
    const float* __restrict__ lin_b, float* __restrict__ out,
    float2* __restrict__ partials) {
  // XCD-bijective swizzle
  int nwg = gridDim.x, orig = blockIdx.x;
  int q = nwg >> 3, r = nwg & 7, xcd = orig & 7, off = orig >> 3;
  int bid = (xcd < r ? xcd * (q + 1) : r * (q + 1) + (xcd - r) * q) + off;
  int bm = bid % 9, bn = bid / 9;
  int m0 = bm * 128, n0 = bn * 128;
  int tid = threadIdx.x, w = tid >> 6, lane = tid & 63, l15 = lane & 15, lhi = lane >> 4;
  int wm = w & 1, wn = w >> 1;
  __shared__ u16 As[2][128][32];
  __shared__ u16 Bs[2][128][32];
  int cl = ((lane & 3) ^ ((lane >> 3) & 3)) * 8;
  int am0 = m0 + w * 32 + (lane >> 2);
  int am1 = am0 + 16;
  int mm0 = (am0 < kM) ? am0 : 0, mm1 = (am1 < kM) ? am1 : 0;
  const u16* arow0 = hist2 + (((size_t)((mm0 % 35) * 32 + mm0 / 35)) << 10) + cl;
  const u16* arow1 = hist2 + (((size_t)((mm1 % 35) * 32 + mm1 / 35)) << 10) + cl;
  int nr0 = n0 + w * 32 + (lane >> 2);
  int nn0 = (nr0 < kVG) ? nr0 : 0, nn1 = (nr0 + 16 < kVG) ? nr0 + 16 : 0;
  const u16* brow0 = linwb + ((size_t)nn0 << 10) + cl;
  const u16* brow1 = linwb + ((size_t)nn1 << 10) + cl;
  const int koff = (lhi ^ ((l15 >> 1) & 3)) * 8;

  f32x4 acc[4][4];
  #pragma unroll
  for (int i = 0; i < 4; ++i)
    #pragma unroll
    for (int j = 0; j < 4; ++j) { f32x4 z = {0.f, 0.f, 0.f, 0.f}; acc[i][j] = z; }

  auto ISSUE = [&](int k0, int buf) {
    gll16(arow0 + k0, &As[buf][w * 32][0]);
    gll16(arow1 + k0, &As[buf][w * 32 + 16][0]);
    gll16(brow0 + k0, &Bs[buf][w * 32][0]);
    gll16(brow1 + k0, &Bs[buf][w * 32 + 16][0]);
  };
  ISSUE(0, 0);
  for (int kt = 0; kt < 32; ++kt) {
    int cur = kt & 1;
    if (kt < 31) {
      ISSUE((kt + 1) * 32, cur ^ 1);
      asm volatile("s_waitcnt vmcnt(4)" ::: "memory");
    } else {
      asm volatile("s_waitcnt vmcnt(0)" ::: "memory");
    }
    __builtin_amdgcn_s_barrier();
    __builtin_amdgcn_sched_barrier(0);
    short8 bfr[4];
    #pragma unroll
    for (int nt = 0; nt < 4; ++nt)
      bfr[nt] = *(const short8*)&Bs[cur][wn * 64 + nt * 16 + l15][koff];
    #pragma unroll
    for (int mt = 0; mt < 4; ++mt) {
      short8 af = *(const short8*)&As[cur][wm * 64 + mt * 16 + l15][koff];
      #pragma unroll
      for (int nt = 0; nt < 4; ++nt)
        acc[mt][nt] = mfma16(af, bfr[nt], acc[mt][nt]);
    }
    __builtin_amdgcn_sched_barrier(0);
    __builtin_amdgcn_s_barrier();
  }
  logits_epilogue(acc, m0, n0, wm, wn, l15, lhi, lin_b, out, partials, bn);
}

// fallback (no bf16 workspace image): reg-staged, fp32 B inline-converted
__global__ void __launch_bounds__(256, 1) gemm_logits_fb(
    const u16* __restrict__ hist2, const float* __restrict__ lin_W,
    const float* __restrict__ lin_b, float* __restrict__ out,
    float2* __restrict__ partials) {
  int nwg = gridDim.x, orig = blockIdx.x;
  int q = nwg >> 3, r = nwg & 7, xcd = orig & 7, off = orig >> 3;
  int bid = (xcd < r ? xcd * (q + 1) : r * (q + 1) + (xcd - r) * q) + off;
  int bm = bid % 9, bn = bid / 9;
  int m0 = bm * 128, n0 = bn * 128;
  int tid = threadIdx.x, w = tid >> 6, lane = tid & 63, l15 = lane & 15, lhi = lane >> 4;
  int wm = w & 1, wn = w >> 1;
  __shared__ u16 As[128][40];
  __shared__ u16 Bs[128][40];
  f32x4 acc[4][4];
  #pragma unroll
  for (int i = 0; i < 4; ++i)
    #pragma unroll
    for (int j = 0; j < 4; ++j) { f32x4 z = {0.f, 0.f, 0.f, 0.f}; acc[i][j] = z; }
  for (int kt = 0; kt < 32; ++kt) {
    int k0 = kt * 32;
    #pragma unroll
    for (int q2 = 0; q2 < 2; ++q2) {
      int c = tid * 2 + q2; int row = c >> 2; int ch = c & 3;
      int m = m0 + row;
      uint4 av{0u, 0u, 0u, 0u};
      if (m < kM) {
        int b = m / 35; int t = m - b * 35;
        av = *(const uint4*)(hist2 + ((size_t)(t * 32 + b) << 10) + k0 + ch * 8);
      }
      *(uint4*)&As[row][ch * 8] = av;
      int n = n0 + row;
      uint4 bv{0u, 0u, 0u, 0u};
      if (n < kVG) {
        const float* src = lin_W + (size_t)n * 1024 + k0 + ch * 8;
        float4 f0 = *(const float4*)(src);
        float4 f1 = *(const float4*)(src + 4);
        bv.x = (unsigned)f2bf(f0.x) | ((unsigned)f2bf(f0.y) << 16);
        bv.y = (unsigned)f2bf(f0.z) | ((unsigned)f2bf(f0.w) << 16);
        bv.z = (unsigned)f2bf(f1.x) | ((unsigned)f2bf(f1.y) << 16);
        bv.w = (unsigned)f2bf(f1.z) | ((unsigned)f2bf(f1.w) << 16);
      }
      *(uint4*)&Bs[row][ch * 8] = bv;
    }
    __syncthreads();
    short8 bfr[4];
    #pragma unroll
    for (int nt = 0; nt < 4; ++nt)
      bfr[nt] = *(const short8*)&Bs[wn * 64 + nt * 16 + l15][lhi * 8];
    #pragma unroll
    for (int mt = 0; mt < 4; ++mt) {
      short8 af = *(const short8*)&As[wm * 64 + mt * 16 + l15][lhi * 8];
      #pragma unroll
      for (int nt = 0; nt < 4; ++nt)
        acc[mt][nt] = mfma16(af, bfr[nt], acc[mt][nt]);
    }
    __syncthreads();
  }
  logits_epilogue(acc, m0, n0, wm, wn, l15, lhi, lin_b, out, partials, bn);
}

// ---------------- row logsumexp reduce --------------------------------------
__global__ void reduce_rows(const float2* __restrict__ partials, float* __restrict__ lse) {
  int m = blockIdx.x, tid = threadIdx.x;
  float mx = -INFINITY, s = 0.f;
  for (int j = tid; j < 782; j += 256) {
    float2 p = partials[(size_t)m * 784 + j];
    if (p.x > mx) { s = s * fexp(mx - p.x) + p.y; mx = p.x; }
    else          { s += p.y * fexp(p.x - mx); }
  }
  for (int d = 1; d < 64; d <<= 1) {
    float omx = __shfl_xor(mx, d, 64);
    float os  = __shfl_xor(s, d, 64);
    if (omx > mx) { s = s * fexp(mx - omx) + os; mx = omx; }
    else          { s += os * fexp(omx - mx); }
  }
  __shared__ float smx[4], ssum[4];
  int w = tid >> 6;
  if ((tid & 63) == 0) { smx[w] = mx; ssum[w] = s; }
  __syncthreads();
  if (tid == 0) {
    for (int i = 1; i < 4; ++i) {
      float omx = smx[i], os = ssum[i];
      if (omx > mx) { s = s * fexp(mx - omx) + os; mx = omx; }
      else          { s += os * fexp(omx - mx); }
    }
    lse[m] = mx + logf(s);
  }
}

// ---------------- in-place log_softmax subtract -----------------------------
__global__ void sub_lse(float* __restrict__ out, const float* __restrict__ lse) {
  const int total4 = 14000000;  // 1120*50000/4
  for (int i = blockIdx.x * blockDim.x + threadIdx.x; i < total4; i += gridDim.x * blockDim.x) {
    int m = i / 12500;
    float4 v = ((float4*)out)[i];
    float L = lse[m];
    v.x -= L; v.y -= L; v.z -= L; v.w -= L;
    ((float4*)out)[i] = v;
  }
}

// ---------------- launch ----------------------------------------------------
extern "C" void kernel_launch(void* const* d_in, const int* in_sizes, int n_in,
                              void* d_out, int out_size, void* d_ws, size_t ws_size,
                              hipStream_t stream) {
  const int*   x_indices  = (const int*)d_in[0];
  const int*   edge_index = (const int*)d_in[1];
  const float* X          = (const float*)d_in[2];
  const float* gat_W      = (const float*)d_in[3];
  const float* att_src    = (const float*)d_in[4];
  const float* att_dst    = (const float*)d_in[5];
  const float* gat_bias   = (const float*)d_in[6];
  const float* W_ih0      = (const float*)d_in[7];
  const float* W_ih_rest  = (const float*)d_in[8];
  const float* W_hh       = (const float*)d_in[9];
  const float* b_ih       = (const float*)d_in[10];
  const float* b_hh       = (const float*)d_in[11];
  const float* lin_W      = (const float*)d_in[12];
  const float* lin_b      = (const float*)d_in[13];
  float* out = (float*)d_out;
  char* ws = (char*)d_ws;

  unsigned* flags    = (unsigned*)(ws + OFF_BAR);
  float*    ws_src   = (float*)(ws + OFF_WSRC);
  float*    ws_dst   = (float*)(ws + OFF_WDST);
  float*    bias_sum = (float*)(ws + OFF_BIAS);
  u16*      sig      = (u16*)(ws + OFF_SIG);
  u16*      wx0      = (u16*)(ws + OFF_WX0);
  u16*      wx12     = (u16*)(ws + OFF_WX12);
  float*    gates    = (float*)(ws + OFF_GATES);
  u16*      hist     = (u16*)(ws + OFF_HIST);
  float2*   partials = (float2*)(ws + OFF_PART);
  float*    lse      = (float*)(ws + OFF_LSE);
  u16*      linwb    = (u16*)(ws + OFF_LINWB);
  u16*      whb      = (u16*)(ws + OFF_WHB);
  bool use_bw  = (ws_size >= kNeedBW);
  bool use_whb = (ws_size >= kNeedWHB);
  bool hide = use_bw && use_whb;   // conversions hidden inside lstm_rec

  u16* hist0 = hist;
  u16* hist1 = hist + (size_t)35 * 32 * 1024;
  u16* hist2 = hist + (size_t)2 * 35 * 32 * 1024;
  const long nLinHalf = (long)kVG * 1024 / 2;   // 25,600,000

  hipMemsetAsync(ws + OFF_BAR, 0, 1024, stream);
  prep_small<<<64, 256, 0, stream>>>(gat_W, att_src, att_dst, b_ih, b_hh,
                                     ws_src, ws_dst, bias_sum);
  wx_prep<<<2048, 256, 0, stream>>>(W_ih0, W_ih_rest, W_hh, wx0, wx12,
                                    use_whb ? whb : nullptr, hide ? 1 : 3);
  if (use_bw && !hide) wb_conv<<<2048, 256, 0, stream>>>(lin_W, linwb);
  gat_kernel<<<kG, 256, 0, stream>>>(x_indices, edge_index, X, gat_W, gat_bias,
                                     ws_src, ws_dst, sig);
  // layer 0 (+ hidden conversions: whb layers 1-2, lin_W first half)
  gemm_ig<<<288, 256, 0, stream>>>(sig, wx0, gates, 640);
  lstm_rec<<<hide ? 256 : 128, 256, 0, stream>>>(
      W_hh, use_whb ? whb : nullptr, gates, bias_sum, hist0, flags, 0u,
      hide ? W_hh + (size_t)4096 * 1024 : nullptr,
      hide ? whb + (size_t)4096 * 1024 : nullptr, (long)2 * 4096 * 1024,
      hide ? lin_W : nullptr, hide ? linwb : nullptr, nLinHalf);
  // layer 1 (+ hidden conversion: lin_W second half)
  gemm_ig<<<288, 256, 0, stream>>>(hist0, wx12, gates, 1024);
  lstm_rec<<<hide ? 256 : 128, 256, 0, stream>>>(
      W_hh + (size_t)4096 * 1024,
      use_whb ? whb + (size_t)4096 * 1024 : nullptr,
      gates, bias_sum + 4096, hist1, flags, 34u,
      hide ? lin_W + nLinHalf : nullptr,
      hide ? linwb + nLinHalf : nullptr, nLinHalf,
      nullptr, nullptr, 0);
  // layer 2
  gemm_ig<<<288, 256, 0, stream>>>(hist1, wx12 + (size_t)4096 * 1024, gates, 1024);
  lstm_rec<<<128, 256, 0, stream>>>(
      W_hh + (size_t)2 * 4096 * 1024,
      use_whb ? whb + (size_t)2 * 4096 * 1024 : nullptr,
      gates, bias_sum + 8192, hist2, flags, 68u,
      nullptr, nullptr, 0, nullptr, nullptr, 0);
  // logits + log_softmax
  if (use_bw)
    gemm_logits_async<<<9 * 391, 256, 0, stream>>>(hist2, linwb, lin_b, out, partials);
  else
    gemm_logits_fb<<<9 * 391, 256, 0, stream>>>(hist2, lin_W, lin_b, out, partials);
  reduce_rows<<<kG, 256, 0, stream>>>(partials, lse);
  sub_lse<<<2048, 256, 0, stream>>>(out, lse);
}